// Round 1
// baseline (1426.537 us; speedup 1.0000x reference)
//
#include <hip/hip_runtime.h>

#define NNODES 50000
#define NEDGES 800000
#define NG 64
#define D 64
#define D2 128
#define INDIM 39
#define EDIM 10
#define BN_EPS 1e-5f
#define BN_BIAS 1e-4f

// ---------------- encoder: h = x @ Wenc + benc ----------------
__global__ __launch_bounds__(256) void k_enc(const float* __restrict__ x,
                                             const float* __restrict__ Wenc,
                                             const float* __restrict__ benc,
                                             float* __restrict__ h) {
    __shared__ float sW[INDIM * D];
    for (int i = threadIdx.x; i < INDIM * D; i += 256) sW[i] = Wenc[i];
    __syncthreads();
    int wave = threadIdx.x >> 6, lane = threadIdx.x & 63;
    int row = blockIdx.x * 4 + wave;
    if (row >= NNODES) return;
    float xv = (lane < INDIM) ? x[row * INDIM + lane] : 0.f;
    float acc = benc[lane];
#pragma unroll
    for (int k = 0; k < INDIM; ++k) acc += __shfl(xv, k) * sW[k * D + lane];
    h[row * D + lane] = acc;
}

// ---------------- prep: hin = h + vn[batch]; zin = (1+eps)*hin ----------------
__global__ __launch_bounds__(256) void k_prep(const float* __restrict__ h,
                                              const float* __restrict__ vn,
                                              const int* __restrict__ batch,
                                              const float* __restrict__ eps, int l,
                                              float* __restrict__ hin,
                                              float* __restrict__ zin) {
    int idx = blockIdx.x * 256 + threadIdx.x;
    if (idx >= NNODES * D) return;
    int row = idx >> 6, col = idx & 63;
    float v = h[idx] + vn[batch[row] * D + col];
    hin[idx] = v;
    zin[idx] = (1.f + eps[l]) * v;
}

// ---------------- edge: zin[dst] += relu(hin[src] + edge_attr@We + be) ----------------
#define EPW 8
__global__ __launch_bounds__(256) void k_edge(const float* __restrict__ edge_attr,
                                              const int* __restrict__ ei,
                                              const float* __restrict__ We,
                                              const float* __restrict__ be, int l,
                                              const float* __restrict__ hin,
                                              float* __restrict__ zin) {
    __shared__ float sW[EDIM * D];
    __shared__ float sb[D];
    const float* Wl = We + l * EDIM * D;
    for (int i = threadIdx.x; i < EDIM * D; i += 256) sW[i] = Wl[i];
    if (threadIdx.x < D) sb[threadIdx.x] = be[l * D + threadIdx.x];
    __syncthreads();
    int wave = threadIdx.x >> 6, lane = threadIdx.x & 63;
    int base = (blockIdx.x * 4 + wave) * EPW;
#pragma unroll 1
    for (int it = 0; it < EPW; ++it) {
        int e = base + it;
        if (e >= NEDGES) return;
        int src = ei[e], dst = ei[NEDGES + e];
        float eav = (lane < EDIM) ? edge_attr[e * EDIM + lane] : 0.f;
        float m = sb[lane];
#pragma unroll
        for (int k = 0; k < EDIM; ++k) m += __shfl(eav, k) * sW[k * D + lane];
        m += hin[src * D + lane];
        m = fmaxf(m, 0.f);
        atomicAdd(&zin[dst * D + lane], m);
    }
}

// ---------------- GEMM1: t = zin @ W1 + b1 (+ BN stats of t) ----------------
__global__ __launch_bounds__(256) void k_gemm1(const float* __restrict__ zin,
                                               const float* __restrict__ W1,
                                               const float* __restrict__ b1, int l,
                                               float* __restrict__ t,
                                               float* __restrict__ stats1) {
    __shared__ float sZ[64 * D];    // 16KB
    __shared__ float sW[D * D2];    // 32KB
    __shared__ float sSum[D2], sSq[D2];
    const float* Wp = W1 + l * D * D2;
    int row0 = blockIdx.x * 64;
    int nvalid = min(64, NNODES - row0);
    for (int i = threadIdx.x; i < D * D2; i += 256) sW[i] = Wp[i];
    for (int i = threadIdx.x; i < 64 * D; i += 256) {
        int r = i >> 6;
        sZ[i] = (r < nvalid) ? zin[(row0 + r) * D + (i & 63)] : 0.f;
    }
    if (threadIdx.x < D2) { sSum[threadIdx.x] = 0.f; sSq[threadIdx.x] = 0.f; }
    __syncthreads();
    int cg = threadIdx.x & 31;   // cols cg*4 .. cg*4+3
    int rg = threadIdx.x >> 5;   // rows rg*8 .. rg*8+7
    float4 binit = *(const float4*)&b1[l * D2 + cg * 4];
    float4 acc[8];
#pragma unroll
    for (int r = 0; r < 8; ++r) acc[r] = binit;
    for (int k = 0; k < D; ++k) {
        float4 w = *(const float4*)&sW[k * D2 + cg * 4];
#pragma unroll
        for (int r = 0; r < 8; ++r) {
            float a = sZ[(rg * 8 + r) * D + k];
            acc[r].x += a * w.x; acc[r].y += a * w.y;
            acc[r].z += a * w.z; acc[r].w += a * w.w;
        }
    }
    float4 s = {0, 0, 0, 0}, sq = {0, 0, 0, 0};
#pragma unroll
    for (int r = 0; r < 8; ++r) {
        int row = rg * 8 + r;
        if (row < nvalid) {
            *(float4*)&t[(row0 + row) * D2 + cg * 4] = acc[r];
            s.x += acc[r].x; s.y += acc[r].y; s.z += acc[r].z; s.w += acc[r].w;
            sq.x += acc[r].x * acc[r].x; sq.y += acc[r].y * acc[r].y;
            sq.z += acc[r].z * acc[r].z; sq.w += acc[r].w * acc[r].w;
        }
    }
    atomicAdd(&sSum[cg * 4 + 0], s.x); atomicAdd(&sSq[cg * 4 + 0], sq.x);
    atomicAdd(&sSum[cg * 4 + 1], s.y); atomicAdd(&sSq[cg * 4 + 1], sq.y);
    atomicAdd(&sSum[cg * 4 + 2], s.z); atomicAdd(&sSq[cg * 4 + 2], sq.z);
    atomicAdd(&sSum[cg * 4 + 3], s.w); atomicAdd(&sSq[cg * 4 + 3], sq.w);
    __syncthreads();
    if (threadIdx.x < D2) {
        atomicAdd(&stats1[threadIdx.x], sSum[threadIdx.x]);
        atomicAdd(&stats1[D2 + threadIdx.x], sSq[threadIdx.x]);
    }
}

// ---------------- GEMM2: z2 = relu(bn(t)) @ W2 + b2 (+ BN stats of z2) ----------------
__global__ __launch_bounds__(256) void k_gemm2(const float* __restrict__ t,
                                               const float* __restrict__ stats1,
                                               const float* __restrict__ W2,
                                               const float* __restrict__ b2, int l,
                                               float* __restrict__ z2,
                                               float* __restrict__ stats2) {
    __shared__ float sT[32 * D2];   // 16KB (normalized input)
    __shared__ float sW[D2 * D];    // 32KB
    __shared__ float sSum[D], sSq[D];
    const float* Wp = W2 + l * D2 * D;
    int row0 = blockIdx.x * 32;
    int nvalid = min(32, NNODES - row0);
    for (int i = threadIdx.x; i < D2 * D; i += 256) sW[i] = Wp[i];
    const float invN = 1.f / NNODES;
    for (int i = threadIdx.x; i < 32 * D2; i += 256) {
        int r = i >> 7, c = i & 127;
        float v = 0.f;
        if (r < nvalid) {
            float mu = stats1[c] * invN;
            float var = stats1[D2 + c] * invN - mu * mu;
            float rstd = rsqrtf(var + BN_EPS);
            v = (t[(row0 + r) * D2 + c] - mu) * rstd + BN_BIAS;
            v = fmaxf(v, 0.f);
        }
        sT[i] = v;
    }
    if (threadIdx.x < D) { sSum[threadIdx.x] = 0.f; sSq[threadIdx.x] = 0.f; }
    __syncthreads();
    int cg = threadIdx.x & 31;   // cols cg*2, cg*2+1
    int rg = threadIdx.x >> 5;   // rows rg*4 .. rg*4+3
    float2 binit = *(const float2*)&b2[l * D + cg * 2];
    float2 acc[4];
#pragma unroll
    for (int r = 0; r < 4; ++r) acc[r] = binit;
    for (int k = 0; k < D2; ++k) {
        float2 w = *(const float2*)&sW[k * D + cg * 2];
#pragma unroll
        for (int r = 0; r < 4; ++r) {
            float a = sT[(rg * 4 + r) * D2 + k];
            acc[r].x += a * w.x; acc[r].y += a * w.y;
        }
    }
    float2 s = {0, 0}, sq = {0, 0};
#pragma unroll
    for (int r = 0; r < 4; ++r) {
        int row = rg * 4 + r;
        if (row < nvalid) {
            *(float2*)&z2[(row0 + row) * D + cg * 2] = acc[r];
            s.x += acc[r].x; s.y += acc[r].y;
            sq.x += acc[r].x * acc[r].x; sq.y += acc[r].y * acc[r].y;
        }
    }
    atomicAdd(&sSum[cg * 2 + 0], s.x); atomicAdd(&sSq[cg * 2 + 0], sq.x);
    atomicAdd(&sSum[cg * 2 + 1], s.y); atomicAdd(&sSq[cg * 2 + 1], sq.y);
    __syncthreads();
    if (threadIdx.x < D) {
        atomicAdd(&stats2[threadIdx.x], sSum[threadIdx.x]);
        atomicAdd(&stats2[D + threadIdx.x], sSq[threadIdx.x]);
    }
}

// ---------------- finish: h = bn(z2) (+relu) ----------------
__global__ __launch_bounds__(256) void k_finish(const float* __restrict__ z2,
                                                const float* __restrict__ stats2,
                                                float* __restrict__ h, int do_relu) {
    int idx = blockIdx.x * 256 + threadIdx.x;
    if (idx >= NNODES * D) return;
    int c = idx & 63;
    const float invN = 1.f / NNODES;
    float mu = stats2[c] * invN;
    float var = stats2[D + c] * invN - mu * mu;
    float rstd = rsqrtf(var + BN_EPS);
    float v = (z2[idx] - mu) * rstd + BN_BIAS;
    if (do_relu) v = fmaxf(v, 0.f);
    h[idx] = v;
}

// ---------------- vt = segment_sum(hin, batch) + vn (batch sorted) ----------------
__global__ __launch_bounds__(256) void k_vt(const float* __restrict__ hin,
                                            const float* __restrict__ vn,
                                            const int* __restrict__ batch,
                                            float* __restrict__ vt) {
    int g = blockIdx.x;
    int col = threadIdx.x & 63, rc = threadIdx.x >> 6;
    int lo = 0, hi = NNODES;
    while (lo < hi) { int mid = (lo + hi) >> 1; if (batch[mid] < g) lo = mid + 1; else hi = mid; }
    int s = lo;
    hi = NNODES;
    while (lo < hi) { int mid = (lo + hi) >> 1; if (batch[mid] < g + 1) lo = mid + 1; else hi = mid; }
    int e = lo;
    float acc = 0.f;
    for (int i = s + rc; i < e; i += 4) acc += hin[i * D + col];
    __shared__ float red[4][D];
    red[rc][col] = acc;
    __syncthreads();
    if (rc == 0)
        vt[g * D + col] = red[0][col] + red[1][col] + red[2][col] + red[3][col] + vn[g * D + col];
}

// ---------------- virtual-node MLP (one block) ----------------
__global__ __launch_bounds__(256) void k_vnmlp(const float* __restrict__ vt,
                                               const float* __restrict__ Wv1,
                                               const float* __restrict__ bv1,
                                               const float* __restrict__ Wv2,
                                               const float* __restrict__ bv2, int l,
                                               float* __restrict__ vn) {
    __shared__ float sV[NG * D];    // 16KB
    __shared__ float sU[NG * D2];   // 32KB
    const float* W1p = Wv1 + l * D * D2;
    const float* W2p = Wv2 + l * D2 * D;
    for (int i = threadIdx.x; i < NG * D; i += 256) sV[i] = vt[i];
    __syncthreads();
    // u = vt @ Wv1 + bv1 : 64x128. thread: row r, 32 cols
    {
        int r = threadIdx.x >> 2, cb = (threadIdx.x & 3) * 32;
        float acc[32];
#pragma unroll
        for (int c = 0; c < 32; ++c) acc[c] = bv1[l * D2 + cb + c];
        for (int k = 0; k < D; ++k) {
            float v = sV[r * D + k];
#pragma unroll
            for (int c = 0; c < 32; ++c) acc[c] += v * W1p[k * D2 + cb + c];
        }
#pragma unroll
        for (int c = 0; c < 32; ++c) sU[r * D2 + cb + c] = acc[c];
    }
    __syncthreads();
    if (threadIdx.x < D2) {   // BN over 64 rows + relu
        int c = threadIdx.x;
        float s = 0, sq = 0;
        for (int r = 0; r < NG; ++r) { float v = sU[r * D2 + c]; s += v; sq += v * v; }
        float mu = s / NG, rstd = rsqrtf(sq / NG - mu * mu + BN_EPS);
        for (int r = 0; r < NG; ++r)
            sU[r * D2 + c] = fmaxf((sU[r * D2 + c] - mu) * rstd + BN_BIAS, 0.f);
    }
    __syncthreads();
    // w = u @ Wv2 + bv2 : 64x64 into sV
    {
        int r = threadIdx.x >> 2, cb = (threadIdx.x & 3) * 16;
        float acc[16];
#pragma unroll
        for (int c = 0; c < 16; ++c) acc[c] = bv2[l * D + cb + c];
        for (int k = 0; k < D2; ++k) {
            float v = sU[r * D2 + k];
#pragma unroll
            for (int c = 0; c < 16; ++c) acc[c] += v * W2p[k * D + cb + c];
        }
#pragma unroll
        for (int c = 0; c < 16; ++c) sV[r * D + cb + c] = acc[c];
    }
    __syncthreads();
    if (threadIdx.x < D) {   // BN over 64 rows + relu -> vn
        int c = threadIdx.x;
        float s = 0, sq = 0;
        for (int r = 0; r < NG; ++r) { float v = sV[r * D + c]; s += v; sq += v * v; }
        float mu = s / NG, rstd = rsqrtf(sq / NG - mu * mu + BN_EPS);
        for (int r = 0; r < NG; ++r)
            vn[r * D + c] = fmaxf((sV[r * D + c] - mu) * rstd + BN_BIAS, 0.f);
    }
}

// ---------------- heads ----------------
__global__ __launch_bounds__(256) void k_node_att(const float* __restrict__ h,
                                                  const float* __restrict__ Wna,
                                                  const float* __restrict__ bna,
                                                  float* __restrict__ out) {
    int wave = threadIdx.x >> 6, lane = threadIdx.x & 63;
    int row = blockIdx.x * 4 + wave;
    if (row >= NNODES) return;
    float v = h[row * D + lane];
    float s0 = v * Wna[lane * 2 + 0];
    float s1 = v * Wna[lane * 2 + 1];
#pragma unroll
    for (int o = 32; o; o >>= 1) { s0 += __shfl_xor(s0, o); s1 += __shfl_xor(s1, o); }
    if (lane == 0) out[row] = 1.f / (1.f + expf((s0 + bna[0]) - (s1 + bna[1])));
}

__global__ __launch_bounds__(256) void k_edge_att(const float* __restrict__ h,
                                                  const int* __restrict__ ei,
                                                  const float* __restrict__ Wea,
                                                  const float* __restrict__ bea,
                                                  float* __restrict__ out) {
    int wave = threadIdx.x >> 6, lane = threadIdx.x & 63;
    int e = blockIdx.x * 4 + wave;
    if (e >= NEDGES) return;
    int src = ei[e], dst = ei[NEDGES + e];
    float vs = h[src * D + lane], vd = h[dst * D + lane];
    float s0 = vs * Wea[lane * 2 + 0] + vd * Wea[(D + lane) * 2 + 0];
    float s1 = vs * Wea[lane * 2 + 1] + vd * Wea[(D + lane) * 2 + 1];
#pragma unroll
    for (int o = 32; o; o >>= 1) { s0 += __shfl_xor(s0, o); s1 += __shfl_xor(s1, o); }
    if (lane == 0) out[NNODES + e] = 1.f / (1.f + expf((s0 + bea[0]) - (s1 + bea[1])));
}

extern "C" void kernel_launch(void* const* d_in, const int* in_sizes, int n_in,
                              void* d_out, int out_size, void* d_ws, size_t ws_size,
                              hipStream_t stream) {
    const float* x    = (const float*)d_in[0];
    const float* ea   = (const float*)d_in[1];
    const int*   ei   = (const int*)d_in[2];
    const int*   batch= (const int*)d_in[3];
    const float* Wenc = (const float*)d_in[4];
    const float* benc = (const float*)d_in[5];
    const float* We   = (const float*)d_in[6];
    const float* be   = (const float*)d_in[7];
    const float* eps  = (const float*)d_in[8];
    const float* W1   = (const float*)d_in[9];
    const float* b1   = (const float*)d_in[10];
    const float* W2   = (const float*)d_in[11];
    const float* b2   = (const float*)d_in[12];
    const float* Wv1  = (const float*)d_in[13];
    const float* bv1  = (const float*)d_in[14];
    const float* Wv2  = (const float*)d_in[15];
    const float* bv2  = (const float*)d_in[16];
    const float* Wea  = (const float*)d_in[17];
    const float* bea  = (const float*)d_in[18];
    const float* Wna  = (const float*)d_in[19];
    const float* bna  = (const float*)d_in[20];
    float* out = (float*)d_out;

    float* ws  = (float*)d_ws;
    float* h   = ws;
    float* hin = h   + (size_t)NNODES * D;
    float* zin = hin + (size_t)NNODES * D;
    float* t   = zin + (size_t)NNODES * D;
    float* z2  = t   + (size_t)NNODES * D2;
    float* vn  = z2  + (size_t)NNODES * D;
    float* vt  = vn  + NG * D;
    float* stats = vt + NG * D;   // [128 sum][128 sq][64 sum][64 sq]

    hipMemsetAsync(vn, 0, NG * D * sizeof(float), stream);
    k_enc<<<NNODES / 4, 256, 0, stream>>>(x, Wenc, benc, h);
    for (int l = 0; l < 3; ++l) {
        k_prep<<<NNODES * D / 256, 256, 0, stream>>>(h, vn, batch, eps, l, hin, zin);
        k_edge<<<NEDGES / 32, 256, 0, stream>>>(ea, ei, We, be, l, hin, zin);
        hipMemsetAsync(stats, 0, 384 * sizeof(float), stream);
        k_gemm1<<<(NNODES + 63) / 64, 256, 0, stream>>>(zin, W1, b1, l, t, stats);
        k_gemm2<<<(NNODES + 31) / 32, 256, 0, stream>>>(t, stats, W2, b2, l, z2, stats + 256);
        k_finish<<<NNODES * D / 256, 256, 0, stream>>>(z2, stats + 256, h, l < 2 ? 1 : 0);
        if (l < 2) {
            k_vt<<<NG, 256, 0, stream>>>(hin, vn, batch, vt);
            k_vnmlp<<<1, 256, 0, stream>>>(vt, Wv1, bv1, Wv2, bv2, l, vn);
        }
    }
    k_node_att<<<NNODES / 4, 256, 0, stream>>>(h, Wna, bna, out);
    k_edge_att<<<NEDGES / 4, 256, 0, stream>>>(h, ei, Wea, bea, out);
}

// Round 2
// 1381.258 us; speedup vs baseline: 1.0328x; 1.0328x over previous
//
#include <hip/hip_runtime.h>

#define NNODES 50000
#define NEDGES 800000
#define NG 64
#define D 64
#define D2 128
#define INDIM 39
#define EDIM 10
#define BN_EPS 1e-5f
#define BN_BIAS 1e-4f

// ---------------- encoder: h = x @ Wenc + benc ----------------
__global__ __launch_bounds__(256) void k_enc(const float* __restrict__ x,
                                             const float* __restrict__ Wenc,
                                             const float* __restrict__ benc,
                                             float* __restrict__ h) {
    __shared__ float sW[INDIM * D];
    for (int i = threadIdx.x; i < INDIM * D; i += 256) sW[i] = Wenc[i];
    __syncthreads();
    int wave = threadIdx.x >> 6, lane = threadIdx.x & 63;
    int row = blockIdx.x * 4 + wave;
    if (row >= NNODES) return;
    float xv = (lane < INDIM) ? x[row * INDIM + lane] : 0.f;
    float acc = benc[lane];
#pragma unroll
    for (int k = 0; k < INDIM; ++k) acc += __shfl(xv, k) * sW[k * D + lane];
    h[row * D + lane] = acc;
}

// ---------------- CSR build ----------------
__global__ __launch_bounds__(256) void k_hist(const int* __restrict__ ei,
                                              int* __restrict__ deg) {
    int e = blockIdx.x * 256 + threadIdx.x;
    if (e < NEDGES) atomicAdd(&deg[ei[NEDGES + e]], 1);
}

#define SCAN_T 1024
#define SCAN_C 49  // 1024*49 >= 50000
__global__ __launch_bounds__(SCAN_T) void k_scan(const int* __restrict__ deg,
                                                 int* __restrict__ off,
                                                 int* __restrict__ cursor) {
    __shared__ int part[SCAN_T];
    int t = threadIdx.x;
    int c0 = min(t * SCAN_C, NNODES), c1 = min(c0 + SCAN_C, NNODES);
    int s = 0;
    for (int i = c0; i < c1; ++i) s += deg[i];
    part[t] = s;
    __syncthreads();
    for (int o = 1; o < SCAN_T; o <<= 1) {
        int v = (t >= o) ? part[t - o] : 0;
        __syncthreads();
        part[t] += v;
        __syncthreads();
    }
    int run = (t == 0) ? 0 : part[t - 1];
    for (int i = c0; i < c1; ++i) {
        off[i] = run; cursor[i] = run; run += deg[i];
    }
    if (t == SCAN_T - 1) off[NNODES] = run;
}

__global__ __launch_bounds__(256) void k_scatter(const int* __restrict__ ei,
                                                 int* __restrict__ cursor,
                                                 int* __restrict__ epos,
                                                 int* __restrict__ esrc) {
    int e = blockIdx.x * 256 + threadIdx.x;
    if (e >= NEDGES) return;
    int d = ei[NEDGES + e];
    int p = atomicAdd(&cursor[d], 1);
    epos[p] = e;
    esrc[p] = ei[e];
}

// ---------------- aggregate: zin[n] = (1+eps)*hin[n] + sum relu(hin[src]+eemb) ----------------
__global__ __launch_bounds__(256) void k_agg(const float* __restrict__ ea,
                                             const int* __restrict__ off,
                                             const int* __restrict__ epos,
                                             const int* __restrict__ esrc,
                                             const float* __restrict__ We,
                                             const float* __restrict__ be,
                                             const float* __restrict__ eps, int l,
                                             const float* __restrict__ hin,
                                             float* __restrict__ zin) {
    __shared__ float sW[EDIM * D];
    __shared__ float sb[D];
    const float* Wl = We + l * EDIM * D;
    for (int i = threadIdx.x; i < EDIM * D; i += 256) sW[i] = Wl[i];
    if (threadIdx.x < D) sb[threadIdx.x] = be[l * D + threadIdx.x];
    __syncthreads();
    int wave = threadIdx.x >> 6, lane = threadIdx.x & 63;
    int n = blockIdx.x * 4 + wave;
    if (n >= NNODES) return;
    int beg = off[n], end = off[n + 1];
    float acc = (1.f + eps[l]) * hin[n * D + lane];
    float bias = sb[lane];
    for (int j = beg; j < end; ++j) {
        int e = epos[j], src = esrc[j];
        float eav = (lane < EDIM) ? ea[e * EDIM + lane] : 0.f;
        float hv = hin[src * D + lane];
        float m = bias;
#pragma unroll
        for (int k = 0; k < EDIM; ++k) m += __shfl(eav, k) * sW[k * D + lane];
        acc += fmaxf(m + hv, 0.f);
    }
    zin[n * D + lane] = acc;
}

// ---------------- GEMM1: t = zin @ W1 + b1 (+ BN stats of t) ----------------
__global__ __launch_bounds__(256) void k_gemm1(const float* __restrict__ zin,
                                               const float* __restrict__ W1,
                                               const float* __restrict__ b1, int l,
                                               float* __restrict__ t,
                                               float* __restrict__ stats1) {
    __shared__ float sZ[64 * D];
    __shared__ float sW[D * D2];
    __shared__ float sSum[D2], sSq[D2];
    const float* Wp = W1 + l * D * D2;
    int row0 = blockIdx.x * 64;
    int nvalid = min(64, NNODES - row0);
    for (int i = threadIdx.x; i < D * D2; i += 256) sW[i] = Wp[i];
    for (int i = threadIdx.x; i < 64 * D; i += 256) {
        int r = i >> 6;
        sZ[i] = (r < nvalid) ? zin[(row0 + r) * D + (i & 63)] : 0.f;
    }
    if (threadIdx.x < D2) { sSum[threadIdx.x] = 0.f; sSq[threadIdx.x] = 0.f; }
    __syncthreads();
    int cg = threadIdx.x & 31;
    int rg = threadIdx.x >> 5;
    float4 binit = *(const float4*)&b1[l * D2 + cg * 4];
    float4 acc[8];
#pragma unroll
    for (int r = 0; r < 8; ++r) acc[r] = binit;
    for (int k = 0; k < D; ++k) {
        float4 w = *(const float4*)&sW[k * D2 + cg * 4];
#pragma unroll
        for (int r = 0; r < 8; ++r) {
            float a = sZ[(rg * 8 + r) * D + k];
            acc[r].x += a * w.x; acc[r].y += a * w.y;
            acc[r].z += a * w.z; acc[r].w += a * w.w;
        }
    }
    float4 s = {0, 0, 0, 0}, sq = {0, 0, 0, 0};
#pragma unroll
    for (int r = 0; r < 8; ++r) {
        int row = rg * 8 + r;
        if (row < nvalid) {
            *(float4*)&t[(row0 + row) * D2 + cg * 4] = acc[r];
            s.x += acc[r].x; s.y += acc[r].y; s.z += acc[r].z; s.w += acc[r].w;
            sq.x += acc[r].x * acc[r].x; sq.y += acc[r].y * acc[r].y;
            sq.z += acc[r].z * acc[r].z; sq.w += acc[r].w * acc[r].w;
        }
    }
    atomicAdd(&sSum[cg * 4 + 0], s.x); atomicAdd(&sSq[cg * 4 + 0], sq.x);
    atomicAdd(&sSum[cg * 4 + 1], s.y); atomicAdd(&sSq[cg * 4 + 1], sq.y);
    atomicAdd(&sSum[cg * 4 + 2], s.z); atomicAdd(&sSq[cg * 4 + 2], sq.z);
    atomicAdd(&sSum[cg * 4 + 3], s.w); atomicAdd(&sSq[cg * 4 + 3], sq.w);
    __syncthreads();
    if (threadIdx.x < D2) {
        atomicAdd(&stats1[threadIdx.x], sSum[threadIdx.x]);
        atomicAdd(&stats1[D2 + threadIdx.x], sSq[threadIdx.x]);
    }
}

// ---------------- GEMM2: z2 = relu(bn(t)) @ W2 + b2 (+ BN stats of z2) ----------------
__global__ __launch_bounds__(256) void k_gemm2(const float* __restrict__ t,
                                               const float* __restrict__ stats1,
                                               const float* __restrict__ W2,
                                               const float* __restrict__ b2, int l,
                                               float* __restrict__ z2,
                                               float* __restrict__ stats2) {
    __shared__ float sT[32 * D2];
    __shared__ float sW[D2 * D];
    __shared__ float sSum[D], sSq[D];
    const float* Wp = W2 + l * D2 * D;
    int row0 = blockIdx.x * 32;
    int nvalid = min(32, NNODES - row0);
    for (int i = threadIdx.x; i < D2 * D; i += 256) sW[i] = Wp[i];
    const float invN = 1.f / NNODES;
    for (int i = threadIdx.x; i < 32 * D2; i += 256) {
        int r = i >> 7, c = i & 127;
        float v = 0.f;
        if (r < nvalid) {
            float mu = stats1[c] * invN;
            float var = stats1[D2 + c] * invN - mu * mu;
            float rstd = rsqrtf(var + BN_EPS);
            v = (t[(row0 + r) * D2 + c] - mu) * rstd + BN_BIAS;
            v = fmaxf(v, 0.f);
        }
        sT[i] = v;
    }
    if (threadIdx.x < D) { sSum[threadIdx.x] = 0.f; sSq[threadIdx.x] = 0.f; }
    __syncthreads();
    int cg = threadIdx.x & 31;
    int rg = threadIdx.x >> 5;
    float2 binit = *(const float2*)&b2[l * D + cg * 2];
    float2 acc[4];
#pragma unroll
    for (int r = 0; r < 4; ++r) acc[r] = binit;
    for (int k = 0; k < D2; ++k) {
        float2 w = *(const float2*)&sW[k * D + cg * 2];
#pragma unroll
        for (int r = 0; r < 4; ++r) {
            float a = sT[(rg * 4 + r) * D2 + k];
            acc[r].x += a * w.x; acc[r].y += a * w.y;
        }
    }
    float2 s = {0, 0}, sq = {0, 0};
#pragma unroll
    for (int r = 0; r < 4; ++r) {
        int row = rg * 4 + r;
        if (row < nvalid) {
            *(float2*)&z2[(row0 + row) * D + cg * 2] = acc[r];
            s.x += acc[r].x; s.y += acc[r].y;
            sq.x += acc[r].x * acc[r].x; sq.y += acc[r].y * acc[r].y;
        }
    }
    atomicAdd(&sSum[cg * 2 + 0], s.x); atomicAdd(&sSq[cg * 2 + 0], sq.x);
    atomicAdd(&sSum[cg * 2 + 1], s.y); atomicAdd(&sSq[cg * 2 + 1], sq.y);
    __syncthreads();
    if (threadIdx.x < D) {
        atomicAdd(&stats2[threadIdx.x], sSum[threadIdx.x]);
        atomicAdd(&stats2[D + threadIdx.x], sSq[threadIdx.x]);
    }
}

// ---------------- fused: hin_next = relu(bn(z2)) + vn[batch] ----------------
__global__ __launch_bounds__(256) void k_bnprep(const float* __restrict__ z2,
                                                const float* __restrict__ stats2,
                                                const float* __restrict__ vn,
                                                const int* __restrict__ batch,
                                                float* __restrict__ hin) {
    int idx = blockIdx.x * 256 + threadIdx.x;
    if (idx >= NNODES * D) return;
    int c = idx & 63, row = idx >> 6;
    const float invN = 1.f / NNODES;
    float mu = stats2[c] * invN;
    float var = stats2[D + c] * invN - mu * mu;
    float rstd = rsqrtf(var + BN_EPS);
    float v = (z2[idx] - mu) * rstd + BN_BIAS;
    v = fmaxf(v, 0.f);
    hin[idx] = v + vn[batch[row] * D + c];
}

// ---------------- fused final: h = bn(z2); node_att ----------------
__global__ __launch_bounds__(256) void k_finish_att(const float* __restrict__ z2,
                                                    const float* __restrict__ stats2,
                                                    const float* __restrict__ Wna,
                                                    const float* __restrict__ bna,
                                                    float* __restrict__ h,
                                                    float* __restrict__ out) {
    int wave = threadIdx.x >> 6, lane = threadIdx.x & 63;
    int row = blockIdx.x * 4 + wave;
    if (row >= NNODES) return;
    const float invN = 1.f / NNODES;
    float mu = stats2[lane] * invN;
    float var = stats2[D + lane] * invN - mu * mu;
    float rstd = rsqrtf(var + BN_EPS);
    float v = (z2[row * D + lane] - mu) * rstd + BN_BIAS;
    h[row * D + lane] = v;
    float s0 = v * Wna[lane * 2 + 0];
    float s1 = v * Wna[lane * 2 + 1];
#pragma unroll
    for (int o = 32; o; o >>= 1) { s0 += __shfl_xor(s0, o); s1 += __shfl_xor(s1, o); }
    if (lane == 0) out[row] = 1.f / (1.f + expf((s0 + bna[0]) - (s1 + bna[1])));
}

// ---------------- vt += segment_sum(hin) over contiguous row chunks ----------------
__global__ __launch_bounds__(256) void k_vt(const float* __restrict__ hin,
                                            const int* __restrict__ batch,
                                            float* __restrict__ vt) {
    int wave = threadIdx.x >> 6, lane = threadIdx.x & 63;
    int wid = blockIdx.x * 4 + wave;
    int r0 = wid * 64;
    if (r0 >= NNODES) return;
    int r1 = min(r0 + 64, NNODES);
    int g = batch[r0];
    float acc = 0.f;
    for (int r = r0; r < r1; ++r) {
        int gb = batch[r];
        if (gb != g) {
            atomicAdd(&vt[g * D + lane], acc);
            acc = 0.f; g = gb;
        }
        acc += hin[r * D + lane];
    }
    atomicAdd(&vt[g * D + lane], acc);
}

// ---------------- virtual-node MLP (one block) ----------------
__global__ __launch_bounds__(256) void k_vnmlp(const float* __restrict__ vt,
                                               const float* __restrict__ Wv1,
                                               const float* __restrict__ bv1,
                                               const float* __restrict__ Wv2,
                                               const float* __restrict__ bv2, int l,
                                               float* __restrict__ vn) {
    __shared__ float sV[NG * D];
    __shared__ float sU[NG * D2];
    const float* W1p = Wv1 + l * D * D2;
    const float* W2p = Wv2 + l * D2 * D;
    for (int i = threadIdx.x; i < NG * D; i += 256) sV[i] = vt[i];
    __syncthreads();
    {
        int r = threadIdx.x >> 2, cb = (threadIdx.x & 3) * 32;
        float acc[32];
#pragma unroll
        for (int c = 0; c < 32; ++c) acc[c] = bv1[l * D2 + cb + c];
        for (int k = 0; k < D; ++k) {
            float v = sV[r * D + k];
#pragma unroll
            for (int c = 0; c < 32; ++c) acc[c] += v * W1p[k * D2 + cb + c];
        }
#pragma unroll
        for (int c = 0; c < 32; ++c) sU[r * D2 + cb + c] = acc[c];
    }
    __syncthreads();
    if (threadIdx.x < D2) {
        int c = threadIdx.x;
        float s = 0, sq = 0;
        for (int r = 0; r < NG; ++r) { float v = sU[r * D2 + c]; s += v; sq += v * v; }
        float mu = s / NG, rstd = rsqrtf(sq / NG - mu * mu + BN_EPS);
        for (int r = 0; r < NG; ++r)
            sU[r * D2 + c] = fmaxf((sU[r * D2 + c] - mu) * rstd + BN_BIAS, 0.f);
    }
    __syncthreads();
    {
        int r = threadIdx.x >> 2, cb = (threadIdx.x & 3) * 16;
        float acc[16];
#pragma unroll
        for (int c = 0; c < 16; ++c) acc[c] = bv2[l * D + cb + c];
        for (int k = 0; k < D2; ++k) {
            float v = sU[r * D2 + k];
#pragma unroll
            for (int c = 0; c < 16; ++c) acc[c] += v * W2p[k * D + cb + c];
        }
#pragma unroll
        for (int c = 0; c < 16; ++c) sV[r * D + cb + c] = acc[c];
    }
    __syncthreads();
    if (threadIdx.x < D) {
        int c = threadIdx.x;
        float s = 0, sq = 0;
        for (int r = 0; r < NG; ++r) { float v = sV[r * D + c]; s += v; sq += v * v; }
        float mu = s / NG, rstd = rsqrtf(sq / NG - mu * mu + BN_EPS);
        for (int r = 0; r < NG; ++r)
            vn[r * D + c] = fmaxf((sV[r * D + c] - mu) * rstd + BN_BIAS, 0.f);
    }
}

// ---------------- edge attention head ----------------
__global__ __launch_bounds__(256) void k_edge_att(const float* __restrict__ h,
                                                  const int* __restrict__ ei,
                                                  const float* __restrict__ Wea,
                                                  const float* __restrict__ bea,
                                                  float* __restrict__ out) {
    int wave = threadIdx.x >> 6, lane = threadIdx.x & 63;
    int e = blockIdx.x * 4 + wave;
    if (e >= NEDGES) return;
    int src = ei[e], dst = ei[NEDGES + e];
    float vs = h[src * D + lane], vd = h[dst * D + lane];
    float s0 = vs * Wea[lane * 2 + 0] + vd * Wea[(D + lane) * 2 + 0];
    float s1 = vs * Wea[lane * 2 + 1] + vd * Wea[(D + lane) * 2 + 1];
#pragma unroll
    for (int o = 32; o; o >>= 1) { s0 += __shfl_xor(s0, o); s1 += __shfl_xor(s1, o); }
    if (lane == 0) out[NNODES + e] = 1.f / (1.f + expf((s0 + bea[0]) - (s1 + bea[1])));
}

extern "C" void kernel_launch(void* const* d_in, const int* in_sizes, int n_in,
                              void* d_out, int out_size, void* d_ws, size_t ws_size,
                              hipStream_t stream) {
    const float* x    = (const float*)d_in[0];
    const float* ea   = (const float*)d_in[1];
    const int*   ei   = (const int*)d_in[2];
    const int*   batch= (const int*)d_in[3];
    const float* Wenc = (const float*)d_in[4];
    const float* benc = (const float*)d_in[5];
    const float* We   = (const float*)d_in[6];
    const float* be   = (const float*)d_in[7];
    const float* eps  = (const float*)d_in[8];
    const float* W1   = (const float*)d_in[9];
    const float* b1   = (const float*)d_in[10];
    const float* W2   = (const float*)d_in[11];
    const float* b2   = (const float*)d_in[12];
    const float* Wv1  = (const float*)d_in[13];
    const float* bv1  = (const float*)d_in[14];
    const float* Wv2  = (const float*)d_in[15];
    const float* bv2  = (const float*)d_in[16];
    const float* Wea  = (const float*)d_in[17];
    const float* bea  = (const float*)d_in[18];
    const float* Wna  = (const float*)d_in[19];
    const float* bna  = (const float*)d_in[20];
    float* out = (float*)d_out;

    float* ws  = (float*)d_ws;
    float* h    = ws;
    float* hin  = h   + (size_t)NNODES * D;
    float* zin  = hin + (size_t)NNODES * D;
    float* t    = zin + (size_t)NNODES * D;
    float* z2   = t   + (size_t)NNODES * D2;
    float* vn   = z2  + (size_t)NNODES * D;
    float* vt   = vn  + NG * D;
    float* stats= vt  + NG * D;           // [128 sum][128 sq] | [64 sum][64 sq]
    int*   deg    = (int*)(stats + 512);
    int*   off    = deg + NNODES;
    int*   cursor = off + NNODES + 1;
    int*   epos   = cursor + NNODES;
    int*   esrc   = epos + NEDGES;

    float* stats2 = stats + 256;

    // init + CSR build (once; reused by all 3 layers)
    hipMemsetAsync(vn, 0, NG * D * sizeof(float), stream);
    hipMemsetAsync(deg, 0, NNODES * sizeof(int), stream);
    k_enc<<<NNODES / 4, 256, 0, stream>>>(x, Wenc, benc, h);
    k_hist<<<(NEDGES + 255) / 256, 256, 0, stream>>>(ei, deg);
    k_scan<<<1, SCAN_T, 0, stream>>>(deg, off, cursor);
    k_scatter<<<(NEDGES + 255) / 256, 256, 0, stream>>>(ei, cursor, epos, esrc);

    for (int l = 0; l < 3; ++l) {
        const float* hin_l = (l == 0) ? h : hin;
        if (l < 2) {
            // vt = segsum(hin_l) + vn ; vn = MLP(vt)   (uses OLD vn; safe to run first)
            hipMemcpyAsync(vt, vn, NG * D * sizeof(float), hipMemcpyDeviceToDevice, stream);
            k_vt<<<(NNODES / 64 + 4) / 4, 256, 0, stream>>>(hin_l, batch, vt);
        }
        hipMemsetAsync(stats, 0, 384 * sizeof(float), stream);
        k_agg<<<(NNODES + 3) / 4, 256, 0, stream>>>(ea, off, epos, esrc, We, be, eps, l, hin_l, zin);
        if (l < 2) k_vnmlp<<<1, 256, 0, stream>>>(vt, Wv1, bv1, Wv2, bv2, l, vn);
        k_gemm1<<<(NNODES + 63) / 64, 256, 0, stream>>>(zin, W1, b1, l, t, stats);
        k_gemm2<<<(NNODES + 31) / 32, 256, 0, stream>>>(t, stats, W2, b2, l, z2, stats2);
        if (l < 2) {
            k_bnprep<<<NNODES * D / 256, 256, 0, stream>>>(z2, stats2, vn, batch, hin);
        } else {
            k_finish_att<<<NNODES / 4, 256, 0, stream>>>(z2, stats2, Wna, bna, h, out);
        }
    }
    k_edge_att<<<NEDGES / 4, 256, 0, stream>>>(h, ei, Wea, bea, out);
}

// Round 3
// 1232.024 us; speedup vs baseline: 1.1579x; 1.1211x over previous
//
#include <hip/hip_runtime.h>
#include <hip/hip_bf16.h>

#define NNODES 50000
#define NEDGES 800000
#define NG 64
#define D 64
#define D2 128
#define INDIM 39
#define EDIM 10
#define BN_EPS 1e-5f
#define BN_BIAS 1e-4f

// ---------------- encoder: h = x @ Wenc + benc (+ bf16 shadow) ----------------
__global__ __launch_bounds__(256) void k_enc(const float* __restrict__ x,
                                             const float* __restrict__ Wenc,
                                             const float* __restrict__ benc,
                                             float* __restrict__ h,
                                             __hip_bfloat16* __restrict__ hbf) {
    __shared__ float sW[INDIM * D];
    for (int i = threadIdx.x; i < INDIM * D; i += 256) sW[i] = Wenc[i];
    __syncthreads();
    int wave = threadIdx.x >> 6, lane = threadIdx.x & 63;
    int row = blockIdx.x * 4 + wave;
    if (row >= NNODES) return;
    float xv = (lane < INDIM) ? x[row * INDIM + lane] : 0.f;
    float acc = benc[lane];
#pragma unroll
    for (int k = 0; k < INDIM; ++k) acc += __shfl(xv, k) * sW[k * D + lane];
    h[row * D + lane] = acc;
    hbf[row * D + lane] = __float2bfloat16(acc);
}

// ---------------- CSR build ----------------
__global__ __launch_bounds__(256) void k_hist(const int* __restrict__ ei,
                                              int* __restrict__ deg) {
    int e = blockIdx.x * 256 + threadIdx.x;
    if (e < NEDGES) atomicAdd(&deg[ei[NEDGES + e]], 1);
}

#define SCAN_T 1024
#define SCAN_C 49  // 1024*49 >= 50000
__global__ __launch_bounds__(SCAN_T) void k_scan(const int* __restrict__ deg,
                                                 int* __restrict__ off,
                                                 int* __restrict__ cursor) {
    __shared__ int part[SCAN_T];
    int t = threadIdx.x;
    int c0 = min(t * SCAN_C, NNODES), c1 = min(c0 + SCAN_C, NNODES);
    int s = 0;
    for (int i = c0; i < c1; ++i) s += deg[i];
    part[t] = s;
    __syncthreads();
    for (int o = 1; o < SCAN_T; o <<= 1) {
        int v = (t >= o) ? part[t - o] : 0;
        __syncthreads();
        part[t] += v;
        __syncthreads();
    }
    int run = (t == 0) ? 0 : part[t - 1];
    for (int i = c0; i < c1; ++i) {
        off[i] = run; cursor[i] = run; run += deg[i];
    }
    if (t == SCAN_T - 1) off[NNODES] = run;
}

__global__ __launch_bounds__(256) void k_scatter(const int* __restrict__ ei,
                                                 int* __restrict__ cursor,
                                                 int* __restrict__ epos,
                                                 int* __restrict__ esrc) {
    int e = blockIdx.x * 256 + threadIdx.x;
    if (e >= NEDGES) return;
    int d = ei[NEDGES + e];
    int p = atomicAdd(&cursor[d], 1);
    epos[p] = e;
    esrc[p] = ei[e];
}

// ---------------- aggregate: zin[n] = (1+eps)*hin[n] + sum relu(hbf[src]+eemb) ----------------
__global__ __launch_bounds__(256) void k_agg(const float* __restrict__ ea,
                                             const int* __restrict__ off,
                                             const int* __restrict__ epos,
                                             const int* __restrict__ esrc,
                                             const float* __restrict__ We,
                                             const float* __restrict__ be,
                                             const float* __restrict__ eps, int l,
                                             const float* __restrict__ hin,
                                             const __hip_bfloat16* __restrict__ hbf,
                                             float* __restrict__ zin) {
    __shared__ float sW[EDIM * D];
    __shared__ float sb[D];
    const float* Wl = We + l * EDIM * D;
    for (int i = threadIdx.x; i < EDIM * D; i += 256) sW[i] = Wl[i];
    if (threadIdx.x < D) sb[threadIdx.x] = be[l * D + threadIdx.x];
    __syncthreads();
    int wave = threadIdx.x >> 6, lane = threadIdx.x & 63;
    int n = blockIdx.x * 4 + wave;
    if (n >= NNODES) return;
    int beg = off[n], end = off[n + 1];
    float acc = (1.f + eps[l]) * hin[n * D + lane];
    float bias = sb[lane];
    for (int j = beg; j < end; ++j) {
        int e = epos[j], src = esrc[j];
        float eav = (lane < EDIM) ? ea[e * EDIM + lane] : 0.f;
        float hv = __bfloat162float(hbf[src * D + lane]);
        float m = bias;
#pragma unroll
        for (int k = 0; k < EDIM; ++k) m += __shfl(eav, k) * sW[k * D + lane];
        acc += fmaxf(m + hv, 0.f);
    }
    zin[n * D + lane] = acc;
}

// ---------------- GEMM1: t = zin @ W1 + b1 (+ BN stats of t) ----------------
__global__ __launch_bounds__(256) void k_gemm1(const float* __restrict__ zin,
                                               const float* __restrict__ W1,
                                               const float* __restrict__ b1, int l,
                                               float* __restrict__ t,
                                               float* __restrict__ stats1) {
    __shared__ float sZ[64 * D];
    __shared__ float sW[D * D2];
    __shared__ float sSum[D2], sSq[D2];
    const float* Wp = W1 + l * D * D2;
    int row0 = blockIdx.x * 64;
    int nvalid = min(64, NNODES - row0);
    for (int i = threadIdx.x; i < D * D2; i += 256) sW[i] = Wp[i];
    for (int i = threadIdx.x; i < 64 * D; i += 256) {
        int r = i >> 6;
        sZ[i] = (r < nvalid) ? zin[(row0 + r) * D + (i & 63)] : 0.f;
    }
    if (threadIdx.x < D2) { sSum[threadIdx.x] = 0.f; sSq[threadIdx.x] = 0.f; }
    __syncthreads();
    int cg = threadIdx.x & 31;
    int rg = threadIdx.x >> 5;
    float4 binit = *(const float4*)&b1[l * D2 + cg * 4];
    float4 acc[8];
#pragma unroll
    for (int r = 0; r < 8; ++r) acc[r] = binit;
    for (int k = 0; k < D; ++k) {
        float4 w = *(const float4*)&sW[k * D2 + cg * 4];
#pragma unroll
        for (int r = 0; r < 8; ++r) {
            float a = sZ[(rg * 8 + r) * D + k];
            acc[r].x += a * w.x; acc[r].y += a * w.y;
            acc[r].z += a * w.z; acc[r].w += a * w.w;
        }
    }
    float4 s = {0, 0, 0, 0}, sq = {0, 0, 0, 0};
#pragma unroll
    for (int r = 0; r < 8; ++r) {
        int row = rg * 8 + r;
        if (row < nvalid) {
            *(float4*)&t[(row0 + row) * D2 + cg * 4] = acc[r];
            s.x += acc[r].x; s.y += acc[r].y; s.z += acc[r].z; s.w += acc[r].w;
            sq.x += acc[r].x * acc[r].x; sq.y += acc[r].y * acc[r].y;
            sq.z += acc[r].z * acc[r].z; sq.w += acc[r].w * acc[r].w;
        }
    }
    atomicAdd(&sSum[cg * 4 + 0], s.x); atomicAdd(&sSq[cg * 4 + 0], sq.x);
    atomicAdd(&sSum[cg * 4 + 1], s.y); atomicAdd(&sSq[cg * 4 + 1], sq.y);
    atomicAdd(&sSum[cg * 4 + 2], s.z); atomicAdd(&sSq[cg * 4 + 2], sq.z);
    atomicAdd(&sSum[cg * 4 + 3], s.w); atomicAdd(&sSq[cg * 4 + 3], sq.w);
    __syncthreads();
    if (threadIdx.x < D2) {
        atomicAdd(&stats1[threadIdx.x], sSum[threadIdx.x]);
        atomicAdd(&stats1[D2 + threadIdx.x], sSq[threadIdx.x]);
    }
}

// ---------------- GEMM2: z2 = relu(bn(t)) @ W2 + b2 (+ BN stats of z2) ----------------
__global__ __launch_bounds__(256) void k_gemm2(const float* __restrict__ t,
                                               const float* __restrict__ stats1,
                                               const float* __restrict__ W2,
                                               const float* __restrict__ b2, int l,
                                               float* __restrict__ z2,
                                               float* __restrict__ stats2) {
    __shared__ float sT[32 * D2];
    __shared__ float sW[D2 * D];
    __shared__ float sSum[D], sSq[D];
    const float* Wp = W2 + l * D2 * D;
    int row0 = blockIdx.x * 32;
    int nvalid = min(32, NNODES - row0);
    for (int i = threadIdx.x; i < D2 * D; i += 256) sW[i] = Wp[i];
    const float invN = 1.f / NNODES;
    for (int i = threadIdx.x; i < 32 * D2; i += 256) {
        int r = i >> 7, c = i & 127;
        float v = 0.f;
        if (r < nvalid) {
            float mu = stats1[c] * invN;
            float var = stats1[D2 + c] * invN - mu * mu;
            float rstd = rsqrtf(var + BN_EPS);
            v = (t[(row0 + r) * D2 + c] - mu) * rstd + BN_BIAS;
            v = fmaxf(v, 0.f);
        }
        sT[i] = v;
    }
    if (threadIdx.x < D) { sSum[threadIdx.x] = 0.f; sSq[threadIdx.x] = 0.f; }
    __syncthreads();
    int cg = threadIdx.x & 31;
    int rg = threadIdx.x >> 5;
    float2 binit = *(const float2*)&b2[l * D + cg * 2];
    float2 acc[4];
#pragma unroll
    for (int r = 0; r < 4; ++r) acc[r] = binit;
    for (int k = 0; k < D2; ++k) {
        float2 w = *(const float2*)&sW[k * D + cg * 2];
#pragma unroll
        for (int r = 0; r < 4; ++r) {
            float a = sT[(rg * 4 + r) * D2 + k];
            acc[r].x += a * w.x; acc[r].y += a * w.y;
        }
    }
    float2 s = {0, 0}, sq = {0, 0};
#pragma unroll
    for (int r = 0; r < 4; ++r) {
        int row = rg * 4 + r;
        if (row < nvalid) {
            *(float2*)&z2[(row0 + row) * D + cg * 2] = acc[r];
            s.x += acc[r].x; s.y += acc[r].y;
            sq.x += acc[r].x * acc[r].x; sq.y += acc[r].y * acc[r].y;
        }
    }
    atomicAdd(&sSum[cg * 2 + 0], s.x); atomicAdd(&sSq[cg * 2 + 0], sq.x);
    atomicAdd(&sSum[cg * 2 + 1], s.y); atomicAdd(&sSq[cg * 2 + 1], sq.y);
    __syncthreads();
    if (threadIdx.x < D) {
        atomicAdd(&stats2[threadIdx.x], sSum[threadIdx.x]);
        atomicAdd(&stats2[D + threadIdx.x], sSq[threadIdx.x]);
    }
}

// ---------------- fused: hin_next = relu(bn(z2)) + vn[batch] (+ bf16 shadow) ----------------
__global__ __launch_bounds__(256) void k_bnprep(const float* __restrict__ z2,
                                                const float* __restrict__ stats2,
                                                const float* __restrict__ vn,
                                                const int* __restrict__ batch,
                                                float* __restrict__ hin,
                                                __hip_bfloat16* __restrict__ hbf) {
    int idx = blockIdx.x * 256 + threadIdx.x;
    if (idx >= NNODES * D) return;
    int c = idx & 63, row = idx >> 6;
    const float invN = 1.f / NNODES;
    float mu = stats2[c] * invN;
    float var = stats2[D + c] * invN - mu * mu;
    float rstd = rsqrtf(var + BN_EPS);
    float v = (z2[idx] - mu) * rstd + BN_BIAS;
    v = fmaxf(v, 0.f);
    v += vn[batch[row] * D + c];
    hin[idx] = v;
    hbf[idx] = __float2bfloat16(v);
}

// ---------------- fused final: bn(z2) -> node att + per-node edge projections ----------------
__global__ __launch_bounds__(256) void k_finish_att_proj(const float* __restrict__ z2,
                                                         const float* __restrict__ stats2,
                                                         const float* __restrict__ Wna,
                                                         const float* __restrict__ bna,
                                                         const float* __restrict__ Wea,
                                                         float* __restrict__ proj,
                                                         float* __restrict__ out) {
    int wave = threadIdx.x >> 6, lane = threadIdx.x & 63;
    int row = blockIdx.x * 4 + wave;
    if (row >= NNODES) return;
    const float invN = 1.f / NNODES;
    float mu = stats2[lane] * invN;
    float var = stats2[D + lane] * invN - mu * mu;
    float rstd = rsqrtf(var + BN_EPS);
    float v = (z2[row * D + lane] - mu) * rstd + BN_BIAS;
    float n0 = v * Wna[lane * 2 + 0];
    float n1 = v * Wna[lane * 2 + 1];
    float pa0 = v * Wea[lane * 2 + 0];
    float pa1 = v * Wea[lane * 2 + 1];
    float pb0 = v * Wea[(D + lane) * 2 + 0];
    float pb1 = v * Wea[(D + lane) * 2 + 1];
#pragma unroll
    for (int o = 32; o; o >>= 1) {
        n0 += __shfl_xor(n0, o); n1 += __shfl_xor(n1, o);
        pa0 += __shfl_xor(pa0, o); pa1 += __shfl_xor(pa1, o);
        pb0 += __shfl_xor(pb0, o); pb1 += __shfl_xor(pb1, o);
    }
    if (lane == 0) {
        out[row] = 1.f / (1.f + expf((n0 + bna[0]) - (n1 + bna[1])));
        proj[row * 4 + 0] = pa0;
        proj[row * 4 + 1] = pa1;
        proj[row * 4 + 2] = pb0;
        proj[row * 4 + 3] = pb1;
    }
}

// ---------------- edge attention from projection tables ----------------
__global__ __launch_bounds__(256) void k_edge_final(const int* __restrict__ ei,
                                                    const float* __restrict__ proj,
                                                    const float* __restrict__ bea,
                                                    float* __restrict__ out) {
    int e = blockIdx.x * 256 + threadIdx.x;
    if (e >= NEDGES) return;
    int src = ei[e], dst = ei[NEDGES + e];
    float4 ps = *(const float4*)&proj[src * 4];
    float4 pd = *(const float4*)&proj[dst * 4];
    float s0 = ps.x + pd.z + bea[0];
    float s1 = ps.y + pd.w + bea[1];
    out[NNODES + e] = 1.f / (1.f + expf(s0 - s1));
}

// ---------------- vt += segment_sum(hin) over contiguous row chunks ----------------
__global__ __launch_bounds__(256) void k_vt(const float* __restrict__ hin,
                                            const int* __restrict__ batch,
                                            float* __restrict__ vt) {
    int wave = threadIdx.x >> 6, lane = threadIdx.x & 63;
    int wid = blockIdx.x * 4 + wave;
    int r0 = wid * 64;
    if (r0 >= NNODES) return;
    int r1 = min(r0 + 64, NNODES);
    int g = batch[r0];
    float acc = 0.f;
    for (int r = r0; r < r1; ++r) {
        int gb = batch[r];
        if (gb != g) {
            atomicAdd(&vt[g * D + lane], acc);
            acc = 0.f; g = gb;
        }
        acc += hin[r * D + lane];
    }
    atomicAdd(&vt[g * D + lane], acc);
}

// ---------------- virtual-node MLP (one block) ----------------
__global__ __launch_bounds__(256) void k_vnmlp(const float* __restrict__ vt,
                                               const float* __restrict__ Wv1,
                                               const float* __restrict__ bv1,
                                               const float* __restrict__ Wv2,
                                               const float* __restrict__ bv2, int l,
                                               float* __restrict__ vn) {
    __shared__ float sV[NG * D];
    __shared__ float sU[NG * D2];
    const float* W1p = Wv1 + l * D * D2;
    const float* W2p = Wv2 + l * D2 * D;
    for (int i = threadIdx.x; i < NG * D; i += 256) sV[i] = vt[i];
    __syncthreads();
    {
        int r = threadIdx.x >> 2, cb = (threadIdx.x & 3) * 32;
        float acc[32];
#pragma unroll
        for (int c = 0; c < 32; ++c) acc[c] = bv1[l * D2 + cb + c];
        for (int k = 0; k < D; ++k) {
            float v = sV[r * D + k];
#pragma unroll
            for (int c = 0; c < 32; ++c) acc[c] += v * W1p[k * D2 + cb + c];
        }
#pragma unroll
        for (int c = 0; c < 32; ++c) sU[r * D2 + cb + c] = acc[c];
    }
    __syncthreads();
    if (threadIdx.x < D2) {
        int c = threadIdx.x;
        float s = 0, sq = 0;
        for (int r = 0; r < NG; ++r) { float v = sU[r * D2 + c]; s += v; sq += v * v; }
        float mu = s / NG, rstd = rsqrtf(sq / NG - mu * mu + BN_EPS);
        for (int r = 0; r < NG; ++r)
            sU[r * D2 + c] = fmaxf((sU[r * D2 + c] - mu) * rstd + BN_BIAS, 0.f);
    }
    __syncthreads();
    {
        int r = threadIdx.x >> 2, cb = (threadIdx.x & 3) * 16;
        float acc[16];
#pragma unroll
        for (int c = 0; c < 16; ++c) acc[c] = bv2[l * D + cb + c];
        for (int k = 0; k < D2; ++k) {
            float v = sU[r * D2 + k];
#pragma unroll
            for (int c = 0; c < 16; ++c) acc[c] += v * W2p[k * D + cb + c];
        }
#pragma unroll
        for (int c = 0; c < 16; ++c) sV[r * D + cb + c] = acc[c];
    }
    __syncthreads();
    if (threadIdx.x < D) {
        int c = threadIdx.x;
        float s = 0, sq = 0;
        for (int r = 0; r < NG; ++r) { float v = sV[r * D + c]; s += v; sq += v * v; }
        float mu = s / NG, rstd = rsqrtf(sq / NG - mu * mu + BN_EPS);
        for (int r = 0; r < NG; ++r)
            vn[r * D + c] = fmaxf((sV[r * D + c] - mu) * rstd + BN_BIAS, 0.f);
    }
}

extern "C" void kernel_launch(void* const* d_in, const int* in_sizes, int n_in,
                              void* d_out, int out_size, void* d_ws, size_t ws_size,
                              hipStream_t stream) {
    const float* x    = (const float*)d_in[0];
    const float* ea   = (const float*)d_in[1];
    const int*   ei   = (const int*)d_in[2];
    const int*   batch= (const int*)d_in[3];
    const float* Wenc = (const float*)d_in[4];
    const float* benc = (const float*)d_in[5];
    const float* We   = (const float*)d_in[6];
    const float* be   = (const float*)d_in[7];
    const float* eps  = (const float*)d_in[8];
    const float* W1   = (const float*)d_in[9];
    const float* b1   = (const float*)d_in[10];
    const float* W2   = (const float*)d_in[11];
    const float* b2   = (const float*)d_in[12];
    const float* Wv1  = (const float*)d_in[13];
    const float* bv1  = (const float*)d_in[14];
    const float* Wv2  = (const float*)d_in[15];
    const float* bv2  = (const float*)d_in[16];
    const float* Wea  = (const float*)d_in[17];
    const float* bea  = (const float*)d_in[18];
    const float* Wna  = (const float*)d_in[19];
    const float* bna  = (const float*)d_in[20];
    float* out = (float*)d_out;

    float* ws  = (float*)d_ws;
    float* h    = ws;                              // [N*D]
    float* hin  = h   + (size_t)NNODES * D;        // [N*D]
    float* zin  = hin + (size_t)NNODES * D;        // [N*D]  (z2 overlays zin)
    float* t    = zin + (size_t)NNODES * D;        // [N*D2]
    float* vn   = t   + (size_t)NNODES * D2;       // [NG*D]
    float* vt   = vn  + NG * D;                    // [NG*D]
    float* stats= vt  + NG * D;                    // 512
    float* proj = stats + 512;                     // [N*4]
    __hip_bfloat16* hbf = (__hip_bfloat16*)(proj + (size_t)NNODES * 4);  // [N*D] bf16
    int*   deg    = (int*)(hbf + (size_t)NNODES * D);
    int*   off    = deg + NNODES;
    int*   cursor = off + NNODES + 1;
    int*   epos   = cursor + NNODES;
    int*   esrc   = epos + NEDGES;

    float* z2     = zin;         // overlay: zin dead after gemm1
    float* stats2 = stats + 256;

    // init + CSR build (reused by all 3 layers)
    hipMemsetAsync(vn, 0, NG * D * sizeof(float), stream);
    hipMemsetAsync(deg, 0, NNODES * sizeof(int), stream);
    k_enc<<<NNODES / 4, 256, 0, stream>>>(x, Wenc, benc, h, hbf);
    k_hist<<<(NEDGES + 255) / 256, 256, 0, stream>>>(ei, deg);
    k_scan<<<1, SCAN_T, 0, stream>>>(deg, off, cursor);
    k_scatter<<<(NEDGES + 255) / 256, 256, 0, stream>>>(ei, cursor, epos, esrc);

    for (int l = 0; l < 3; ++l) {
        const float* hin_l = (l == 0) ? h : hin;
        if (l < 2) {
            hipMemcpyAsync(vt, vn, NG * D * sizeof(float), hipMemcpyDeviceToDevice, stream);
            k_vt<<<(NNODES / 64 + 4) / 4, 256, 0, stream>>>(hin_l, batch, vt);
        }
        hipMemsetAsync(stats, 0, 384 * sizeof(float), stream);
        k_agg<<<(NNODES + 3) / 4, 256, 0, stream>>>(ea, off, epos, esrc, We, be, eps, l,
                                                    hin_l, hbf, zin);
        if (l < 2) k_vnmlp<<<1, 256, 0, stream>>>(vt, Wv1, bv1, Wv2, bv2, l, vn);
        k_gemm1<<<(NNODES + 63) / 64, 256, 0, stream>>>(zin, W1, b1, l, t, stats);
        k_gemm2<<<(NNODES + 31) / 32, 256, 0, stream>>>(t, stats, W2, b2, l, z2, stats2);
        if (l < 2) {
            k_bnprep<<<NNODES * D / 256, 256, 0, stream>>>(z2, stats2, vn, batch, hin, hbf);
        } else {
            k_finish_att_proj<<<NNODES / 4, 256, 0, stream>>>(z2, stats2, Wna, bna, Wea,
                                                              proj, out);
        }
    }
    k_edge_final<<<(NEDGES + 255) / 256, 256, 0, stream>>>(ei, proj, bea, out);
}

// Round 4
// 1150.173 us; speedup vs baseline: 1.2403x; 1.0712x over previous
//
#include <hip/hip_runtime.h>
#include <hip/hip_bf16.h>

#define NNODES 50000
#define NEDGES 800000
#define NG 64
#define D 64
#define D2 128
#define INDIM 39
#define EDIM 10
#define BN_EPS 1e-5f
#define BN_BIAS 1e-4f

// ---------------- encoder: h = x @ Wenc + benc (+ bf16 shadow) ----------------
__global__ __launch_bounds__(256) void k_enc(const float* __restrict__ x,
                                             const float* __restrict__ Wenc,
                                             const float* __restrict__ benc,
                                             float* __restrict__ h,
                                             __hip_bfloat16* __restrict__ hbf) {
    __shared__ float sW[INDIM * D];
    for (int i = threadIdx.x; i < INDIM * D; i += 256) sW[i] = Wenc[i];
    __syncthreads();
    int wave = threadIdx.x >> 6, lane = threadIdx.x & 63;
    int row = blockIdx.x * 4 + wave;
    if (row >= NNODES) return;
    float xv = (lane < INDIM) ? x[row * INDIM + lane] : 0.f;
    float acc = benc[lane];
#pragma unroll
    for (int k = 0; k < INDIM; ++k) acc += __shfl(xv, k) * sW[k * D + lane];
    h[row * D + lane] = acc;
    hbf[row * D + lane] = __float2bfloat16(acc);
}

// ---------------- CSR build ----------------
__global__ __launch_bounds__(256) void k_hist(const int* __restrict__ ei,
                                              int* __restrict__ deg) {
    int e = blockIdx.x * 256 + threadIdx.x;
    if (e < NEDGES) atomicAdd(&deg[ei[NEDGES + e]], 1);
}

#define SCAN_T 1024
#define SCAN_C 49  // 1024*49 >= 50000
__global__ __launch_bounds__(SCAN_T) void k_scan(const int* __restrict__ deg,
                                                 int* __restrict__ off,
                                                 int* __restrict__ cursor) {
    __shared__ int part[SCAN_T];
    int t = threadIdx.x;
    int c0 = min(t * SCAN_C, NNODES), c1 = min(c0 + SCAN_C, NNODES);
    int s = 0;
    for (int i = c0; i < c1; ++i) s += deg[i];
    part[t] = s;
    __syncthreads();
    for (int o = 1; o < SCAN_T; o <<= 1) {
        int v = (t >= o) ? part[t - o] : 0;
        __syncthreads();
        part[t] += v;
        __syncthreads();
    }
    int run = (t == 0) ? 0 : part[t - 1];
    for (int i = c0; i < c1; ++i) {
        off[i] = run; cursor[i] = run; run += deg[i];
    }
    if (t == SCAN_T - 1) off[NNODES] = run;
}

// scatter src index AND edge_attr (bf16) into CSR order
__global__ __launch_bounds__(256) void k_scatter(const int* __restrict__ ei,
                                                 const float* __restrict__ ea,
                                                 int* __restrict__ cursor,
                                                 int* __restrict__ esrc,
                                                 __hip_bfloat16* __restrict__ ea_s) {
    int e = blockIdx.x * 256 + threadIdx.x;
    if (e >= NEDGES) return;
    int d = ei[NEDGES + e];
    int p = atomicAdd(&cursor[d], 1);
    esrc[p] = ei[e];
    float v[EDIM];
#pragma unroll
    for (int i = 0; i < EDIM; ++i) v[i] = ea[e * EDIM + i];
    unsigned int* dst = (unsigned int*)(ea_s + (size_t)p * EDIM);
#pragma unroll
    for (int i = 0; i < 5; ++i) {
        __hip_bfloat16 b0 = __float2bfloat16(v[2 * i]);
        __hip_bfloat16 b1 = __float2bfloat16(v[2 * i + 1]);
        unsigned int u = ((unsigned int)*(unsigned short*)&b1 << 16) |
                         (unsigned int)*(unsigned short*)&b0;
        dst[i] = u;
    }
}

// ---------------- aggregate: zin[n] = (1+eps)*hin[n] + sum relu(hbf[src]+eemb) ----------------
__global__ __launch_bounds__(256) void k_agg(const __hip_bfloat16* __restrict__ ea_s,
                                             const int* __restrict__ off,
                                             const int* __restrict__ esrc,
                                             const float* __restrict__ We,
                                             const float* __restrict__ be,
                                             const float* __restrict__ eps, int l,
                                             const float* __restrict__ hin,
                                             const __hip_bfloat16* __restrict__ hbf,
                                             float* __restrict__ zin) {
    __shared__ float sW[EDIM * D];
    __shared__ float sb[D];
    const float* Wl = We + l * EDIM * D;
    for (int i = threadIdx.x; i < EDIM * D; i += 256) sW[i] = Wl[i];
    if (threadIdx.x < D) sb[threadIdx.x] = be[l * D + threadIdx.x];
    __syncthreads();
    int wave = threadIdx.x >> 6, lane = threadIdx.x & 63;
    int n = blockIdx.x * 4 + wave;
    if (n >= NNODES) return;
    int beg = off[n], end = off[n + 1];
    float acc = (1.f + eps[l]) * hin[n * D + lane];
    float bias = sb[lane];
    int j = beg;
    for (; j + 3 < end; j += 4) {
        int s0 = esrc[j], s1 = esrc[j + 1], s2 = esrc[j + 2], s3 = esrc[j + 3];
        float hv0 = __bfloat162float(hbf[(size_t)s0 * D + lane]);
        float hv1 = __bfloat162float(hbf[(size_t)s1 * D + lane]);
        float hv2 = __bfloat162float(hbf[(size_t)s2 * D + lane]);
        float hv3 = __bfloat162float(hbf[(size_t)s3 * D + lane]);
        float ev0 = (lane < EDIM) ? __bfloat162float(ea_s[(size_t)j * EDIM + lane]) : 0.f;
        float ev1 = (lane < EDIM) ? __bfloat162float(ea_s[(size_t)(j + 1) * EDIM + lane]) : 0.f;
        float ev2 = (lane < EDIM) ? __bfloat162float(ea_s[(size_t)(j + 2) * EDIM + lane]) : 0.f;
        float ev3 = (lane < EDIM) ? __bfloat162float(ea_s[(size_t)(j + 3) * EDIM + lane]) : 0.f;
        float m0 = bias, m1 = bias, m2 = bias, m3 = bias;
#pragma unroll
        for (int k = 0; k < EDIM; ++k) {
            float w = sW[k * D + lane];
            m0 += __shfl(ev0, k) * w;
            m1 += __shfl(ev1, k) * w;
            m2 += __shfl(ev2, k) * w;
            m3 += __shfl(ev3, k) * w;
        }
        acc += fmaxf(m0 + hv0, 0.f) + fmaxf(m1 + hv1, 0.f) +
               fmaxf(m2 + hv2, 0.f) + fmaxf(m3 + hv3, 0.f);
    }
    for (; j < end; ++j) {
        int src = esrc[j];
        float hv = __bfloat162float(hbf[(size_t)src * D + lane]);
        float ev = (lane < EDIM) ? __bfloat162float(ea_s[(size_t)j * EDIM + lane]) : 0.f;
        float m = bias;
#pragma unroll
        for (int k = 0; k < EDIM; ++k) m += __shfl(ev, k) * sW[k * D + lane];
        acc += fmaxf(m + hv, 0.f);
    }
    zin[n * D + lane] = acc;
}

// ---------------- GEMM1: t = zin @ W1 + b1 (+ BN stats of t) ----------------
__global__ __launch_bounds__(256) void k_gemm1(const float* __restrict__ zin,
                                               const float* __restrict__ W1,
                                               const float* __restrict__ b1, int l,
                                               float* __restrict__ t,
                                               float* __restrict__ stats1) {
    __shared__ float sZ[64 * D];
    __shared__ float sW[D * D2];
    __shared__ float sSum[D2], sSq[D2];
    const float* Wp = W1 + l * D * D2;
    int row0 = blockIdx.x * 64;
    int nvalid = min(64, NNODES - row0);
    for (int i = threadIdx.x; i < D * D2; i += 256) sW[i] = Wp[i];
    for (int i = threadIdx.x; i < 64 * D; i += 256) {
        int r = i >> 6;
        sZ[i] = (r < nvalid) ? zin[(row0 + r) * D + (i & 63)] : 0.f;
    }
    if (threadIdx.x < D2) { sSum[threadIdx.x] = 0.f; sSq[threadIdx.x] = 0.f; }
    __syncthreads();
    int cg = threadIdx.x & 31;
    int rg = threadIdx.x >> 5;
    float4 binit = *(const float4*)&b1[l * D2 + cg * 4];
    float4 acc[8];
#pragma unroll
    for (int r = 0; r < 8; ++r) acc[r] = binit;
    for (int k = 0; k < D; ++k) {
        float4 w = *(const float4*)&sW[k * D2 + cg * 4];
#pragma unroll
        for (int r = 0; r < 8; ++r) {
            float a = sZ[(rg * 8 + r) * D + k];
            acc[r].x += a * w.x; acc[r].y += a * w.y;
            acc[r].z += a * w.z; acc[r].w += a * w.w;
        }
    }
    float4 s = {0, 0, 0, 0}, sq = {0, 0, 0, 0};
#pragma unroll
    for (int r = 0; r < 8; ++r) {
        int row = rg * 8 + r;
        if (row < nvalid) {
            *(float4*)&t[(row0 + row) * D2 + cg * 4] = acc[r];
            s.x += acc[r].x; s.y += acc[r].y; s.z += acc[r].z; s.w += acc[r].w;
            sq.x += acc[r].x * acc[r].x; sq.y += acc[r].y * acc[r].y;
            sq.z += acc[r].z * acc[r].z; sq.w += acc[r].w * acc[r].w;
        }
    }
    atomicAdd(&sSum[cg * 4 + 0], s.x); atomicAdd(&sSq[cg * 4 + 0], sq.x);
    atomicAdd(&sSum[cg * 4 + 1], s.y); atomicAdd(&sSq[cg * 4 + 1], sq.y);
    atomicAdd(&sSum[cg * 4 + 2], s.z); atomicAdd(&sSq[cg * 4 + 2], sq.z);
    atomicAdd(&sSum[cg * 4 + 3], s.w); atomicAdd(&sSq[cg * 4 + 3], sq.w);
    __syncthreads();
    if (threadIdx.x < D2) {
        atomicAdd(&stats1[threadIdx.x], sSum[threadIdx.x]);
        atomicAdd(&stats1[D2 + threadIdx.x], sSq[threadIdx.x]);
    }
}

// ---------------- GEMM2: z2 = relu(bn(t)) @ W2 + b2 (+ BN stats of z2) ----------------
__global__ __launch_bounds__(256) void k_gemm2(const float* __restrict__ t,
                                               const float* __restrict__ stats1,
                                               const float* __restrict__ W2,
                                               const float* __restrict__ b2, int l,
                                               float* __restrict__ z2,
                                               float* __restrict__ stats2) {
    __shared__ float sT[32 * D2];
    __shared__ float sW[D2 * D];
    __shared__ float sSum[D], sSq[D];
    const float* Wp = W2 + l * D2 * D;
    int row0 = blockIdx.x * 32;
    int nvalid = min(32, NNODES - row0);
    for (int i = threadIdx.x; i < D2 * D; i += 256) sW[i] = Wp[i];
    const float invN = 1.f / NNODES;
    for (int i = threadIdx.x; i < 32 * D2; i += 256) {
        int r = i >> 7, c = i & 127;
        float v = 0.f;
        if (r < nvalid) {
            float mu = stats1[c] * invN;
            float var = stats1[D2 + c] * invN - mu * mu;
            float rstd = rsqrtf(var + BN_EPS);
            v = (t[(row0 + r) * D2 + c] - mu) * rstd + BN_BIAS;
            v = fmaxf(v, 0.f);
        }
        sT[i] = v;
    }
    if (threadIdx.x < D) { sSum[threadIdx.x] = 0.f; sSq[threadIdx.x] = 0.f; }
    __syncthreads();
    int cg = threadIdx.x & 31;
    int rg = threadIdx.x >> 5;
    float2 binit = *(const float2*)&b2[l * D + cg * 2];
    float2 acc[4];
#pragma unroll
    for (int r = 0; r < 4; ++r) acc[r] = binit;
    for (int k = 0; k < D2; ++k) {
        float2 w = *(const float2*)&sW[k * D + cg * 2];
#pragma unroll
        for (int r = 0; r < 4; ++r) {
            float a = sT[(rg * 4 + r) * D2 + k];
            acc[r].x += a * w.x; acc[r].y += a * w.y;
        }
    }
    float2 s = {0, 0}, sq = {0, 0};
#pragma unroll
    for (int r = 0; r < 4; ++r) {
        int row = rg * 4 + r;
        if (row < nvalid) {
            *(float2*)&z2[(row0 + row) * D + cg * 2] = acc[r];
            s.x += acc[r].x; s.y += acc[r].y;
            sq.x += acc[r].x * acc[r].x; sq.y += acc[r].y * acc[r].y;
        }
    }
    atomicAdd(&sSum[cg * 2 + 0], s.x); atomicAdd(&sSq[cg * 2 + 0], sq.x);
    atomicAdd(&sSum[cg * 2 + 1], s.y); atomicAdd(&sSq[cg * 2 + 1], sq.y);
    __syncthreads();
    if (threadIdx.x < D) {
        atomicAdd(&stats2[threadIdx.x], sSum[threadIdx.x]);
        atomicAdd(&stats2[D + threadIdx.x], sSq[threadIdx.x]);
    }
}

// ---------------- fused: hin_next = relu(bn(z2)) + vn[batch] (+ bf16 shadow) ----------------
__global__ __launch_bounds__(256) void k_bnprep(const float* __restrict__ z2,
                                                const float* __restrict__ stats2,
                                                const float* __restrict__ vn,
                                                const int* __restrict__ batch,
                                                float* __restrict__ hin,
                                                __hip_bfloat16* __restrict__ hbf) {
    int idx = blockIdx.x * 256 + threadIdx.x;
    if (idx >= NNODES * D) return;
    int c = idx & 63, row = idx >> 6;
    const float invN = 1.f / NNODES;
    float mu = stats2[c] * invN;
    float var = stats2[D + c] * invN - mu * mu;
    float rstd = rsqrtf(var + BN_EPS);
    float v = (z2[idx] - mu) * rstd + BN_BIAS;
    v = fmaxf(v, 0.f);
    v += vn[batch[row] * D + c];
    hin[idx] = v;
    hbf[idx] = __float2bfloat16(v);
}

// ---------------- fused final: bn(z2) -> node att + per-node edge projections ----------------
__global__ __launch_bounds__(256) void k_finish_att_proj(const float* __restrict__ z2,
                                                         const float* __restrict__ stats2,
                                                         const float* __restrict__ Wna,
                                                         const float* __restrict__ bna,
                                                         const float* __restrict__ Wea,
                                                         float* __restrict__ proj,
                                                         float* __restrict__ out) {
    int wave = threadIdx.x >> 6, lane = threadIdx.x & 63;
    int row = blockIdx.x * 4 + wave;
    if (row >= NNODES) return;
    const float invN = 1.f / NNODES;
    float mu = stats2[lane] * invN;
    float var = stats2[D + lane] * invN - mu * mu;
    float rstd = rsqrtf(var + BN_EPS);
    float v = (z2[row * D + lane] - mu) * rstd + BN_BIAS;
    float n0 = v * Wna[lane * 2 + 0];
    float n1 = v * Wna[lane * 2 + 1];
    float pa0 = v * Wea[lane * 2 + 0];
    float pa1 = v * Wea[lane * 2 + 1];
    float pb0 = v * Wea[(D + lane) * 2 + 0];
    float pb1 = v * Wea[(D + lane) * 2 + 1];
#pragma unroll
    for (int o = 32; o; o >>= 1) {
        n0 += __shfl_xor(n0, o); n1 += __shfl_xor(n1, o);
        pa0 += __shfl_xor(pa0, o); pa1 += __shfl_xor(pa1, o);
        pb0 += __shfl_xor(pb0, o); pb1 += __shfl_xor(pb1, o);
    }
    if (lane == 0) {
        out[row] = 1.f / (1.f + expf((n0 + bna[0]) - (n1 + bna[1])));
        proj[row * 4 + 0] = pa0;
        proj[row * 4 + 1] = pa1;
        proj[row * 4 + 2] = pb0;
        proj[row * 4 + 3] = pb1;
    }
}

// ---------------- edge attention from projection tables ----------------
__global__ __launch_bounds__(256) void k_edge_final(const int* __restrict__ ei,
                                                    const float* __restrict__ proj,
                                                    const float* __restrict__ bea,
                                                    float* __restrict__ out) {
    int e = blockIdx.x * 256 + threadIdx.x;
    if (e >= NEDGES) return;
    int src = ei[e], dst = ei[NEDGES + e];
    float4 ps = *(const float4*)&proj[src * 4];
    float4 pd = *(const float4*)&proj[dst * 4];
    float s0 = ps.x + pd.z + bea[0];
    float s1 = ps.y + pd.w + bea[1];
    out[NNODES + e] = 1.f / (1.f + expf(s0 - s1));
}

// ---------------- vt += segment_sum(hin) over contiguous row chunks ----------------
__global__ __launch_bounds__(256) void k_vt(const float* __restrict__ hin,
                                            const int* __restrict__ batch,
                                            float* __restrict__ vt) {
    int wave = threadIdx.x >> 6, lane = threadIdx.x & 63;
    int wid = blockIdx.x * 4 + wave;
    int r0 = wid * 64;
    if (r0 >= NNODES) return;
    int r1 = min(r0 + 64, NNODES);
    int g = batch[r0];
    float acc = 0.f;
    for (int r = r0; r < r1; ++r) {
        int gb = batch[r];
        if (gb != g) {
            atomicAdd(&vt[g * D + lane], acc);
            acc = 0.f; g = gb;
        }
        acc += hin[r * D + lane];
    }
    atomicAdd(&vt[g * D + lane], acc);
}

// ---------------- virtual-node MLP (one block) ----------------
__global__ __launch_bounds__(256) void k_vnmlp(const float* __restrict__ vt,
                                               const float* __restrict__ Wv1,
                                               const float* __restrict__ bv1,
                                               const float* __restrict__ Wv2,
                                               const float* __restrict__ bv2, int l,
                                               float* __restrict__ vn) {
    __shared__ float sV[NG * D];
    __shared__ float sU[NG * D2];
    const float* W1p = Wv1 + l * D * D2;
    const float* W2p = Wv2 + l * D2 * D;
    for (int i = threadIdx.x; i < NG * D; i += 256) sV[i] = vt[i];
    __syncthreads();
    {
        int r = threadIdx.x >> 2, cb = (threadIdx.x & 3) * 32;
        float acc[32];
#pragma unroll
        for (int c = 0; c < 32; ++c) acc[c] = bv1[l * D2 + cb + c];
        for (int k = 0; k < D; ++k) {
            float v = sV[r * D + k];
#pragma unroll
            for (int c = 0; c < 32; ++c) acc[c] += v * W1p[k * D2 + cb + c];
        }
#pragma unroll
        for (int c = 0; c < 32; ++c) sU[r * D2 + cb + c] = acc[c];
    }
    __syncthreads();
    if (threadIdx.x < D2) {
        int c = threadIdx.x;
        float s = 0, sq = 0;
        for (int r = 0; r < NG; ++r) { float v = sU[r * D2 + c]; s += v; sq += v * v; }
        float mu = s / NG, rstd = rsqrtf(sq / NG - mu * mu + BN_EPS);
        for (int r = 0; r < NG; ++r)
            sU[r * D2 + c] = fmaxf((sU[r * D2 + c] - mu) * rstd + BN_BIAS, 0.f);
    }
    __syncthreads();
    {
        int r = threadIdx.x >> 2, cb = (threadIdx.x & 3) * 16;
        float acc[16];
#pragma unroll
        for (int c = 0; c < 16; ++c) acc[c] = bv2[l * D + cb + c];
        for (int k = 0; k < D2; ++k) {
            float v = sU[r * D2 + k];
#pragma unroll
            for (int c = 0; c < 16; ++c) acc[c] += v * W2p[k * D + cb + c];
        }
#pragma unroll
        for (int c = 0; c < 16; ++c) sV[r * D + cb + c] = acc[c];
    }
    __syncthreads();
    if (threadIdx.x < D) {
        int c = threadIdx.x;
        float s = 0, sq = 0;
        for (int r = 0; r < NG; ++r) { float v = sV[r * D + c]; s += v; sq += v * v; }
        float mu = s / NG, rstd = rsqrtf(sq / NG - mu * mu + BN_EPS);
        for (int r = 0; r < NG; ++r)
            vn[r * D + c] = fmaxf((sV[r * D + c] - mu) * rstd + BN_BIAS, 0.f);
    }
}

extern "C" void kernel_launch(void* const* d_in, const int* in_sizes, int n_in,
                              void* d_out, int out_size, void* d_ws, size_t ws_size,
                              hipStream_t stream) {
    const float* x    = (const float*)d_in[0];
    const float* ea   = (const float*)d_in[1];
    const int*   ei   = (const int*)d_in[2];
    const int*   batch= (const int*)d_in[3];
    const float* Wenc = (const float*)d_in[4];
    const float* benc = (const float*)d_in[5];
    const float* We   = (const float*)d_in[6];
    const float* be   = (const float*)d_in[7];
    const float* eps  = (const float*)d_in[8];
    const float* W1   = (const float*)d_in[9];
    const float* b1   = (const float*)d_in[10];
    const float* W2   = (const float*)d_in[11];
    const float* b2   = (const float*)d_in[12];
    const float* Wv1  = (const float*)d_in[13];
    const float* bv1  = (const float*)d_in[14];
    const float* Wv2  = (const float*)d_in[15];
    const float* bv2  = (const float*)d_in[16];
    const float* Wea  = (const float*)d_in[17];
    const float* bea  = (const float*)d_in[18];
    const float* Wna  = (const float*)d_in[19];
    const float* bna  = (const float*)d_in[20];
    float* out = (float*)d_out;

    float* ws  = (float*)d_ws;
    float* h    = ws;                              // [N*D]
    float* hin  = h   + (size_t)NNODES * D;        // [N*D]
    float* zin  = hin + (size_t)NNODES * D;        // [N*D]  (z2 overlays zin)
    float* t    = zin + (size_t)NNODES * D;        // [N*D2]
    float* vn   = t   + (size_t)NNODES * D2;       // [NG*D]
    float* vt   = vn  + NG * D;                    // [NG*D]
    float* stats= vt  + NG * D;                    // 512
    float* proj = stats + 512;                     // [N*4]
    __hip_bfloat16* hbf  = (__hip_bfloat16*)(proj + (size_t)NNODES * 4);   // [N*D]
    __hip_bfloat16* ea_s = hbf + (size_t)NNODES * D;                       // [E*EDIM]
    int*   deg    = (int*)(ea_s + (size_t)NEDGES * EDIM);
    int*   off    = deg + NNODES;
    int*   cursor = off + NNODES + 1;
    int*   esrc   = cursor + NNODES;

    float* z2     = zin;         // overlay: zin dead after gemm1
    float* stats2 = stats + 256;

    // init + CSR build (reused by all 3 layers)
    hipMemsetAsync(vn, 0, NG * D * sizeof(float), stream);
    hipMemsetAsync(deg, 0, NNODES * sizeof(int), stream);
    k_enc<<<NNODES / 4, 256, 0, stream>>>(x, Wenc, benc, h, hbf);
    k_hist<<<(NEDGES + 255) / 256, 256, 0, stream>>>(ei, deg);
    k_scan<<<1, SCAN_T, 0, stream>>>(deg, off, cursor);
    k_scatter<<<(NEDGES + 255) / 256, 256, 0, stream>>>(ei, ea, cursor, esrc, ea_s);

    for (int l = 0; l < 3; ++l) {
        const float* hin_l = (l == 0) ? h : hin;
        if (l < 2) {
            hipMemcpyAsync(vt, vn, NG * D * sizeof(float), hipMemcpyDeviceToDevice, stream);
            k_vt<<<(NNODES / 64 + 4) / 4, 256, 0, stream>>>(hin_l, batch, vt);
        }
        hipMemsetAsync(stats, 0, 384 * sizeof(float), stream);
        k_agg<<<(NNODES + 3) / 4, 256, 0, stream>>>(ea_s, off, esrc, We, be, eps, l,
                                                    hin_l, hbf, zin);
        if (l < 2) k_vnmlp<<<1, 256, 0, stream>>>(vt, Wv1, bv1, Wv2, bv2, l, vn);
        k_gemm1<<<(NNODES + 63) / 64, 256, 0, stream>>>(zin, W1, b1, l, t, stats);
        k_gemm2<<<(NNODES + 31) / 32, 256, 0, stream>>>(t, stats, W2, b2, l, z2, stats2);
        if (l < 2) {
            k_bnprep<<<NNODES * D / 256, 256, 0, stream>>>(z2, stats2, vn, batch, hin, hbf);
        } else {
            k_finish_att_proj<<<NNODES / 4, 256, 0, stream>>>(z2, stats2, Wna, bna, Wea,
                                                              proj, out);
        }
    }
    k_edge_final<<<(NEDGES + 255) / 256, 256, 0, stream>>>(ei, proj, bea, out);
}

// Round 5
// 1049.114 us; speedup vs baseline: 1.3598x; 1.0963x over previous
//
#include <hip/hip_runtime.h>
#include <hip/hip_bf16.h>

#define NNODES 50000
#define NEDGES 800000
#define NG 64
#define D 64
#define D2 128
#define INDIM 39
#define EDIM 10
#define BN_EPS 1e-5f
#define BN_BIAS 1e-4f
#define NSB ((NNODES + 255) / 256)   // 196 scan blocks

// ---------------- encoder: h = x @ Wenc + benc (+ bf16 shadow) ----------------
__global__ __launch_bounds__(256) void k_enc(const float* __restrict__ x,
                                             const float* __restrict__ Wenc,
                                             const float* __restrict__ benc,
                                             float* __restrict__ h,
                                             __hip_bfloat16* __restrict__ hbf) {
    __shared__ float sW[INDIM * D];
    for (int i = threadIdx.x; i < INDIM * D; i += 256) sW[i] = Wenc[i];
    __syncthreads();
    int wave = threadIdx.x >> 6, lane = threadIdx.x & 63;
    int row = blockIdx.x * 4 + wave;
    if (row >= NNODES) return;
    float xv = (lane < INDIM) ? x[row * INDIM + lane] : 0.f;
    float acc = benc[lane];
#pragma unroll
    for (int k = 0; k < INDIM; ++k) acc += __shfl(xv, k) * sW[k * D + lane];
    h[row * D + lane] = acc;
    hbf[row * D + lane] = __float2bfloat16(acc);
}

// ---------------- CSR build ----------------
__global__ __launch_bounds__(256) void k_hist(const int* __restrict__ ei,
                                              int* __restrict__ deg) {
    int e = blockIdx.x * 256 + threadIdx.x;
    if (e < NEDGES) atomicAdd(&deg[ei[NEDGES + e]], 1);
}

// hierarchical scan: per-block sums -> scan of sums -> per-block write
__global__ __launch_bounds__(256) void k_scansum(const int* __restrict__ deg,
                                                 int* __restrict__ bsum) {
    int i = blockIdx.x * 256 + threadIdx.x;
    int v = (i < NNODES) ? deg[i] : 0;
#pragma unroll
    for (int o = 32; o; o >>= 1) v += __shfl_xor(v, o);
    __shared__ int ws[4];
    if ((threadIdx.x & 63) == 0) ws[threadIdx.x >> 6] = v;
    __syncthreads();
    if (threadIdx.x == 0) bsum[blockIdx.x] = ws[0] + ws[1] + ws[2] + ws[3];
}

__global__ __launch_bounds__(256) void k_scanbase(const int* __restrict__ bsum,
                                                  int* __restrict__ bbase,
                                                  int* __restrict__ off) {
    __shared__ int s[256];
    int t = threadIdx.x;
    int v = (t < NSB) ? bsum[t] : 0;
    s[t] = v;
    __syncthreads();
    for (int o = 1; o < 256; o <<= 1) {
        int u = (t >= o) ? s[t - o] : 0;
        __syncthreads();
        s[t] += u;
        __syncthreads();
    }
    if (t < NSB) bbase[t] = s[t] - v;   // exclusive base
    if (t == 255) off[NNODES] = s[255];
}

__global__ __launch_bounds__(256) void k_scanwrite(const int* __restrict__ deg,
                                                   const int* __restrict__ bbase,
                                                   int* __restrict__ off,
                                                   int* __restrict__ cursor) {
    __shared__ int s[256];
    int t = threadIdx.x;
    int i = blockIdx.x * 256 + t;
    int v = (i < NNODES) ? deg[i] : 0;
    s[t] = v;
    __syncthreads();
    for (int o = 1; o < 256; o <<= 1) {
        int u = (t >= o) ? s[t - o] : 0;
        __syncthreads();
        s[t] += u;
        __syncthreads();
    }
    int excl = bbase[blockIdx.x] + s[t] - v;
    if (i < NNODES) { off[i] = excl; cursor[i] = excl; }
}

// scatter src index AND edge_attr (bf16) into CSR order
__global__ __launch_bounds__(256) void k_scatter(const int* __restrict__ ei,
                                                 const float* __restrict__ ea,
                                                 int* __restrict__ cursor,
                                                 int* __restrict__ esrc,
                                                 __hip_bfloat16* __restrict__ ea_s) {
    int e = blockIdx.x * 256 + threadIdx.x;
    if (e >= NEDGES) return;
    int d = ei[NEDGES + e];
    int p = atomicAdd(&cursor[d], 1);
    esrc[p] = ei[e];
    float v[EDIM];
#pragma unroll
    for (int i = 0; i < EDIM; ++i) v[i] = ea[e * EDIM + i];
    unsigned int* dst = (unsigned int*)(ea_s + (size_t)p * EDIM);
#pragma unroll
    for (int i = 0; i < 5; ++i) {
        __hip_bfloat16 b0 = __float2bfloat16(v[2 * i]);
        __hip_bfloat16 b1 = __float2bfloat16(v[2 * i + 1]);
        unsigned int u = ((unsigned int)*(unsigned short*)&b1 << 16) |
                         (unsigned int)*(unsigned short*)&b0;
        dst[i] = u;
    }
}

// ---------------- aggregate: zin[n] = (1+eps)*hin[n] + sum relu(hbf[src]+eemb) ----------------
__global__ __launch_bounds__(256) void k_agg(const __hip_bfloat16* __restrict__ ea_s,
                                             const int* __restrict__ off,
                                             const int* __restrict__ esrc,
                                             const float* __restrict__ We,
                                             const float* __restrict__ be,
                                             const float* __restrict__ eps, int l,
                                             const float* __restrict__ hin,
                                             const __hip_bfloat16* __restrict__ hbf,
                                             float* __restrict__ zin) {
    __shared__ float sW[EDIM * D];
    __shared__ float sb[D];
    const float* Wl = We + l * EDIM * D;
    for (int i = threadIdx.x; i < EDIM * D; i += 256) sW[i] = Wl[i];
    if (threadIdx.x < D) sb[threadIdx.x] = be[l * D + threadIdx.x];
    __syncthreads();
    int wave = threadIdx.x >> 6, lane = threadIdx.x & 63;
    int n = blockIdx.x * 4 + wave;
    if (n >= NNODES) return;
    int beg = off[n], end = off[n + 1];
    float acc = (1.f + eps[l]) * hin[n * D + lane];
    float bias = sb[lane];
    int j = beg;
    for (; j + 3 < end; j += 4) {
        int s0 = esrc[j], s1 = esrc[j + 1], s2 = esrc[j + 2], s3 = esrc[j + 3];
        float hv0 = __bfloat162float(hbf[(size_t)s0 * D + lane]);
        float hv1 = __bfloat162float(hbf[(size_t)s1 * D + lane]);
        float hv2 = __bfloat162float(hbf[(size_t)s2 * D + lane]);
        float hv3 = __bfloat162float(hbf[(size_t)s3 * D + lane]);
        float ev0 = (lane < EDIM) ? __bfloat162float(ea_s[(size_t)j * EDIM + lane]) : 0.f;
        float ev1 = (lane < EDIM) ? __bfloat162float(ea_s[(size_t)(j + 1) * EDIM + lane]) : 0.f;
        float ev2 = (lane < EDIM) ? __bfloat162float(ea_s[(size_t)(j + 2) * EDIM + lane]) : 0.f;
        float ev3 = (lane < EDIM) ? __bfloat162float(ea_s[(size_t)(j + 3) * EDIM + lane]) : 0.f;
        float m0 = bias, m1 = bias, m2 = bias, m3 = bias;
#pragma unroll
        for (int k = 0; k < EDIM; ++k) {
            float w = sW[k * D + lane];
            m0 += __shfl(ev0, k) * w;
            m1 += __shfl(ev1, k) * w;
            m2 += __shfl(ev2, k) * w;
            m3 += __shfl(ev3, k) * w;
        }
        acc += fmaxf(m0 + hv0, 0.f) + fmaxf(m1 + hv1, 0.f) +
               fmaxf(m2 + hv2, 0.f) + fmaxf(m3 + hv3, 0.f);
    }
    for (; j < end; ++j) {
        int src = esrc[j];
        float hv = __bfloat162float(hbf[(size_t)src * D + lane]);
        float ev = (lane < EDIM) ? __bfloat162float(ea_s[(size_t)j * EDIM + lane]) : 0.f;
        float m = bias;
#pragma unroll
        for (int k = 0; k < EDIM; ++k) m += __shfl(ev, k) * sW[k * D + lane];
        acc += fmaxf(m + hv, 0.f);
    }
    zin[n * D + lane] = acc;
}

// ---------------- GEMM1: t = zin @ W1 + b1 (+ BN stats of t) ----------------
__global__ __launch_bounds__(256) void k_gemm1(const float* __restrict__ zin,
                                               const float* __restrict__ W1,
                                               const float* __restrict__ b1, int l,
                                               float* __restrict__ t,
                                               float* __restrict__ stats1) {
    __shared__ float sZ[64 * D];
    __shared__ float sW[D * D2];
    __shared__ float sSum[D2], sSq[D2];
    const float* Wp = W1 + l * D * D2;
    int row0 = blockIdx.x * 64;
    int nvalid = min(64, NNODES - row0);
    for (int i = threadIdx.x; i < D * D2; i += 256) sW[i] = Wp[i];
    for (int i = threadIdx.x; i < 64 * D; i += 256) {
        int r = i >> 6;
        sZ[i] = (r < nvalid) ? zin[(row0 + r) * D + (i & 63)] : 0.f;
    }
    if (threadIdx.x < D2) { sSum[threadIdx.x] = 0.f; sSq[threadIdx.x] = 0.f; }
    __syncthreads();
    int cg = threadIdx.x & 31;
    int rg = threadIdx.x >> 5;
    float4 binit = *(const float4*)&b1[l * D2 + cg * 4];
    float4 acc[8];
#pragma unroll
    for (int r = 0; r < 8; ++r) acc[r] = binit;
    for (int k = 0; k < D; ++k) {
        float4 w = *(const float4*)&sW[k * D2 + cg * 4];
#pragma unroll
        for (int r = 0; r < 8; ++r) {
            float a = sZ[(rg * 8 + r) * D + k];
            acc[r].x += a * w.x; acc[r].y += a * w.y;
            acc[r].z += a * w.z; acc[r].w += a * w.w;
        }
    }
    float4 s = {0, 0, 0, 0}, sq = {0, 0, 0, 0};
#pragma unroll
    for (int r = 0; r < 8; ++r) {
        int row = rg * 8 + r;
        if (row < nvalid) {
            *(float4*)&t[(row0 + row) * D2 + cg * 4] = acc[r];
            s.x += acc[r].x; s.y += acc[r].y; s.z += acc[r].z; s.w += acc[r].w;
            sq.x += acc[r].x * acc[r].x; sq.y += acc[r].y * acc[r].y;
            sq.z += acc[r].z * acc[r].z; sq.w += acc[r].w * acc[r].w;
        }
    }
    atomicAdd(&sSum[cg * 4 + 0], s.x); atomicAdd(&sSq[cg * 4 + 0], sq.x);
    atomicAdd(&sSum[cg * 4 + 1], s.y); atomicAdd(&sSq[cg * 4 + 1], sq.y);
    atomicAdd(&sSum[cg * 4 + 2], s.z); atomicAdd(&sSq[cg * 4 + 2], sq.z);
    atomicAdd(&sSum[cg * 4 + 3], s.w); atomicAdd(&sSq[cg * 4 + 3], sq.w);
    __syncthreads();
    if (threadIdx.x < D2) {
        atomicAdd(&stats1[threadIdx.x], sSum[threadIdx.x]);
        atomicAdd(&stats1[D2 + threadIdx.x], sSq[threadIdx.x]);
    }
}

// ---------------- GEMM2: z2 = relu(bn(t)) @ W2 + b2 (+ BN stats of z2) ----------------
__global__ __launch_bounds__(256) void k_gemm2(const float* __restrict__ t,
                                               const float* __restrict__ stats1,
                                               const float* __restrict__ W2,
                                               const float* __restrict__ b2, int l,
                                               float* __restrict__ z2,
                                               float* __restrict__ stats2) {
    __shared__ float sT[32 * D2];
    __shared__ float sW[D2 * D];
    __shared__ float sSum[D], sSq[D];
    const float* Wp = W2 + l * D2 * D;
    int row0 = blockIdx.x * 32;
    int nvalid = min(32, NNODES - row0);
    for (int i = threadIdx.x; i < D2 * D; i += 256) sW[i] = Wp[i];
    const float invN = 1.f / NNODES;
    for (int i = threadIdx.x; i < 32 * D2; i += 256) {
        int r = i >> 7, c = i & 127;
        float v = 0.f;
        if (r < nvalid) {
            float mu = stats1[c] * invN;
            float var = stats1[D2 + c] * invN - mu * mu;
            float rstd = rsqrtf(var + BN_EPS);
            v = (t[(row0 + r) * D2 + c] - mu) * rstd + BN_BIAS;
            v = fmaxf(v, 0.f);
        }
        sT[i] = v;
    }
    if (threadIdx.x < D) { sSum[threadIdx.x] = 0.f; sSq[threadIdx.x] = 0.f; }
    __syncthreads();
    int cg = threadIdx.x & 31;
    int rg = threadIdx.x >> 5;
    float2 binit = *(const float2*)&b2[l * D + cg * 2];
    float2 acc[4];
#pragma unroll
    for (int r = 0; r < 4; ++r) acc[r] = binit;
    for (int k = 0; k < D2; ++k) {
        float2 w = *(const float2*)&sW[k * D + cg * 2];
#pragma unroll
        for (int r = 0; r < 4; ++r) {
            float a = sT[(rg * 4 + r) * D2 + k];
            acc[r].x += a * w.x; acc[r].y += a * w.y;
        }
    }
    float2 s = {0, 0}, sq = {0, 0};
#pragma unroll
    for (int r = 0; r < 4; ++r) {
        int row = rg * 4 + r;
        if (row < nvalid) {
            *(float2*)&z2[(row0 + row) * D + cg * 2] = acc[r];
            s.x += acc[r].x; s.y += acc[r].y;
            sq.x += acc[r].x * acc[r].x; sq.y += acc[r].y * acc[r].y;
        }
    }
    atomicAdd(&sSum[cg * 2 + 0], s.x); atomicAdd(&sSq[cg * 2 + 0], sq.x);
    atomicAdd(&sSum[cg * 2 + 1], s.y); atomicAdd(&sSq[cg * 2 + 1], sq.y);
    __syncthreads();
    if (threadIdx.x < D) {
        atomicAdd(&stats2[threadIdx.x], sSum[threadIdx.x]);
        atomicAdd(&stats2[D + threadIdx.x], sSq[threadIdx.x]);
    }
}

// ---------------- fused: hin_next = relu(bn(z2)) + vn[batch] (+ bf16 shadow) ----------------
__global__ __launch_bounds__(256) void k_bnprep(const float* __restrict__ z2,
                                                const float* __restrict__ stats2,
                                                const float* __restrict__ vn,
                                                const int* __restrict__ batch,
                                                float* __restrict__ hin,
                                                __hip_bfloat16* __restrict__ hbf) {
    int idx = blockIdx.x * 256 + threadIdx.x;
    if (idx >= NNODES * D) return;
    int c = idx & 63, row = idx >> 6;
    const float invN = 1.f / NNODES;
    float mu = stats2[c] * invN;
    float var = stats2[D + c] * invN - mu * mu;
    float rstd = rsqrtf(var + BN_EPS);
    float v = (z2[idx] - mu) * rstd + BN_BIAS;
    v = fmaxf(v, 0.f);
    v += vn[batch[row] * D + c];
    hin[idx] = v;
    hbf[idx] = __float2bfloat16(v);
}

// ---------------- fused final: bn(z2) -> node att + per-node edge projections ----------------
__global__ __launch_bounds__(256) void k_finish_att_proj(const float* __restrict__ z2,
                                                         const float* __restrict__ stats2,
                                                         const float* __restrict__ Wna,
                                                         const float* __restrict__ bna,
                                                         const float* __restrict__ Wea,
                                                         float* __restrict__ proj,
                                                         float* __restrict__ out) {
    int wave = threadIdx.x >> 6, lane = threadIdx.x & 63;
    int row = blockIdx.x * 4 + wave;
    if (row >= NNODES) return;
    const float invN = 1.f / NNODES;
    float mu = stats2[lane] * invN;
    float var = stats2[D + lane] * invN - mu * mu;
    float rstd = rsqrtf(var + BN_EPS);
    float v = (z2[row * D + lane] - mu) * rstd + BN_BIAS;
    float n0 = v * Wna[lane * 2 + 0];
    float n1 = v * Wna[lane * 2 + 1];
    float pa0 = v * Wea[lane * 2 + 0];
    float pa1 = v * Wea[lane * 2 + 1];
    float pb0 = v * Wea[(D + lane) * 2 + 0];
    float pb1 = v * Wea[(D + lane) * 2 + 1];
#pragma unroll
    for (int o = 32; o; o >>= 1) {
        n0 += __shfl_xor(n0, o); n1 += __shfl_xor(n1, o);
        pa0 += __shfl_xor(pa0, o); pa1 += __shfl_xor(pa1, o);
        pb0 += __shfl_xor(pb0, o); pb1 += __shfl_xor(pb1, o);
    }
    if (lane == 0) {
        out[row] = 1.f / (1.f + expf((n0 + bna[0]) - (n1 + bna[1])));
        proj[row * 4 + 0] = pa0;
        proj[row * 4 + 1] = pa1;
        proj[row * 4 + 2] = pb0;
        proj[row * 4 + 3] = pb1;
    }
}

// ---------------- edge attention from projection tables ----------------
__global__ __launch_bounds__(256) void k_edge_final(const int* __restrict__ ei,
                                                    const float* __restrict__ proj,
                                                    const float* __restrict__ bea,
                                                    float* __restrict__ out) {
    int e = blockIdx.x * 256 + threadIdx.x;
    if (e >= NEDGES) return;
    int src = ei[e], dst = ei[NEDGES + e];
    float4 ps = *(const float4*)&proj[src * 4];
    float4 pd = *(const float4*)&proj[dst * 4];
    float s0 = ps.x + pd.z + bea[0];
    float s1 = ps.y + pd.w + bea[1];
    out[NNODES + e] = 1.f / (1.f + expf(s0 - s1));
}

// ---------------- vt += segment_sum(hin) over contiguous row chunks ----------------
__global__ __launch_bounds__(256) void k_vt(const float* __restrict__ hin,
                                            const int* __restrict__ batch,
                                            float* __restrict__ vt) {
    int wave = threadIdx.x >> 6, lane = threadIdx.x & 63;
    int wid = blockIdx.x * 4 + wave;
    int r0 = wid * 64;
    if (r0 >= NNODES) return;
    int r1 = min(r0 + 64, NNODES);
    int g = batch[r0];
    float acc = 0.f;
    for (int r = r0; r < r1; ++r) {
        int gb = batch[r];
        if (gb != g) {
            atomicAdd(&vt[g * D + lane], acc);
            acc = 0.f; g = gb;
        }
        acc += hin[r * D + lane];
    }
    atomicAdd(&vt[g * D + lane], acc);
}

// ---------------- virtual-node MLP (one block) ----------------
__global__ __launch_bounds__(256) void k_vnmlp(const float* __restrict__ vt,
                                               const float* __restrict__ Wv1,
                                               const float* __restrict__ bv1,
                                               const float* __restrict__ Wv2,
                                               const float* __restrict__ bv2, int l,
                                               float* __restrict__ vn) {
    __shared__ float sV[NG * D];
    __shared__ float sU[NG * D2];
    const float* W1p = Wv1 + l * D * D2;
    const float* W2p = Wv2 + l * D2 * D;
    for (int i = threadIdx.x; i < NG * D; i += 256) sV[i] = vt[i];
    __syncthreads();
    {
        int r = threadIdx.x >> 2, cb = (threadIdx.x & 3) * 32;
        float acc[32];
#pragma unroll
        for (int c = 0; c < 32; ++c) acc[c] = bv1[l * D2 + cb + c];
        for (int k = 0; k < D; ++k) {
            float v = sV[r * D + k];
#pragma unroll
            for (int c = 0; c < 32; ++c) acc[c] += v * W1p[k * D2 + cb + c];
        }
#pragma unroll
        for (int c = 0; c < 32; ++c) sU[r * D2 + cb + c] = acc[c];
    }
    __syncthreads();
    if (threadIdx.x < D2) {
        int c = threadIdx.x;
        float s = 0, sq = 0;
        for (int r = 0; r < NG; ++r) { float v = sU[r * D2 + c]; s += v; sq += v * v; }
        float mu = s / NG, rstd = rsqrtf(sq / NG - mu * mu + BN_EPS);
        for (int r = 0; r < NG; ++r)
            sU[r * D2 + c] = fmaxf((sU[r * D2 + c] - mu) * rstd + BN_BIAS, 0.f);
    }
    __syncthreads();
    {
        int r = threadIdx.x >> 2, cb = (threadIdx.x & 3) * 16;
        float acc[16];
#pragma unroll
        for (int c = 0; c < 16; ++c) acc[c] = bv2[l * D + cb + c];
        for (int k = 0; k < D2; ++k) {
            float v = sU[r * D2 + k];
#pragma unroll
            for (int c = 0; c < 16; ++c) acc[c] += v * W2p[k * D + cb + c];
        }
#pragma unroll
        for (int c = 0; c < 16; ++c) sV[r * D + cb + c] = acc[c];
    }
    __syncthreads();
    if (threadIdx.x < D) {
        int c = threadIdx.x;
        float s = 0, sq = 0;
        for (int r = 0; r < NG; ++r) { float v = sV[r * D + c]; s += v; sq += v * v; }
        float mu = s / NG, rstd = rsqrtf(sq / NG - mu * mu + BN_EPS);
        for (int r = 0; r < NG; ++r)
            vn[r * D + c] = fmaxf((sV[r * D + c] - mu) * rstd + BN_BIAS, 0.f);
    }
}

extern "C" void kernel_launch(void* const* d_in, const int* in_sizes, int n_in,
                              void* d_out, int out_size, void* d_ws, size_t ws_size,
                              hipStream_t stream) {
    const float* x    = (const float*)d_in[0];
    const float* ea   = (const float*)d_in[1];
    const int*   ei   = (const int*)d_in[2];
    const int*   batch= (const int*)d_in[3];
    const float* Wenc = (const float*)d_in[4];
    const float* benc = (const float*)d_in[5];
    const float* We   = (const float*)d_in[6];
    const float* be   = (const float*)d_in[7];
    const float* eps  = (const float*)d_in[8];
    const float* W1   = (const float*)d_in[9];
    const float* b1   = (const float*)d_in[10];
    const float* W2   = (const float*)d_in[11];
    const float* b2   = (const float*)d_in[12];
    const float* Wv1  = (const float*)d_in[13];
    const float* bv1  = (const float*)d_in[14];
    const float* Wv2  = (const float*)d_in[15];
    const float* bv2  = (const float*)d_in[16];
    const float* Wea  = (const float*)d_in[17];
    const float* bea  = (const float*)d_in[18];
    const float* Wna  = (const float*)d_in[19];
    const float* bna  = (const float*)d_in[20];
    float* out = (float*)d_out;

    float* ws  = (float*)d_ws;
    float* h    = ws;                              // [N*D]
    float* hin  = h   + (size_t)NNODES * D;        // [N*D]
    float* zin  = hin + (size_t)NNODES * D;        // [N*D]  (z2 overlays zin)
    float* t    = zin + (size_t)NNODES * D;        // [N*D2]
    float* vn   = t   + (size_t)NNODES * D2;       // [NG*D]
    float* vt   = vn  + NG * D;                    // [NG*D]
    float* stats= vt  + NG * D;                    // 512
    float* proj = stats + 512;                     // [N*4]
    __hip_bfloat16* hbf  = (__hip_bfloat16*)(proj + (size_t)NNODES * 4);   // [N*D]
    __hip_bfloat16* ea_s = hbf + (size_t)NNODES * D;                       // [E*EDIM]
    int*   deg    = (int*)(ea_s + (size_t)NEDGES * EDIM);
    int*   off    = deg + NNODES;
    int*   cursor = off + NNODES + 1;
    int*   esrc   = cursor + NNODES;
    int*   bsum   = esrc + NEDGES;                 // [NSB]
    int*   bbase  = bsum + NSB;                    // [NSB]

    float* z2     = zin;         // overlay: zin dead after gemm1
    float* stats2 = stats + 256;

    // init + CSR build (reused by all 3 layers)
    hipMemsetAsync(vn, 0, NG * D * sizeof(float), stream);
    hipMemsetAsync(deg, 0, NNODES * sizeof(int), stream);
    k_enc<<<NNODES / 4, 256, 0, stream>>>(x, Wenc, benc, h, hbf);
    k_hist<<<(NEDGES + 255) / 256, 256, 0, stream>>>(ei, deg);
    k_scansum<<<NSB, 256, 0, stream>>>(deg, bsum);
    k_scanbase<<<1, 256, 0, stream>>>(bsum, bbase, off);
    k_scanwrite<<<NSB, 256, 0, stream>>>(deg, bbase, off, cursor);
    k_scatter<<<(NEDGES + 255) / 256, 256, 0, stream>>>(ei, ea, cursor, esrc, ea_s);

    for (int l = 0; l < 3; ++l) {
        const float* hin_l = (l == 0) ? h : hin;
        if (l < 2) {
            hipMemcpyAsync(vt, vn, NG * D * sizeof(float), hipMemcpyDeviceToDevice, stream);
            k_vt<<<(NNODES / 64 + 4) / 4, 256, 0, stream>>>(hin_l, batch, vt);
        }
        hipMemsetAsync(stats, 0, 384 * sizeof(float), stream);
        k_agg<<<(NNODES + 3) / 4, 256, 0, stream>>>(ea_s, off, esrc, We, be, eps, l,
                                                    hin_l, hbf, zin);
        if (l < 2) k_vnmlp<<<1, 256, 0, stream>>>(vt, Wv1, bv1, Wv2, bv2, l, vn);
        k_gemm1<<<(NNODES + 63) / 64, 256, 0, stream>>>(zin, W1, b1, l, t, stats);
        k_gemm2<<<(NNODES + 31) / 32, 256, 0, stream>>>(t, stats, W2, b2, l, z2, stats2);
        if (l < 2) {
            k_bnprep<<<NNODES * D / 256, 256, 0, stream>>>(z2, stats2, vn, batch, hin, hbf);
        } else {
            k_finish_att_proj<<<NNODES / 4, 256, 0, stream>>>(z2, stats2, Wna, bna, Wea,
                                                              proj, out);
        }
    }
    k_edge_final<<<(NEDGES + 255) / 256, 256, 0, stream>>>(ei, proj, bea, out);
}

// Round 6
// 975.783 us; speedup vs baseline: 1.4619x; 1.0752x over previous
//
#include <hip/hip_runtime.h>
#include <hip/hip_bf16.h>

#define NNODES 50000
#define NEDGES 800000
#define NG 64
#define D 64
#define D2 128
#define INDIM 39
#define EDIM 10
#define EPAD 12            // padded bf16 elems per ea_s row (24B, 8B-aligned)
#define BN_EPS 1e-5f
#define BN_BIAS 1e-4f
#define NSB ((NNODES + 255) / 256)   // 196 scan blocks

__device__ __forceinline__ float blo(unsigned u) {
    union { unsigned i; float f; } c; c.i = u << 16; return c.f;
}
__device__ __forceinline__ float bhi(unsigned u) {
    union { unsigned i; float f; } c; c.i = u & 0xffff0000u; return c.f;
}

// ---------------- encoder: hin = x @ Wenc + benc (+ bf16 shadow) ----------------
__global__ __launch_bounds__(256) void k_enc(const float* __restrict__ x,
                                             const float* __restrict__ Wenc,
                                             const float* __restrict__ benc,
                                             float* __restrict__ hin,
                                             __hip_bfloat16* __restrict__ hbf) {
    __shared__ float sW[INDIM * D];
    for (int i = threadIdx.x; i < INDIM * D; i += 256) sW[i] = Wenc[i];
    __syncthreads();
    int wave = threadIdx.x >> 6, lane = threadIdx.x & 63;
    int row = blockIdx.x * 4 + wave;
    if (row >= NNODES) return;
    float xv = (lane < INDIM) ? x[row * INDIM + lane] : 0.f;
    float acc = benc[lane];
#pragma unroll
    for (int k = 0; k < INDIM; ++k) acc += __shfl(xv, k) * sW[k * D + lane];
    hin[row * D + lane] = acc;
    hbf[row * D + lane] = __float2bfloat16(acc);
}

// ---------------- CSR build ----------------
__global__ __launch_bounds__(256) void k_hist(const int* __restrict__ ei,
                                              int* __restrict__ deg) {
    int e = blockIdx.x * 256 + threadIdx.x;
    if (e < NEDGES) atomicAdd(&deg[ei[NEDGES + e]], 1);
}

__global__ __launch_bounds__(256) void k_scansum(const int* __restrict__ deg,
                                                 int* __restrict__ bsum) {
    int i = blockIdx.x * 256 + threadIdx.x;
    int v = (i < NNODES) ? deg[i] : 0;
#pragma unroll
    for (int o = 32; o; o >>= 1) v += __shfl_xor(v, o);
    __shared__ int ws[4];
    if ((threadIdx.x & 63) == 0) ws[threadIdx.x >> 6] = v;
    __syncthreads();
    if (threadIdx.x == 0) bsum[blockIdx.x] = ws[0] + ws[1] + ws[2] + ws[3];
}

__global__ __launch_bounds__(256) void k_scanbase(const int* __restrict__ bsum,
                                                  int* __restrict__ bbase,
                                                  int* __restrict__ off) {
    __shared__ int s[256];
    int t = threadIdx.x;
    int v = (t < NSB) ? bsum[t] : 0;
    s[t] = v;
    __syncthreads();
    for (int o = 1; o < 256; o <<= 1) {
        int u = (t >= o) ? s[t - o] : 0;
        __syncthreads();
        s[t] += u;
        __syncthreads();
    }
    if (t < NSB) bbase[t] = s[t] - v;
    if (t == 255) off[NNODES] = s[255];
}

__global__ __launch_bounds__(256) void k_scanwrite(const int* __restrict__ deg,
                                                   const int* __restrict__ bbase,
                                                   int* __restrict__ off,
                                                   int* __restrict__ cursor) {
    __shared__ int s[256];
    int t = threadIdx.x;
    int i = blockIdx.x * 256 + t;
    int v = (i < NNODES) ? deg[i] : 0;
    s[t] = v;
    __syncthreads();
    for (int o = 1; o < 256; o <<= 1) {
        int u = (t >= o) ? s[t - o] : 0;
        __syncthreads();
        s[t] += u;
        __syncthreads();
    }
    int excl = bbase[blockIdx.x] + s[t] - v;
    if (i < NNODES) { off[i] = excl; cursor[i] = excl; }
}

// scatter src index AND edge_attr (bf16, 24B padded row) into CSR order
__global__ __launch_bounds__(256) void k_scatter(const int* __restrict__ ei,
                                                 const float* __restrict__ ea,
                                                 int* __restrict__ cursor,
                                                 int* __restrict__ esrc,
                                                 __hip_bfloat16* __restrict__ ea_s) {
    int e = blockIdx.x * 256 + threadIdx.x;
    if (e >= NEDGES) return;
    int d = ei[NEDGES + e];
    int p = atomicAdd(&cursor[d], 1);
    esrc[p] = ei[e];
    unsigned u[5];
#pragma unroll
    for (int i = 0; i < 5; ++i) {
        __hip_bfloat16 b0 = __float2bfloat16(ea[e * EDIM + 2 * i]);
        __hip_bfloat16 b1 = __float2bfloat16(ea[e * EDIM + 2 * i + 1]);
        u[i] = ((unsigned)*(unsigned short*)&b1 << 16) | (unsigned)*(unsigned short*)&b0;
    }
    unsigned* dst = (unsigned*)(ea_s + (size_t)p * EPAD);
    *(uint2*)(dst) = make_uint2(u[0], u[1]);
    *(uint2*)(dst + 2) = make_uint2(u[2], u[3]);
    dst[4] = u[4];
}

// ---------------- aggregate (no LDS, no shfl): zin[n] = (1+eps)*hin[n] + sum relu(...) ----
__global__ __launch_bounds__(256) void k_agg(const __hip_bfloat16* __restrict__ ea_s,
                                             const int* __restrict__ off,
                                             const int* __restrict__ esrc,
                                             const float* __restrict__ We,
                                             const float* __restrict__ be,
                                             const float* __restrict__ eps, int l,
                                             const float* __restrict__ hin,
                                             const __hip_bfloat16* __restrict__ hbf,
                                             float* __restrict__ zin) {
    int wave = threadIdx.x >> 6, lane = threadIdx.x & 63;
    int n = blockIdx.x * 4 + wave;
    if (n >= NNODES) return;
    const float* Wl = We + l * EDIM * D;
    float w[EDIM];
#pragma unroll
    for (int k = 0; k < EDIM; ++k) w[k] = Wl[k * D + lane];
    float bias = be[l * D + lane];
    int beg = off[n], end = off[n + 1];
    float acc = (1.f + eps[l]) * hin[n * D + lane];
    const unsigned* eap = (const unsigned*)ea_s;
    int j = beg;
#define EMB(a, b, c, m)                                                          \
    {                                                                            \
        m = bias;                                                                \
        m += blo(a.x) * w[0] + bhi(a.x) * w[1] + blo(a.y) * w[2] + bhi(a.y) * w[3]; \
        m += blo(b.x) * w[4] + bhi(b.x) * w[5] + blo(b.y) * w[6] + bhi(b.y) * w[7]; \
        m += blo(c) * w[8] + bhi(c) * w[9];                                      \
    }
    for (; j + 3 < end; j += 4) {
        int s0 = esrc[j], s1 = esrc[j + 1], s2 = esrc[j + 2], s3 = esrc[j + 3];
        float hv0 = __bfloat162float(hbf[(size_t)s0 * D + lane]);
        float hv1 = __bfloat162float(hbf[(size_t)s1 * D + lane]);
        float hv2 = __bfloat162float(hbf[(size_t)s2 * D + lane]);
        float hv3 = __bfloat162float(hbf[(size_t)s3 * D + lane]);
        const unsigned* e0 = eap + (size_t)j * 6;
        uint2 a0 = *(const uint2*)(e0), b0 = *(const uint2*)(e0 + 2); unsigned c0 = e0[4];
        uint2 a1 = *(const uint2*)(e0 + 6), b1 = *(const uint2*)(e0 + 8); unsigned c1 = e0[10];
        uint2 a2 = *(const uint2*)(e0 + 12), b2 = *(const uint2*)(e0 + 14); unsigned c2 = e0[16];
        uint2 a3 = *(const uint2*)(e0 + 18), b3 = *(const uint2*)(e0 + 20); unsigned c3 = e0[22];
        float m0, m1, m2, m3;
        EMB(a0, b0, c0, m0) EMB(a1, b1, c1, m1) EMB(a2, b2, c2, m2) EMB(a3, b3, c3, m3)
        acc += fmaxf(m0 + hv0, 0.f) + fmaxf(m1 + hv1, 0.f) +
               fmaxf(m2 + hv2, 0.f) + fmaxf(m3 + hv3, 0.f);
    }
    for (; j < end; ++j) {
        int src = esrc[j];
        float hv = __bfloat162float(hbf[(size_t)src * D + lane]);
        const unsigned* e0 = eap + (size_t)j * 6;
        uint2 a = *(const uint2*)(e0), b = *(const uint2*)(e0 + 2); unsigned c = e0[4];
        float m;
        EMB(a, b, c, m)
        acc += fmaxf(m + hv, 0.f);
    }
#undef EMB
    zin[n * D + lane] = acc;
}

// ---------------- GEMM1: t = zin @ W1 + b1 (+ BN stats of t) ----------------
__global__ __launch_bounds__(256) void k_gemm1(const float* __restrict__ zin,
                                               const float* __restrict__ W1,
                                               const float* __restrict__ b1, int l,
                                               float* __restrict__ t,
                                               float* __restrict__ stats1) {
    __shared__ float sZ[64 * D];
    __shared__ float sW[D * D2];
    __shared__ float sSum[D2], sSq[D2];
    const float* Wp = W1 + l * D * D2;
    int row0 = blockIdx.x * 64;
    int nvalid = min(64, NNODES - row0);
    for (int i = threadIdx.x; i < D * D2; i += 256) sW[i] = Wp[i];
    for (int i = threadIdx.x; i < 64 * D; i += 256) {
        int r = i >> 6;
        sZ[i] = (r < nvalid) ? zin[(row0 + r) * D + (i & 63)] : 0.f;
    }
    if (threadIdx.x < D2) { sSum[threadIdx.x] = 0.f; sSq[threadIdx.x] = 0.f; }
    __syncthreads();
    int cg = threadIdx.x & 31;
    int rg = threadIdx.x >> 5;
    float4 binit = *(const float4*)&b1[l * D2 + cg * 4];
    float4 acc[8];
#pragma unroll
    for (int r = 0; r < 8; ++r) acc[r] = binit;
    for (int k = 0; k < D; ++k) {
        float4 w = *(const float4*)&sW[k * D2 + cg * 4];
#pragma unroll
        for (int r = 0; r < 8; ++r) {
            float a = sZ[(rg * 8 + r) * D + k];
            acc[r].x += a * w.x; acc[r].y += a * w.y;
            acc[r].z += a * w.z; acc[r].w += a * w.w;
        }
    }
    float4 s = {0, 0, 0, 0}, sq = {0, 0, 0, 0};
#pragma unroll
    for (int r = 0; r < 8; ++r) {
        int row = rg * 8 + r;
        if (row < nvalid) {
            *(float4*)&t[(row0 + row) * D2 + cg * 4] = acc[r];
            s.x += acc[r].x; s.y += acc[r].y; s.z += acc[r].z; s.w += acc[r].w;
            sq.x += acc[r].x * acc[r].x; sq.y += acc[r].y * acc[r].y;
            sq.z += acc[r].z * acc[r].z; sq.w += acc[r].w * acc[r].w;
        }
    }
    atomicAdd(&sSum[cg * 4 + 0], s.x); atomicAdd(&sSq[cg * 4 + 0], sq.x);
    atomicAdd(&sSum[cg * 4 + 1], s.y); atomicAdd(&sSq[cg * 4 + 1], sq.y);
    atomicAdd(&sSum[cg * 4 + 2], s.z); atomicAdd(&sSq[cg * 4 + 2], sq.z);
    atomicAdd(&sSum[cg * 4 + 3], s.w); atomicAdd(&sSq[cg * 4 + 3], sq.w);
    __syncthreads();
    if (threadIdx.x < D2) {
        atomicAdd(&stats1[threadIdx.x], sSum[threadIdx.x]);
        atomicAdd(&stats1[D2 + threadIdx.x], sSq[threadIdx.x]);
    }
}

// ---------------- GEMM2: z2 = relu(bn(t)) @ W2 + b2 (+ BN stats of z2) ----------------
__global__ __launch_bounds__(256) void k_gemm2(const float* __restrict__ t,
                                               const float* __restrict__ stats1,
                                               const float* __restrict__ W2,
                                               const float* __restrict__ b2, int l,
                                               float* __restrict__ z2,
                                               float* __restrict__ stats2) {
    __shared__ float sT[32 * D2];
    __shared__ float sW[D2 * D];
    __shared__ float sSum[D], sSq[D];
    const float* Wp = W2 + l * D2 * D;
    int row0 = blockIdx.x * 32;
    int nvalid = min(32, NNODES - row0);
    for (int i = threadIdx.x; i < D2 * D; i += 256) sW[i] = Wp[i];
    const float invN = 1.f / NNODES;
    for (int i = threadIdx.x; i < 32 * D2; i += 256) {
        int r = i >> 7, c = i & 127;
        float v = 0.f;
        if (r < nvalid) {
            float mu = stats1[c] * invN;
            float var = stats1[D2 + c] * invN - mu * mu;
            float rstd = rsqrtf(var + BN_EPS);
            v = (t[(row0 + r) * D2 + c] - mu) * rstd + BN_BIAS;
            v = fmaxf(v, 0.f);
        }
        sT[i] = v;
    }
    if (threadIdx.x < D) { sSum[threadIdx.x] = 0.f; sSq[threadIdx.x] = 0.f; }
    __syncthreads();
    int cg = threadIdx.x & 31;
    int rg = threadIdx.x >> 5;
    float2 binit = *(const float2*)&b2[l * D + cg * 2];
    float2 acc[4];
#pragma unroll
    for (int r = 0; r < 4; ++r) acc[r] = binit;
    for (int k = 0; k < D2; ++k) {
        float2 w = *(const float2*)&sW[k * D + cg * 2];
#pragma unroll
        for (int r = 0; r < 4; ++r) {
            float a = sT[(rg * 4 + r) * D2 + k];
            acc[r].x += a * w.x; acc[r].y += a * w.y;
        }
    }
    float2 s = {0, 0}, sq = {0, 0};
#pragma unroll
    for (int r = 0; r < 4; ++r) {
        int row = rg * 4 + r;
        if (row < nvalid) {
            *(float2*)&z2[(row0 + row) * D + cg * 2] = acc[r];
            s.x += acc[r].x; s.y += acc[r].y;
            sq.x += acc[r].x * acc[r].x; sq.y += acc[r].y * acc[r].y;
        }
    }
    atomicAdd(&sSum[cg * 2 + 0], s.x); atomicAdd(&sSq[cg * 2 + 0], sq.x);
    atomicAdd(&sSum[cg * 2 + 1], s.y); atomicAdd(&sSq[cg * 2 + 1], sq.y);
    __syncthreads();
    if (threadIdx.x < D) {
        atomicAdd(&stats2[threadIdx.x], sSum[threadIdx.x]);
        atomicAdd(&stats2[D + threadIdx.x], sSq[threadIdx.x]);
    }
}

// ---------------- fused: hin = relu(bn(z2)) + vn[batch] (+ bf16 shadow) ----------------
__global__ __launch_bounds__(256) void k_bnprep(const float* __restrict__ z2,
                                                const float* __restrict__ stats2,
                                                const float* __restrict__ vn,
                                                const int* __restrict__ batch,
                                                float* __restrict__ hin,
                                                __hip_bfloat16* __restrict__ hbf) {
    int idx = blockIdx.x * 256 + threadIdx.x;
    if (idx >= NNODES * D) return;
    int c = idx & 63, row = idx >> 6;
    const float invN = 1.f / NNODES;
    float mu = stats2[c] * invN;
    float var = stats2[D + c] * invN - mu * mu;
    float rstd = rsqrtf(var + BN_EPS);
    float v = (z2[idx] - mu) * rstd + BN_BIAS;
    v = fmaxf(v, 0.f);
    v += vn[batch[row] * D + c];
    hin[idx] = v;
    hbf[idx] = __float2bfloat16(v);
}

// ---------------- fused final: bn(z2) -> node att + per-node edge projections ----------------
__global__ __launch_bounds__(256) void k_finish_att_proj(const float* __restrict__ z2,
                                                         const float* __restrict__ stats2,
                                                         const float* __restrict__ Wna,
                                                         const float* __restrict__ bna,
                                                         const float* __restrict__ Wea,
                                                         float* __restrict__ proj,
                                                         float* __restrict__ out) {
    int wave = threadIdx.x >> 6, lane = threadIdx.x & 63;
    int row = blockIdx.x * 4 + wave;
    if (row >= NNODES) return;
    const float invN = 1.f / NNODES;
    float mu = stats2[lane] * invN;
    float var = stats2[D + lane] * invN - mu * mu;
    float rstd = rsqrtf(var + BN_EPS);
    float v = (z2[row * D + lane] - mu) * rstd + BN_BIAS;
    float n0 = v * Wna[lane * 2 + 0];
    float n1 = v * Wna[lane * 2 + 1];
    float pa0 = v * Wea[lane * 2 + 0];
    float pa1 = v * Wea[lane * 2 + 1];
    float pb0 = v * Wea[(D + lane) * 2 + 0];
    float pb1 = v * Wea[(D + lane) * 2 + 1];
#pragma unroll
    for (int o = 32; o; o >>= 1) {
        n0 += __shfl_xor(n0, o); n1 += __shfl_xor(n1, o);
        pa0 += __shfl_xor(pa0, o); pa1 += __shfl_xor(pa1, o);
        pb0 += __shfl_xor(pb0, o); pb1 += __shfl_xor(pb1, o);
    }
    if (lane == 0) {
        out[row] = 1.f / (1.f + expf((n0 + bna[0]) - (n1 + bna[1])));
        proj[row * 4 + 0] = pa0;
        proj[row * 4 + 1] = pa1;
        proj[row * 4 + 2] = pb0;
        proj[row * 4 + 3] = pb1;
    }
}

// ---------------- edge attention from projection tables ----------------
__global__ __launch_bounds__(256) void k_edge_final(const int* __restrict__ ei,
                                                    const float* __restrict__ proj,
                                                    const float* __restrict__ bea,
                                                    float* __restrict__ out) {
    int e = blockIdx.x * 256 + threadIdx.x;
    if (e >= NEDGES) return;
    int src = ei[e], dst = ei[NEDGES + e];
    float4 ps = *(const float4*)&proj[src * 4];
    float4 pd = *(const float4*)&proj[dst * 4];
    float s0 = ps.x + pd.z + bea[0];
    float s1 = ps.y + pd.w + bea[1];
    out[NNODES + e] = 1.f / (1.f + expf(s0 - s1));
}

// ---------------- vt += segment_sum(hin) over contiguous row chunks ----------------
__global__ __launch_bounds__(256) void k_vt(const float* __restrict__ hin,
                                            const int* __restrict__ batch,
                                            float* __restrict__ vt) {
    int wave = threadIdx.x >> 6, lane = threadIdx.x & 63;
    int wid = blockIdx.x * 4 + wave;
    int r0 = wid * 64;
    if (r0 >= NNODES) return;
    int r1 = min(r0 + 64, NNODES);
    int g = batch[r0];
    float acc = 0.f;
    for (int r = r0; r < r1; ++r) {
        int gb = batch[r];
        if (gb != g) {
            atomicAdd(&vt[g * D + lane], acc);
            acc = 0.f; g = gb;
        }
        acc += hin[r * D + lane];
    }
    atomicAdd(&vt[g * D + lane], acc);
}

// ---------------- virtual-node MLP (one block); reads vt+vn, writes vn ----------------
__global__ __launch_bounds__(256) void k_vnmlp(const float* __restrict__ vt,
                                               const float* __restrict__ Wv1,
                                               const float* __restrict__ bv1,
                                               const float* __restrict__ Wv2,
                                               const float* __restrict__ bv2, int l,
                                               float* __restrict__ vn) {
    __shared__ float sV[NG * D];
    __shared__ float sU[NG * D2];
    const float* W1p = Wv1 + l * D * D2;
    const float* W2p = Wv2 + l * D2 * D;
    for (int i = threadIdx.x; i < NG * D; i += 256) sV[i] = vt[i] + vn[i];
    __syncthreads();
    {
        int r = threadIdx.x >> 2, cb = (threadIdx.x & 3) * 32;
        float acc[32];
#pragma unroll
        for (int c = 0; c < 32; ++c) acc[c] = bv1[l * D2 + cb + c];
        for (int k = 0; k < D; ++k) {
            float v = sV[r * D + k];
#pragma unroll
            for (int c = 0; c < 32; ++c) acc[c] += v * W1p[k * D2 + cb + c];
        }
#pragma unroll
        for (int c = 0; c < 32; ++c) sU[r * D2 + cb + c] = acc[c];
    }
    __syncthreads();
    if (threadIdx.x < D2) {
        int c = threadIdx.x;
        float s = 0, sq = 0;
        for (int r = 0; r < NG; ++r) { float v = sU[r * D2 + c]; s += v; sq += v * v; }
        float mu = s / NG, rstd = rsqrtf(sq / NG - mu * mu + BN_EPS);
        for (int r = 0; r < NG; ++r)
            sU[r * D2 + c] = fmaxf((sU[r * D2 + c] - mu) * rstd + BN_BIAS, 0.f);
    }
    __syncthreads();
    {
        int r = threadIdx.x >> 2, cb = (threadIdx.x & 3) * 16;
        float acc[16];
#pragma unroll
        for (int c = 0; c < 16; ++c) acc[c] = bv2[l * D + cb + c];
        for (int k = 0; k < D2; ++k) {
            float v = sU[r * D2 + k];
#pragma unroll
            for (int c = 0; c < 16; ++c) acc[c] += v * W2p[k * D + cb + c];
        }
#pragma unroll
        for (int c = 0; c < 16; ++c) sV[r * D + cb + c] = acc[c];
    }
    __syncthreads();
    if (threadIdx.x < D) {
        int c = threadIdx.x;
        float s = 0, sq = 0;
        for (int r = 0; r < NG; ++r) { float v = sV[r * D + c]; s += v; sq += v * v; }
        float mu = s / NG, rstd = rsqrtf(sq / NG - mu * mu + BN_EPS);
        for (int r = 0; r < NG; ++r)
            vn[r * D + c] = fmaxf((sV[r * D + c] - mu) * rstd + BN_BIAS, 0.f);
    }
}

extern "C" void kernel_launch(void* const* d_in, const int* in_sizes, int n_in,
                              void* d_out, int out_size, void* d_ws, size_t ws_size,
                              hipStream_t stream) {
    const float* x    = (const float*)d_in[0];
    const float* ea   = (const float*)d_in[1];
    const int*   ei   = (const int*)d_in[2];
    const int*   batch= (const int*)d_in[3];
    const float* Wenc = (const float*)d_in[4];
    const float* benc = (const float*)d_in[5];
    const float* We   = (const float*)d_in[6];
    const float* be   = (const float*)d_in[7];
    const float* eps  = (const float*)d_in[8];
    const float* W1   = (const float*)d_in[9];
    const float* b1   = (const float*)d_in[10];
    const float* W2   = (const float*)d_in[11];
    const float* b2   = (const float*)d_in[12];
    const float* Wv1  = (const float*)d_in[13];
    const float* bv1  = (const float*)d_in[14];
    const float* Wv2  = (const float*)d_in[15];
    const float* bv2  = (const float*)d_in[16];
    const float* Wea  = (const float*)d_in[17];
    const float* bea  = (const float*)d_in[18];
    const float* Wna  = (const float*)d_in[19];
    const float* bna  = (const float*)d_in[20];
    float* out = (float*)d_out;

    float* ws   = (float*)d_ws;
    float* hin  = ws;                              // [N*D]
    float* zin  = hin + (size_t)NNODES * D;        // [N*D]  (z2 overlays zin)
    float* t    = zin + (size_t)NNODES * D;        // [N*D2]
    float* proj = t   + (size_t)NNODES * D2;       // [N*4]
    __hip_bfloat16* hbf  = (__hip_bfloat16*)(proj + (size_t)NNODES * 4);   // [N*D]
    __hip_bfloat16* ea_s = hbf + (size_t)NNODES * D;                       // [E*EPAD]
    // ---- contiguous zero-region: vn | vt0 | vt1 | stats(1536) | deg ----
    float* vn    = (float*)(ea_s + (size_t)NEDGES * EPAD);
    float* vt0   = vn  + NG * D;
    float* vt1   = vt0 + NG * D;
    float* stats = vt1 + NG * D;                   // statsA: l*256 (0..767); statsB: 768+l*128
    int*   deg   = (int*)(stats + 1536);
    // ---- end zero-region ----
    int*   off    = deg + NNODES;
    int*   cursor = off + NNODES + 1;
    int*   esrc   = cursor + NNODES;
    int*   bsum   = esrc + NEDGES;
    int*   bbase  = bsum + NSB;

    float* z2 = zin;   // overlay: zin dead after gemm1

    size_t zero_bytes = (size_t)(3 * NG * D + 1536) * 4 + (size_t)NNODES * 4;
    hipMemsetAsync(vn, 0, zero_bytes, stream);
    k_enc<<<NNODES / 4, 256, 0, stream>>>(x, Wenc, benc, hin, hbf);
    k_hist<<<(NEDGES + 255) / 256, 256, 0, stream>>>(ei, deg);
    k_scansum<<<NSB, 256, 0, stream>>>(deg, bsum);
    k_scanbase<<<1, 256, 0, stream>>>(bsum, bbase, off);
    k_scanwrite<<<NSB, 256, 0, stream>>>(deg, bbase, off, cursor);
    k_scatter<<<(NEDGES + 255) / 256, 256, 0, stream>>>(ei, ea, cursor, esrc, ea_s);

    for (int l = 0; l < 3; ++l) {
        float* statsA = stats + l * 256;
        float* statsB = stats + 768 + l * 128;
        if (l < 2) {
            float* vtb = (l == 0) ? vt0 : vt1;
            k_vt<<<(NNODES / 64 + 4) / 4, 256, 0, stream>>>(hin, batch, vtb);
            k_agg<<<(NNODES + 3) / 4, 256, 0, stream>>>(ea_s, off, esrc, We, be, eps, l,
                                                        hin, hbf, zin);
            k_vnmlp<<<1, 256, 0, stream>>>(vtb, Wv1, bv1, Wv2, bv2, l, vn);
        } else {
            k_agg<<<(NNODES + 3) / 4, 256, 0, stream>>>(ea_s, off, esrc, We, be, eps, l,
                                                        hin, hbf, zin);
        }
        k_gemm1<<<(NNODES + 63) / 64, 256, 0, stream>>>(zin, W1, b1, l, t, statsA);
        k_gemm2<<<(NNODES + 31) / 32, 256, 0, stream>>>(t, statsA, W2, b2, l, z2, statsB);
        if (l < 2) {
            k_bnprep<<<NNODES * D / 256, 256, 0, stream>>>(z2, statsB, vn, batch, hin, hbf);
        } else {
            k_finish_att_proj<<<NNODES / 4, 256, 0, stream>>>(z2, statsB, Wna, bna, Wea,
                                                              proj, out);
        }
    }
    k_edge_final<<<(NEDGES + 255) / 256, 256, 0, stream>>>(ei, proj, bea, out);
}

// Round 7
// 798.312 us; speedup vs baseline: 1.7869x; 1.2223x over previous
//
#include <hip/hip_runtime.h>
#include <hip/hip_bf16.h>

#define NNODES 50000
#define NEDGES 800000
#define NG 64
#define D 64
#define D2 128
#define INDIM 39
#define EDIM 10
#define EPAD 12            // padded bf16 elems per ea_s row (24B, 8B-aligned)
#define BN_EPS 1e-5f
#define BN_BIAS 1e-4f
#define NSB ((NNODES + 255) / 256)   // 196 scan blocks

__device__ __forceinline__ float blo(unsigned u) {
    union { unsigned i; float f; } c; c.i = u << 16; return c.f;
}
__device__ __forceinline__ float bhi(unsigned u) {
    union { unsigned i; float f; } c; c.i = u & 0xffff0000u; return c.f;
}

// ---------------- encoder: hin = x @ Wenc + benc (+ bf16 shadow) ----------------
__global__ __launch_bounds__(256) void k_enc(const float* __restrict__ x,
                                             const float* __restrict__ Wenc,
                                             const float* __restrict__ benc,
                                             float* __restrict__ hin,
                                             __hip_bfloat16* __restrict__ hbf) {
    __shared__ float sW[INDIM * D];
    for (int i = threadIdx.x; i < INDIM * D; i += 256) sW[i] = Wenc[i];
    __syncthreads();
    int wave = threadIdx.x >> 6, lane = threadIdx.x & 63;
    int row = blockIdx.x * 4 + wave;
    if (row >= NNODES) return;
    float xv = (lane < INDIM) ? x[row * INDIM + lane] : 0.f;
    float acc = benc[lane];
#pragma unroll
    for (int k = 0; k < INDIM; ++k) acc += __shfl(xv, k) * sW[k * D + lane];
    hin[row * D + lane] = acc;
    hbf[row * D + lane] = __float2bfloat16(acc);
}

// ---------------- CSR build ----------------
__global__ __launch_bounds__(256) void k_hist(const int* __restrict__ ei,
                                              int* __restrict__ deg) {
    int e = blockIdx.x * 256 + threadIdx.x;
    if (e < NEDGES) atomicAdd(&deg[ei[NEDGES + e]], 1);
}

__global__ __launch_bounds__(256) void k_scansum(const int* __restrict__ deg,
                                                 int* __restrict__ bsum) {
    int i = blockIdx.x * 256 + threadIdx.x;
    int v = (i < NNODES) ? deg[i] : 0;
#pragma unroll
    for (int o = 32; o; o >>= 1) v += __shfl_xor(v, o);
    __shared__ int ws[4];
    if ((threadIdx.x & 63) == 0) ws[threadIdx.x >> 6] = v;
    __syncthreads();
    if (threadIdx.x == 0) bsum[blockIdx.x] = ws[0] + ws[1] + ws[2] + ws[3];
}

__global__ __launch_bounds__(256) void k_scanbase(const int* __restrict__ bsum,
                                                  int* __restrict__ bbase,
                                                  int* __restrict__ off) {
    __shared__ int s[256];
    int t = threadIdx.x;
    int v = (t < NSB) ? bsum[t] : 0;
    s[t] = v;
    __syncthreads();
    for (int o = 1; o < 256; o <<= 1) {
        int u = (t >= o) ? s[t - o] : 0;
        __syncthreads();
        s[t] += u;
        __syncthreads();
    }
    if (t < NSB) bbase[t] = s[t] - v;
    if (t == 255) off[NNODES] = s[255];
}

__global__ __launch_bounds__(256) void k_scanwrite(const int* __restrict__ deg,
                                                   const int* __restrict__ bbase,
                                                   int* __restrict__ off,
                                                   int* __restrict__ cursor) {
    __shared__ int s[256];
    int t = threadIdx.x;
    int i = blockIdx.x * 256 + t;
    int v = (i < NNODES) ? deg[i] : 0;
    s[t] = v;
    __syncthreads();
    for (int o = 1; o < 256; o <<= 1) {
        int u = (t >= o) ? s[t - o] : 0;
        __syncthreads();
        s[t] += u;
        __syncthreads();
    }
    int excl = bbase[blockIdx.x] + s[t] - v;
    if (i < NNODES) { off[i] = excl; cursor[i] = excl; }
}

// scatter src index AND edge_attr (bf16, 24B padded row) into CSR order
__global__ __launch_bounds__(256) void k_scatter(const int* __restrict__ ei,
                                                 const float* __restrict__ ea,
                                                 int* __restrict__ cursor,
                                                 int* __restrict__ esrc,
                                                 __hip_bfloat16* __restrict__ ea_s) {
    int e = blockIdx.x * 256 + threadIdx.x;
    if (e >= NEDGES) return;
    int d = ei[NEDGES + e];
    int p = atomicAdd(&cursor[d], 1);
    esrc[p] = ei[e];
    unsigned u[5];
#pragma unroll
    for (int i = 0; i < 5; ++i) {
        __hip_bfloat16 b0 = __float2bfloat16(ea[e * EDIM + 2 * i]);
        __hip_bfloat16 b1 = __float2bfloat16(ea[e * EDIM + 2 * i + 1]);
        u[i] = ((unsigned)*(unsigned short*)&b1 << 16) | (unsigned)*(unsigned short*)&b0;
    }
    unsigned* dst = (unsigned*)(ea_s + (size_t)p * EPAD);
    *(uint2*)(dst) = make_uint2(u[0], u[1]);
    *(uint2*)(dst + 2) = make_uint2(u[2], u[3]);
    dst[4] = u[4];
}

// ---------------- aggregate (no LDS, no shfl): zin[n] = (1+eps)*hin[n] + sum relu(...) ----
__global__ __launch_bounds__(256) void k_agg(const __hip_bfloat16* __restrict__ ea_s,
                                             const int* __restrict__ off,
                                             const int* __restrict__ esrc,
                                             const float* __restrict__ We,
                                             const float* __restrict__ be,
                                             const float* __restrict__ eps, int l,
                                             const float* __restrict__ hin,
                                             const __hip_bfloat16* __restrict__ hbf,
                                             float* __restrict__ zin) {
    int wave = threadIdx.x >> 6, lane = threadIdx.x & 63;
    int n = blockIdx.x * 4 + wave;
    if (n >= NNODES) return;
    const float* Wl = We + l * EDIM * D;
    float w[EDIM];
#pragma unroll
    for (int k = 0; k < EDIM; ++k) w[k] = Wl[k * D + lane];
    float bias = be[l * D + lane];
    int beg = off[n], end = off[n + 1];
    float acc = (1.f + eps[l]) * hin[n * D + lane];
    const unsigned* eap = (const unsigned*)ea_s;
    int j = beg;
#define EMB(a, b, c, m)                                                          \
    {                                                                            \
        m = bias;                                                                \
        m += blo(a.x) * w[0] + bhi(a.x) * w[1] + blo(a.y) * w[2] + bhi(a.y) * w[3]; \
        m += blo(b.x) * w[4] + bhi(b.x) * w[5] + blo(b.y) * w[6] + bhi(b.y) * w[7]; \
        m += blo(c) * w[8] + bhi(c) * w[9];                                      \
    }
    for (; j + 3 < end; j += 4) {
        int s0 = esrc[j], s1 = esrc[j + 1], s2 = esrc[j + 2], s3 = esrc[j + 3];
        float hv0 = __bfloat162float(hbf[(size_t)s0 * D + lane]);
        float hv1 = __bfloat162float(hbf[(size_t)s1 * D + lane]);
        float hv2 = __bfloat162float(hbf[(size_t)s2 * D + lane]);
        float hv3 = __bfloat162float(hbf[(size_t)s3 * D + lane]);
        const unsigned* e0 = eap + (size_t)j * 6;
        uint2 a0 = *(const uint2*)(e0), b0 = *(const uint2*)(e0 + 2); unsigned c0 = e0[4];
        uint2 a1 = *(const uint2*)(e0 + 6), b1 = *(const uint2*)(e0 + 8); unsigned c1 = e0[10];
        uint2 a2 = *(const uint2*)(e0 + 12), b2 = *(const uint2*)(e0 + 14); unsigned c2 = e0[16];
        uint2 a3 = *(const uint2*)(e0 + 18), b3 = *(const uint2*)(e0 + 20); unsigned c3 = e0[22];
        float m0, m1, m2, m3;
        EMB(a0, b0, c0, m0) EMB(a1, b1, c1, m1) EMB(a2, b2, c2, m2) EMB(a3, b3, c3, m3)
        acc += fmaxf(m0 + hv0, 0.f) + fmaxf(m1 + hv1, 0.f) +
               fmaxf(m2 + hv2, 0.f) + fmaxf(m3 + hv3, 0.f);
    }
    for (; j < end; ++j) {
        int src = esrc[j];
        float hv = __bfloat162float(hbf[(size_t)src * D + lane]);
        const unsigned* e0 = eap + (size_t)j * 6;
        uint2 a = *(const uint2*)(e0), b = *(const uint2*)(e0 + 2); unsigned c = e0[4];
        float m;
        EMB(a, b, c, m)
        acc += fmaxf(m + hv, 0.f);
    }
#undef EMB
    zin[n * D + lane] = acc;
}

// ---------------- GEMM1: t = zin @ W1 + b1 (+ BN stats of t) ----------------
__global__ __launch_bounds__(256) void k_gemm1(const float* __restrict__ zin,
                                               const float* __restrict__ W1,
                                               const float* __restrict__ b1, int l,
                                               float* __restrict__ t,
                                               float* __restrict__ stats1) {
    __shared__ float sZ[64 * D];
    __shared__ float sW[D * D2];
    __shared__ float sSum[D2], sSq[D2];
    const float* Wp = W1 + l * D * D2;
    int row0 = blockIdx.x * 64;
    int nvalid = min(64, NNODES - row0);
    for (int i = threadIdx.x; i < D * D2; i += 256) sW[i] = Wp[i];
    for (int i = threadIdx.x; i < 64 * D; i += 256) {
        int r = i >> 6;
        sZ[i] = (r < nvalid) ? zin[(row0 + r) * D + (i & 63)] : 0.f;
    }
    if (threadIdx.x < D2) { sSum[threadIdx.x] = 0.f; sSq[threadIdx.x] = 0.f; }
    __syncthreads();
    int cg = threadIdx.x & 31;
    int rg = threadIdx.x >> 5;
    float4 binit = *(const float4*)&b1[l * D2 + cg * 4];
    float4 acc[8];
#pragma unroll
    for (int r = 0; r < 8; ++r) acc[r] = binit;
    for (int k = 0; k < D; ++k) {
        float4 w = *(const float4*)&sW[k * D2 + cg * 4];
#pragma unroll
        for (int r = 0; r < 8; ++r) {
            float a = sZ[(rg * 8 + r) * D + k];
            acc[r].x += a * w.x; acc[r].y += a * w.y;
            acc[r].z += a * w.z; acc[r].w += a * w.w;
        }
    }
    float4 s = {0, 0, 0, 0}, sq = {0, 0, 0, 0};
#pragma unroll
    for (int r = 0; r < 8; ++r) {
        int row = rg * 8 + r;
        if (row < nvalid) {
            *(float4*)&t[(row0 + row) * D2 + cg * 4] = acc[r];
            s.x += acc[r].x; s.y += acc[r].y; s.z += acc[r].z; s.w += acc[r].w;
            sq.x += acc[r].x * acc[r].x; sq.y += acc[r].y * acc[r].y;
            sq.z += acc[r].z * acc[r].z; sq.w += acc[r].w * acc[r].w;
        }
    }
    atomicAdd(&sSum[cg * 4 + 0], s.x); atomicAdd(&sSq[cg * 4 + 0], sq.x);
    atomicAdd(&sSum[cg * 4 + 1], s.y); atomicAdd(&sSq[cg * 4 + 1], sq.y);
    atomicAdd(&sSum[cg * 4 + 2], s.z); atomicAdd(&sSq[cg * 4 + 2], sq.z);
    atomicAdd(&sSum[cg * 4 + 3], s.w); atomicAdd(&sSq[cg * 4 + 3], sq.w);
    __syncthreads();
    if (threadIdx.x < D2) {
        atomicAdd(&stats1[threadIdx.x], sSum[threadIdx.x]);
        atomicAdd(&stats1[D2 + threadIdx.x], sSq[threadIdx.x]);
    }
}

// ---------------- GEMM2: z2 = relu(bn(t)) @ W2 + b2 (+ BN stats of z2) ----------------
__global__ __launch_bounds__(256) void k_gemm2(const float* __restrict__ t,
                                               const float* __restrict__ stats1,
                                               const float* __restrict__ W2,
                                               const float* __restrict__ b2, int l,
                                               float* __restrict__ z2,
                                               float* __restrict__ stats2) {
    __shared__ float sT[32 * D2];
    __shared__ float sW[D2 * D];
    __shared__ float sSum[D], sSq[D];
    const float* Wp = W2 + l * D2 * D;
    int row0 = blockIdx.x * 32;
    int nvalid = min(32, NNODES - row0);
    for (int i = threadIdx.x; i < D2 * D; i += 256) sW[i] = Wp[i];
    const float invN = 1.f / NNODES;
    for (int i = threadIdx.x; i < 32 * D2; i += 256) {
        int r = i >> 7, c = i & 127;
        float v = 0.f;
        if (r < nvalid) {
            float mu = stats1[c] * invN;
            float var = stats1[D2 + c] * invN - mu * mu;
            float rstd = rsqrtf(var + BN_EPS);
            v = (t[(row0 + r) * D2 + c] - mu) * rstd + BN_BIAS;
            v = fmaxf(v, 0.f);
        }
        sT[i] = v;
    }
    if (threadIdx.x < D) { sSum[threadIdx.x] = 0.f; sSq[threadIdx.x] = 0.f; }
    __syncthreads();
    int cg = threadIdx.x & 31;
    int rg = threadIdx.x >> 5;
    float2 binit = *(const float2*)&b2[l * D + cg * 2];
    float2 acc[4];
#pragma unroll
    for (int r = 0; r < 4; ++r) acc[r] = binit;
    for (int k = 0; k < D2; ++k) {
        float2 w = *(const float2*)&sW[k * D + cg * 2];
#pragma unroll
        for (int r = 0; r < 4; ++r) {
            float a = sT[(rg * 4 + r) * D2 + k];
            acc[r].x += a * w.x; acc[r].y += a * w.y;
        }
    }
    float2 s = {0, 0}, sq = {0, 0};
#pragma unroll
    for (int r = 0; r < 4; ++r) {
        int row = rg * 4 + r;
        if (row < nvalid) {
            *(float2*)&z2[(row0 + row) * D + cg * 2] = acc[r];
            s.x += acc[r].x; s.y += acc[r].y;
            sq.x += acc[r].x * acc[r].x; sq.y += acc[r].y * acc[r].y;
        }
    }
    atomicAdd(&sSum[cg * 2 + 0], s.x); atomicAdd(&sSq[cg * 2 + 0], sq.x);
    atomicAdd(&sSum[cg * 2 + 1], s.y); atomicAdd(&sSq[cg * 2 + 1], sq.y);
    __syncthreads();
    if (threadIdx.x < D) {
        atomicAdd(&stats2[threadIdx.x], sSum[threadIdx.x]);
        atomicAdd(&stats2[D + threadIdx.x], sSq[threadIdx.x]);
    }
}

// ---------------- fused: hin = relu(bn(z2)) + vn[batch] (+ bf16 shadow) ----------------
__global__ __launch_bounds__(256) void k_bnprep(const float* __restrict__ z2,
                                                const float* __restrict__ stats2,
                                                const float* __restrict__ vn,
                                                const int* __restrict__ batch,
                                                float* __restrict__ hin,
                                                __hip_bfloat16* __restrict__ hbf) {
    int idx = blockIdx.x * 256 + threadIdx.x;
    if (idx >= NNODES * D) return;
    int c = idx & 63, row = idx >> 6;
    const float invN = 1.f / NNODES;
    float mu = stats2[c] * invN;
    float var = stats2[D + c] * invN - mu * mu;
    float rstd = rsqrtf(var + BN_EPS);
    float v = (z2[idx] - mu) * rstd + BN_BIAS;
    v = fmaxf(v, 0.f);
    v += vn[batch[row] * D + c];
    hin[idx] = v;
    hbf[idx] = __float2bfloat16(v);
}

// ---------------- fused final: bn(z2) -> node att + per-node edge projections ----------------
__global__ __launch_bounds__(256) void k_finish_att_proj(const float* __restrict__ z2,
                                                         const float* __restrict__ stats2,
                                                         const float* __restrict__ Wna,
                                                         const float* __restrict__ bna,
                                                         const float* __restrict__ Wea,
                                                         float* __restrict__ proj,
                                                         float* __restrict__ out) {
    int wave = threadIdx.x >> 6, lane = threadIdx.x & 63;
    int row = blockIdx.x * 4 + wave;
    if (row >= NNODES) return;
    const float invN = 1.f / NNODES;
    float mu = stats2[lane] * invN;
    float var = stats2[D + lane] * invN - mu * mu;
    float rstd = rsqrtf(var + BN_EPS);
    float v = (z2[row * D + lane] - mu) * rstd + BN_BIAS;
    float n0 = v * Wna[lane * 2 + 0];
    float n1 = v * Wna[lane * 2 + 1];
    float pa0 = v * Wea[lane * 2 + 0];
    float pa1 = v * Wea[lane * 2 + 1];
    float pb0 = v * Wea[(D + lane) * 2 + 0];
    float pb1 = v * Wea[(D + lane) * 2 + 1];
#pragma unroll
    for (int o = 32; o; o >>= 1) {
        n0 += __shfl_xor(n0, o); n1 += __shfl_xor(n1, o);
        pa0 += __shfl_xor(pa0, o); pa1 += __shfl_xor(pa1, o);
        pb0 += __shfl_xor(pb0, o); pb1 += __shfl_xor(pb1, o);
    }
    if (lane == 0) {
        out[row] = 1.f / (1.f + expf((n0 + bna[0]) - (n1 + bna[1])));
        proj[row * 4 + 0] = pa0;
        proj[row * 4 + 1] = pa1;
        proj[row * 4 + 2] = pb0;
        proj[row * 4 + 3] = pb1;
    }
}

// ---------------- edge attention from projection tables ----------------
__global__ __launch_bounds__(256) void k_edge_final(const int* __restrict__ ei,
                                                    const float* __restrict__ proj,
                                                    const float* __restrict__ bea,
                                                    float* __restrict__ out) {
    int e = blockIdx.x * 256 + threadIdx.x;
    if (e >= NEDGES) return;
    int src = ei[e], dst = ei[NEDGES + e];
    float4 ps = *(const float4*)&proj[src * 4];
    float4 pd = *(const float4*)&proj[dst * 4];
    float s0 = ps.x + pd.z + bea[0];
    float s1 = ps.y + pd.w + bea[1];
    out[NNODES + e] = 1.f / (1.f + expf(s0 - s1));
}

// ---------------- vt += segment_sum(hin) over contiguous row chunks ----------------
__global__ __launch_bounds__(256) void k_vt(const float* __restrict__ hin,
                                            const int* __restrict__ batch,
                                            float* __restrict__ vt) {
    int wave = threadIdx.x >> 6, lane = threadIdx.x & 63;
    int wid = blockIdx.x * 4 + wave;
    int r0 = wid * 64;
    if (r0 >= NNODES) return;
    int r1 = min(r0 + 64, NNODES);
    int g = batch[r0];
    float acc = 0.f;
    for (int r = r0; r < r1; ++r) {
        int gb = batch[r];
        if (gb != g) {
            atomicAdd(&vt[g * D + lane], acc);
            acc = 0.f; g = gb;
        }
        acc += hin[r * D + lane];
    }
    atomicAdd(&vt[g * D + lane], acc);
}

// ---------------- vn-MLP stage 1: ucm[col][row] = relu(bn((vt+vn) @ Wv1 + bv1)) ----------------
// 32 blocks x 256 thr; wave = one output column, lane = row. Exact column BN via shfl.
__global__ __launch_bounds__(256) void k_vn1(const float* __restrict__ vt,
                                             const float* __restrict__ vn,
                                             const float* __restrict__ Wv1,
                                             const float* __restrict__ bv1, int l,
                                             float* __restrict__ ucm) {
    __shared__ float sV[NG * 65];
    __shared__ float sW[NG * 4];
    int c0 = blockIdx.x * 4;
    for (int i = threadIdx.x; i < NG * D; i += 256) {
        int r = i >> 6, c = i & 63;
        sV[r * 65 + c] = vt[i] + vn[i];
    }
    {
        int k = threadIdx.x >> 2, c = threadIdx.x & 3;
        sW[threadIdx.x] = Wv1[l * D * D2 + k * D2 + c0 + c];
    }
    __syncthreads();
    int lane = threadIdx.x & 63, w = threadIdx.x >> 6;
    float acc = bv1[l * D2 + c0 + w];
#pragma unroll
    for (int k = 0; k < D; ++k) acc += sV[lane * 65 + k] * sW[k * 4 + w];
    float s = acc, sq = acc * acc;
#pragma unroll
    for (int o = 32; o; o >>= 1) { s += __shfl_xor(s, o); sq += __shfl_xor(sq, o); }
    float mu = s * (1.f / NG);
    float rstd = rsqrtf(sq * (1.f / NG) - mu * mu + BN_EPS);
    ucm[(c0 + w) * NG + lane] = fmaxf((acc - mu) * rstd + BN_BIAS, 0.f);
}

// ---------------- vn-MLP stage 2: vn = relu(bn(ucm^T @ Wv2 + bv2)) ----------------
// 16 blocks x 256 thr; wave = one output column, lane = row.
__global__ __launch_bounds__(256) void k_vn2(const float* __restrict__ ucm,
                                             const float* __restrict__ Wv2,
                                             const float* __restrict__ bv2, int l,
                                             float* __restrict__ vn) {
    __shared__ float sU[D2 * NG];   // [k][row]; lane-stride 1 -> conflict-free
    __shared__ float sW[D2 * 4];
    int c0 = blockIdx.x * 4;
    for (int i = threadIdx.x; i < D2 * NG; i += 256) sU[i] = ucm[i];
    for (int i = threadIdx.x; i < D2 * 4; i += 256) {
        int k = i >> 2, c = i & 3;
        sW[i] = Wv2[l * D2 * D + k * D + c0 + c];
    }
    __syncthreads();
    int lane = threadIdx.x & 63, w = threadIdx.x >> 6;
    float acc = bv2[l * D + c0 + w];
#pragma unroll
    for (int k = 0; k < D2; ++k) acc += sU[k * NG + lane] * sW[k * 4 + w];
    float s = acc, sq = acc * acc;
#pragma unroll
    for (int o = 32; o; o >>= 1) { s += __shfl_xor(s, o); sq += __shfl_xor(sq, o); }
    float mu = s * (1.f / NG);
    float rstd = rsqrtf(sq * (1.f / NG) - mu * mu + BN_EPS);
    vn[lane * D + c0 + w] = fmaxf((acc - mu) * rstd + BN_BIAS, 0.f);
}

extern "C" void kernel_launch(void* const* d_in, const int* in_sizes, int n_in,
                              void* d_out, int out_size, void* d_ws, size_t ws_size,
                              hipStream_t stream) {
    const float* x    = (const float*)d_in[0];
    const float* ea   = (const float*)d_in[1];
    const int*   ei   = (const int*)d_in[2];
    const int*   batch= (const int*)d_in[3];
    const float* Wenc = (const float*)d_in[4];
    const float* benc = (const float*)d_in[5];
    const float* We   = (const float*)d_in[6];
    const float* be   = (const float*)d_in[7];
    const float* eps  = (const float*)d_in[8];
    const float* W1   = (const float*)d_in[9];
    const float* b1   = (const float*)d_in[10];
    const float* W2   = (const float*)d_in[11];
    const float* b2   = (const float*)d_in[12];
    const float* Wv1  = (const float*)d_in[13];
    const float* bv1  = (const float*)d_in[14];
    const float* Wv2  = (const float*)d_in[15];
    const float* bv2  = (const float*)d_in[16];
    const float* Wea  = (const float*)d_in[17];
    const float* bea  = (const float*)d_in[18];
    const float* Wna  = (const float*)d_in[19];
    const float* bna  = (const float*)d_in[20];
    float* out = (float*)d_out;

    float* ws   = (float*)d_ws;
    float* hin  = ws;                              // [N*D]
    float* zin  = hin + (size_t)NNODES * D;        // [N*D]  (z2 overlays zin)
    float* t    = zin + (size_t)NNODES * D;        // [N*D2]
    float* proj = t   + (size_t)NNODES * D2;       // [N*4]
    __hip_bfloat16* hbf  = (__hip_bfloat16*)(proj + (size_t)NNODES * 4);   // [N*D]
    __hip_bfloat16* ea_s = hbf + (size_t)NNODES * D;                       // [E*EPAD]
    // ---- contiguous zero-region: vn | vt0 | vt1 | stats(1536) | deg ----
    float* vn    = (float*)(ea_s + (size_t)NEDGES * EPAD);
    float* vt0   = vn  + NG * D;
    float* vt1   = vt0 + NG * D;
    float* stats = vt1 + NG * D;                   // statsA: l*256 (0..767); statsB: 768+l*128
    int*   deg   = (int*)(stats + 1536);
    // ---- end zero-region ----
    int*   off    = deg + NNODES;
    int*   cursor = off + NNODES + 1;
    int*   esrc   = cursor + NNODES;
    int*   bsum   = esrc + NEDGES;
    int*   bbase  = bsum + NSB;
    float* ucm    = (float*)(bbase + NSB);         // [D2*NG]

    float* z2 = zin;   // overlay: zin dead after gemm1

    size_t zero_bytes = (size_t)(3 * NG * D + 1536) * 4 + (size_t)NNODES * 4;
    hipMemsetAsync(vn, 0, zero_bytes, stream);
    k_enc<<<NNODES / 4, 256, 0, stream>>>(x, Wenc, benc, hin, hbf);
    k_hist<<<(NEDGES + 255) / 256, 256, 0, stream>>>(ei, deg);
    k_scansum<<<NSB, 256, 0, stream>>>(deg, bsum);
    k_scanbase<<<1, 256, 0, stream>>>(bsum, bbase, off);
    k_scanwrite<<<NSB, 256, 0, stream>>>(deg, bbase, off, cursor);
    k_scatter<<<(NEDGES + 255) / 256, 256, 0, stream>>>(ei, ea, cursor, esrc, ea_s);

    for (int l = 0; l < 3; ++l) {
        float* statsA = stats + l * 256;
        float* statsB = stats + 768 + l * 128;
        if (l < 2) {
            float* vtb = (l == 0) ? vt0 : vt1;
            k_vt<<<(NNODES / 64 + 4) / 4, 256, 0, stream>>>(hin, batch, vtb);
            k_agg<<<(NNODES + 3) / 4, 256, 0, stream>>>(ea_s, off, esrc, We, be, eps, l,
                                                        hin, hbf, zin);
            k_vn1<<<32, 256, 0, stream>>>(vtb, vn, Wv1, bv1, l, ucm);
            k_vn2<<<16, 256, 0, stream>>>(ucm, Wv2, bv2, l, vn);
        } else {
            k_agg<<<(NNODES + 3) / 4, 256, 0, stream>>>(ea_s, off, esrc, We, be, eps, l,
                                                        hin, hbf, zin);
        }
        k_gemm1<<<(NNODES + 63) / 64, 256, 0, stream>>>(zin, W1, b1, l, t, statsA);
        k_gemm2<<<(NNODES + 31) / 32, 256, 0, stream>>>(t, statsA, W2, b2, l, z2, statsB);
        if (l < 2) {
            k_bnprep<<<NNODES * D / 256, 256, 0, stream>>>(z2, statsB, vn, batch, hin, hbf);
        } else {
            k_finish_att_proj<<<NNODES / 4, 256, 0, stream>>>(z2, statsB, Wna, bna, Wea,
                                                              proj, out);
        }
    }
    k_edge_final<<<(NEDGES + 255) / 256, 256, 0, stream>>>(ei, proj, bea, out);
}

// Round 8
// 746.918 us; speedup vs baseline: 1.9099x; 1.0688x over previous
//
#include <hip/hip_runtime.h>
#include <hip/hip_bf16.h>

#define NNODES 50000
#define NEDGES 800000
#define NG 64
#define D 64
#define D2 128
#define INDIM 39
#define EDIM 10
#define EPW 32             // edges per wave in k_agg
#define BN_EPS 1e-5f
#define BN_BIAS 1e-4f
#define NSB ((NNODES + 255) / 256)   // 196 scan blocks

__device__ __forceinline__ float blo(unsigned u) {
    union { unsigned i; float f; } c; c.i = u << 16; return c.f;
}
__device__ __forceinline__ float bhi(unsigned u) {
    union { unsigned i; float f; } c; c.i = u & 0xffff0000u; return c.f;
}

// ---------------- encoder: hin = x @ Wenc + benc (+ bf16 shadow, + zin init) ----------------
__global__ __launch_bounds__(256) void k_enc(const float* __restrict__ x,
                                             const float* __restrict__ Wenc,
                                             const float* __restrict__ benc,
                                             const float* __restrict__ eps,
                                             float* __restrict__ hin,
                                             __hip_bfloat16* __restrict__ hbf,
                                             float* __restrict__ zin) {
    __shared__ float sW[INDIM * D];
    for (int i = threadIdx.x; i < INDIM * D; i += 256) sW[i] = Wenc[i];
    __syncthreads();
    int wave = threadIdx.x >> 6, lane = threadIdx.x & 63;
    int row = blockIdx.x * 4 + wave;
    if (row >= NNODES) return;
    float xv = (lane < INDIM) ? x[row * INDIM + lane] : 0.f;
    float acc = benc[lane];
#pragma unroll
    for (int k = 0; k < INDIM; ++k) acc += __shfl(xv, k) * sW[k * D + lane];
    hin[row * D + lane] = acc;
    hbf[row * D + lane] = __float2bfloat16(acc);
    zin[row * D + lane] = (1.f + eps[0]) * acc;
}

// ---------------- CSR build ----------------
__global__ __launch_bounds__(256) void k_hist(const int* __restrict__ ei,
                                              int* __restrict__ deg) {
    int e = blockIdx.x * 256 + threadIdx.x;
    if (e < NEDGES) atomicAdd(&deg[ei[NEDGES + e]], 1);
}

__global__ __launch_bounds__(256) void k_scansum(const int* __restrict__ deg,
                                                 int* __restrict__ bsum) {
    int i = blockIdx.x * 256 + threadIdx.x;
    int v = (i < NNODES) ? deg[i] : 0;
#pragma unroll
    for (int o = 32; o; o >>= 1) v += __shfl_xor(v, o);
    __shared__ int ws[4];
    if ((threadIdx.x & 63) == 0) ws[threadIdx.x >> 6] = v;
    __syncthreads();
    if (threadIdx.x == 0) bsum[blockIdx.x] = ws[0] + ws[1] + ws[2] + ws[3];
}

__global__ __launch_bounds__(256) void k_scanbase(const int* __restrict__ bsum,
                                                  int* __restrict__ bbase) {
    __shared__ int s[256];
    int t = threadIdx.x;
    int v = (t < NSB) ? bsum[t] : 0;
    s[t] = v;
    __syncthreads();
    for (int o = 1; o < 256; o <<= 1) {
        int u = (t >= o) ? s[t - o] : 0;
        __syncthreads();
        s[t] += u;
        __syncthreads();
    }
    if (t < NSB) bbase[t] = s[t] - v;
}

__global__ __launch_bounds__(256) void k_scanwrite(const int* __restrict__ deg,
                                                   const int* __restrict__ bbase,
                                                   int* __restrict__ cursor) {
    __shared__ int s[256];
    int t = threadIdx.x;
    int i = blockIdx.x * 256 + t;
    int v = (i < NNODES) ? deg[i] : 0;
    s[t] = v;
    __syncthreads();
    for (int o = 1; o < 256; o <<= 1) {
        int u = (t >= o) ? s[t - o] : 0;
        __syncthreads();
        s[t] += u;
        __syncthreads();
    }
    int excl = bbase[blockIdx.x] + s[t] - v;
    if (i < NNODES) cursor[i] = excl;
}

// scatter fused 32B edge record {src, dst, 5 x bf16-pair} into CSR (dst-sorted) order
__global__ __launch_bounds__(256) void k_scatter(const int* __restrict__ ei,
                                                 const float* __restrict__ ea,
                                                 int* __restrict__ cursor,
                                                 uint4* __restrict__ e32) {
    int e = blockIdx.x * 256 + threadIdx.x;
    if (e >= NEDGES) return;
    int s = ei[e], d = ei[NEDGES + e];
    int p = atomicAdd(&cursor[d], 1);
    unsigned u[5];
#pragma unroll
    for (int i = 0; i < 5; ++i) {
        __hip_bfloat16 b0 = __float2bfloat16(ea[e * EDIM + 2 * i]);
        __hip_bfloat16 b1 = __float2bfloat16(ea[e * EDIM + 2 * i + 1]);
        u[i] = ((unsigned)*(unsigned short*)&b1 << 16) | (unsigned)*(unsigned short*)&b0;
    }
    uint4 lo, hi;
    lo.x = (unsigned)s; lo.y = (unsigned)d; lo.z = u[0]; lo.w = u[1];
    hi.x = u[2]; hi.y = u[3]; hi.z = u[4]; hi.w = 0;
    e32[(size_t)p * 2] = lo;
    e32[(size_t)p * 2 + 1] = hi;
}

// ---------------- aggregate, edge-balanced: zin[dst] += relu(hbf[src] + eemb) ----------------
// zin pre-initialized to (1+eps)*hin by producer kernels. 32 edges/wave, CSR order,
// register-accumulate, wave-uniform boundary flush via atomicAdd.
__global__ __launch_bounds__(256) void k_agg(const uint4* __restrict__ e32,
                                             const float* __restrict__ We,
                                             const float* __restrict__ be, int l,
                                             const __hip_bfloat16* __restrict__ hbf,
                                             float* __restrict__ zin) {
    int wave = threadIdx.x >> 6, lane = threadIdx.x & 63;
    int j0 = (blockIdx.x * 4 + wave) * EPW;
    if (j0 >= NEDGES) return;
    int j1 = min(j0 + EPW, NEDGES);
    const float* Wl = We + l * EDIM * D;
    float w[EDIM];
#pragma unroll
    for (int k = 0; k < EDIM; ++k) w[k] = Wl[k * D + lane];
    float bias = be[l * D + lane];
    float acc = 0.f;
    int cur = (int)((const unsigned*)e32)[(size_t)j0 * 8 + 1];
#define EMB(lo, hi, m)                                                                   \
    {                                                                                    \
        m = bias;                                                                        \
        m += blo(lo.z) * w[0] + bhi(lo.z) * w[1] + blo(lo.w) * w[2] + bhi(lo.w) * w[3];  \
        m += blo(hi.x) * w[4] + bhi(hi.x) * w[5] + blo(hi.y) * w[6] + bhi(hi.y) * w[7];  \
        m += blo(hi.z) * w[8] + bhi(hi.z) * w[9];                                        \
    }
#define STEP(dd, mm, hh)                                                                 \
    {                                                                                    \
        if (dd != cur) {                                                                 \
            atomicAdd(&zin[(size_t)cur * D + lane], acc);                                \
            acc = 0.f; cur = dd;                                                         \
        }                                                                                \
        acc += fmaxf(mm + hh, 0.f);                                                      \
    }
    int j = j0;
    for (; j + 3 < j1; j += 4) {
        const uint4* r = e32 + (size_t)j * 2;
        uint4 lo0 = r[0], hi0 = r[1];
        uint4 lo1 = r[2], hi1 = r[3];
        uint4 lo2 = r[4], hi2 = r[5];
        uint4 lo3 = r[6], hi3 = r[7];
        float hv0 = __bfloat162float(hbf[(size_t)lo0.x * D + lane]);
        float hv1 = __bfloat162float(hbf[(size_t)lo1.x * D + lane]);
        float hv2 = __bfloat162float(hbf[(size_t)lo2.x * D + lane]);
        float hv3 = __bfloat162float(hbf[(size_t)lo3.x * D + lane]);
        float m0, m1, m2, m3;
        EMB(lo0, hi0, m0) EMB(lo1, hi1, m1) EMB(lo2, hi2, m2) EMB(lo3, hi3, m3)
        STEP((int)lo0.y, m0, hv0)
        STEP((int)lo1.y, m1, hv1)
        STEP((int)lo2.y, m2, hv2)
        STEP((int)lo3.y, m3, hv3)
    }
    for (; j < j1; ++j) {
        const uint4* r = e32 + (size_t)j * 2;
        uint4 lo = r[0], hi = r[1];
        float hv = __bfloat162float(hbf[(size_t)lo.x * D + lane]);
        float m;
        EMB(lo, hi, m)
        STEP((int)lo.y, m, hv)
    }
#undef EMB
#undef STEP
    atomicAdd(&zin[(size_t)cur * D + lane], acc);
}

// ---------------- GEMM1: t = zin @ W1 + b1 (+ BN stats of t) ----------------
__global__ __launch_bounds__(256) void k_gemm1(const float* __restrict__ zin,
                                               const float* __restrict__ W1,
                                               const float* __restrict__ b1, int l,
                                               float* __restrict__ t,
                                               float* __restrict__ stats1) {
    __shared__ float sZ[64 * D];
    __shared__ float sW[D * D2];
    __shared__ float sSum[D2], sSq[D2];
    const float* Wp = W1 + l * D * D2;
    int row0 = blockIdx.x * 64;
    int nvalid = min(64, NNODES - row0);
    for (int i = threadIdx.x; i < D * D2; i += 256) sW[i] = Wp[i];
    for (int i = threadIdx.x; i < 64 * D; i += 256) {
        int r = i >> 6;
        sZ[i] = (r < nvalid) ? zin[(row0 + r) * D + (i & 63)] : 0.f;
    }
    if (threadIdx.x < D2) { sSum[threadIdx.x] = 0.f; sSq[threadIdx.x] = 0.f; }
    __syncthreads();
    int cg = threadIdx.x & 31;
    int rg = threadIdx.x >> 5;
    float4 binit = *(const float4*)&b1[l * D2 + cg * 4];
    float4 acc[8];
#pragma unroll
    for (int r = 0; r < 8; ++r) acc[r] = binit;
    for (int k = 0; k < D; ++k) {
        float4 w = *(const float4*)&sW[k * D2 + cg * 4];
#pragma unroll
        for (int r = 0; r < 8; ++r) {
            float a = sZ[(rg * 8 + r) * D + k];
            acc[r].x += a * w.x; acc[r].y += a * w.y;
            acc[r].z += a * w.z; acc[r].w += a * w.w;
        }
    }
    float4 s = {0, 0, 0, 0}, sq = {0, 0, 0, 0};
#pragma unroll
    for (int r = 0; r < 8; ++r) {
        int row = rg * 8 + r;
        if (row < nvalid) {
            *(float4*)&t[(row0 + row) * D2 + cg * 4] = acc[r];
            s.x += acc[r].x; s.y += acc[r].y; s.z += acc[r].z; s.w += acc[r].w;
            sq.x += acc[r].x * acc[r].x; sq.y += acc[r].y * acc[r].y;
            sq.z += acc[r].z * acc[r].z; sq.w += acc[r].w * acc[r].w;
        }
    }
    atomicAdd(&sSum[cg * 4 + 0], s.x); atomicAdd(&sSq[cg * 4 + 0], sq.x);
    atomicAdd(&sSum[cg * 4 + 1], s.y); atomicAdd(&sSq[cg * 4 + 1], sq.y);
    atomicAdd(&sSum[cg * 4 + 2], s.z); atomicAdd(&sSq[cg * 4 + 2], sq.z);
    atomicAdd(&sSum[cg * 4 + 3], s.w); atomicAdd(&sSq[cg * 4 + 3], sq.w);
    __syncthreads();
    if (threadIdx.x < D2) {
        atomicAdd(&stats1[threadIdx.x], sSum[threadIdx.x]);
        atomicAdd(&stats1[D2 + threadIdx.x], sSq[threadIdx.x]);
    }
}

// ---------------- GEMM2: z2 = relu(bn(t)) @ W2 + b2 (+ BN stats of z2) ----------------
__global__ __launch_bounds__(256) void k_gemm2(const float* __restrict__ t,
                                               const float* __restrict__ stats1,
                                               const float* __restrict__ W2,
                                               const float* __restrict__ b2, int l,
                                               float* __restrict__ z2,
                                               float* __restrict__ stats2) {
    __shared__ float sT[32 * D2];
    __shared__ float sW[D2 * D];
    __shared__ float sSum[D], sSq[D];
    const float* Wp = W2 + l * D2 * D;
    int row0 = blockIdx.x * 32;
    int nvalid = min(32, NNODES - row0);
    for (int i = threadIdx.x; i < D2 * D; i += 256) sW[i] = Wp[i];
    const float invN = 1.f / NNODES;
    for (int i = threadIdx.x; i < 32 * D2; i += 256) {
        int r = i >> 7, c = i & 127;
        float v = 0.f;
        if (r < nvalid) {
            float mu = stats1[c] * invN;
            float var = stats1[D2 + c] * invN - mu * mu;
            float rstd = rsqrtf(var + BN_EPS);
            v = (t[(row0 + r) * D2 + c] - mu) * rstd + BN_BIAS;
            v = fmaxf(v, 0.f);
        }
        sT[i] = v;
    }
    if (threadIdx.x < D) { sSum[threadIdx.x] = 0.f; sSq[threadIdx.x] = 0.f; }
    __syncthreads();
    int cg = threadIdx.x & 31;
    int rg = threadIdx.x >> 5;
    float2 binit = *(const float2*)&b2[l * D + cg * 2];
    float2 acc[4];
#pragma unroll
    for (int r = 0; r < 4; ++r) acc[r] = binit;
    for (int k = 0; k < D2; ++k) {
        float2 w = *(const float2*)&sW[k * D + cg * 2];
#pragma unroll
        for (int r = 0; r < 4; ++r) {
            float a = sT[(rg * 4 + r) * D2 + k];
            acc[r].x += a * w.x; acc[r].y += a * w.y;
        }
    }
    float2 s = {0, 0}, sq = {0, 0};
#pragma unroll
    for (int r = 0; r < 4; ++r) {
        int row = rg * 4 + r;
        if (row < nvalid) {
            *(float2*)&z2[(row0 + row) * D + cg * 2] = acc[r];
            s.x += acc[r].x; s.y += acc[r].y;
            sq.x += acc[r].x * acc[r].x; sq.y += acc[r].y * acc[r].y;
        }
    }
    atomicAdd(&sSum[cg * 2 + 0], s.x); atomicAdd(&sSq[cg * 2 + 0], sq.x);
    atomicAdd(&sSum[cg * 2 + 1], s.y); atomicAdd(&sSq[cg * 2 + 1], sq.y);
    __syncthreads();
    if (threadIdx.x < D) {
        atomicAdd(&stats2[threadIdx.x], sSum[threadIdx.x]);
        atomicAdd(&stats2[D + threadIdx.x], sSq[threadIdx.x]);
    }
}

// ------- fused: hin = relu(bn(z2)) + vn[batch]; hbf shadow; zin init for NEXT layer -------
// in-place safe: zin aliases z2; each thread reads z2[idx] before writing zin[idx].
__global__ __launch_bounds__(256) void k_bnprep(const float* __restrict__ z2,
                                                const float* __restrict__ stats2,
                                                const float* __restrict__ vn,
                                                const int* __restrict__ batch,
                                                const float* __restrict__ eps, int lnext,
                                                float* __restrict__ hin,
                                                __hip_bfloat16* __restrict__ hbf,
                                                float* __restrict__ zin) {
    int idx = blockIdx.x * 256 + threadIdx.x;
    if (idx >= NNODES * D) return;
    int c = idx & 63, row = idx >> 6;
    const float invN = 1.f / NNODES;
    float mu = stats2[c] * invN;
    float var = stats2[D + c] * invN - mu * mu;
    float rstd = rsqrtf(var + BN_EPS);
    float v = (z2[idx] - mu) * rstd + BN_BIAS;
    v = fmaxf(v, 0.f);
    v += vn[batch[row] * D + c];
    hin[idx] = v;
    hbf[idx] = __float2bfloat16(v);
    zin[idx] = (1.f + eps[lnext]) * v;
}

// ---------------- fused final: bn(z2) -> node att + per-node edge projections ----------------
__global__ __launch_bounds__(256) void k_finish_att_proj(const float* __restrict__ z2,
                                                         const float* __restrict__ stats2,
                                                         const float* __restrict__ Wna,
                                                         const float* __restrict__ bna,
                                                         const float* __restrict__ Wea,
                                                         float* __restrict__ proj,
                                                         float* __restrict__ out) {
    int wave = threadIdx.x >> 6, lane = threadIdx.x & 63;
    int row = blockIdx.x * 4 + wave;
    if (row >= NNODES) return;
    const float invN = 1.f / NNODES;
    float mu = stats2[lane] * invN;
    float var = stats2[D + lane] * invN - mu * mu;
    float rstd = rsqrtf(var + BN_EPS);
    float v = (z2[row * D + lane] - mu) * rstd + BN_BIAS;
    float n0 = v * Wna[lane * 2 + 0];
    float n1 = v * Wna[lane * 2 + 1];
    float pa0 = v * Wea[lane * 2 + 0];
    float pa1 = v * Wea[lane * 2 + 1];
    float pb0 = v * Wea[(D + lane) * 2 + 0];
    float pb1 = v * Wea[(D + lane) * 2 + 1];
#pragma unroll
    for (int o = 32; o; o >>= 1) {
        n0 += __shfl_xor(n0, o); n1 += __shfl_xor(n1, o);
        pa0 += __shfl_xor(pa0, o); pa1 += __shfl_xor(pa1, o);
        pb0 += __shfl_xor(pb0, o); pb1 += __shfl_xor(pb1, o);
    }
    if (lane == 0) {
        out[row] = 1.f / (1.f + expf((n0 + bna[0]) - (n1 + bna[1])));
        proj[row * 4 + 0] = pa0;
        proj[row * 4 + 1] = pa1;
        proj[row * 4 + 2] = pb0;
        proj[row * 4 + 3] = pb1;
    }
}

// ---------------- edge attention from projection tables ----------------
__global__ __launch_bounds__(256) void k_edge_final(const int* __restrict__ ei,
                                                    const float* __restrict__ proj,
                                                    const float* __restrict__ bea,
                                                    float* __restrict__ out) {
    int e = blockIdx.x * 256 + threadIdx.x;
    if (e >= NEDGES) return;
    int src = ei[e], dst = ei[NEDGES + e];
    float4 ps = *(const float4*)&proj[src * 4];
    float4 pd = *(const float4*)&proj[dst * 4];
    float s0 = ps.x + pd.z + bea[0];
    float s1 = ps.y + pd.w + bea[1];
    out[NNODES + e] = 1.f / (1.f + expf(s0 - s1));
}

// ---------------- vt += segment_sum(hin) over contiguous row chunks ----------------
__global__ __launch_bounds__(256) void k_vt(const float* __restrict__ hin,
                                            const int* __restrict__ batch,
                                            float* __restrict__ vt) {
    int wave = threadIdx.x >> 6, lane = threadIdx.x & 63;
    int wid = blockIdx.x * 4 + wave;
    int r0 = wid * 64;
    if (r0 >= NNODES) return;
    int r1 = min(r0 + 64, NNODES);
    int g = batch[r0];
    float acc = 0.f;
    for (int r = r0; r < r1; ++r) {
        int gb = batch[r];
        if (gb != g) {
            atomicAdd(&vt[g * D + lane], acc);
            acc = 0.f; g = gb;
        }
        acc += hin[r * D + lane];
    }
    atomicAdd(&vt[g * D + lane], acc);
}

// ---------------- vn-MLP stage 1: ucm[col][row] = relu(bn((vt+vn) @ Wv1 + bv1)) ----------------
__global__ __launch_bounds__(256) void k_vn1(const float* __restrict__ vt,
                                             const float* __restrict__ vn,
                                             const float* __restrict__ Wv1,
                                             const float* __restrict__ bv1, int l,
                                             float* __restrict__ ucm) {
    __shared__ float sV[NG * 65];
    __shared__ float sW[NG * 4];
    int c0 = blockIdx.x * 4;
    for (int i = threadIdx.x; i < NG * D; i += 256) {
        int r = i >> 6, c = i & 63;
        sV[r * 65 + c] = vt[i] + vn[i];
    }
    {
        int k = threadIdx.x >> 2, c = threadIdx.x & 3;
        sW[threadIdx.x] = Wv1[l * D * D2 + k * D2 + c0 + c];
    }
    __syncthreads();
    int lane = threadIdx.x & 63, w = threadIdx.x >> 6;
    float acc = bv1[l * D2 + c0 + w];
#pragma unroll
    for (int k = 0; k < D; ++k) acc += sV[lane * 65 + k] * sW[k * 4 + w];
    float s = acc, sq = acc * acc;
#pragma unroll
    for (int o = 32; o; o >>= 1) { s += __shfl_xor(s, o); sq += __shfl_xor(sq, o); }
    float mu = s * (1.f / NG);
    float rstd = rsqrtf(sq * (1.f / NG) - mu * mu + BN_EPS);
    ucm[(c0 + w) * NG + lane] = fmaxf((acc - mu) * rstd + BN_BIAS, 0.f);
}

// ---------------- vn-MLP stage 2: vn = relu(bn(ucm^T @ Wv2 + bv2)) ----------------
__global__ __launch_bounds__(256) void k_vn2(const float* __restrict__ ucm,
                                             const float* __restrict__ Wv2,
                                             const float* __restrict__ bv2, int l,
                                             float* __restrict__ vn) {
    __shared__ float sU[D2 * NG];
    __shared__ float sW[D2 * 4];
    int c0 = blockIdx.x * 4;
    for (int i = threadIdx.x; i < D2 * NG; i += 256) sU[i] = ucm[i];
    for (int i = threadIdx.x; i < D2 * 4; i += 256) {
        int k = i >> 2, c = i & 3;
        sW[i] = Wv2[l * D2 * D + k * D + c0 + c];
    }
    __syncthreads();
    int lane = threadIdx.x & 63, w = threadIdx.x >> 6;
    float acc = bv2[l * D + c0 + w];
#pragma unroll
    for (int k = 0; k < D2; ++k) acc += sU[k * NG + lane] * sW[k * 4 + w];
    float s = acc, sq = acc * acc;
#pragma unroll
    for (int o = 32; o; o >>= 1) { s += __shfl_xor(s, o); sq += __shfl_xor(sq, o); }
    float mu = s * (1.f / NG);
    float rstd = rsqrtf(sq * (1.f / NG) - mu * mu + BN_EPS);
    vn[lane * D + c0 + w] = fmaxf((acc - mu) * rstd + BN_BIAS, 0.f);
}

extern "C" void kernel_launch(void* const* d_in, const int* in_sizes, int n_in,
                              void* d_out, int out_size, void* d_ws, size_t ws_size,
                              hipStream_t stream) {
    const float* x    = (const float*)d_in[0];
    const float* ea   = (const float*)d_in[1];
    const int*   ei   = (const int*)d_in[2];
    const int*   batch= (const int*)d_in[3];
    const float* Wenc = (const float*)d_in[4];
    const float* benc = (const float*)d_in[5];
    const float* We   = (const float*)d_in[6];
    const float* be   = (const float*)d_in[7];
    const float* eps  = (const float*)d_in[8];
    const float* W1   = (const float*)d_in[9];
    const float* b1   = (const float*)d_in[10];
    const float* W2   = (const float*)d_in[11];
    const float* b2   = (const float*)d_in[12];
    const float* Wv1  = (const float*)d_in[13];
    const float* bv1  = (const float*)d_in[14];
    const float* Wv2  = (const float*)d_in[15];
    const float* bv2  = (const float*)d_in[16];
    const float* Wea  = (const float*)d_in[17];
    const float* bea  = (const float*)d_in[18];
    const float* Wna  = (const float*)d_in[19];
    const float* bna  = (const float*)d_in[20];
    float* out = (float*)d_out;

    float* ws   = (float*)d_ws;
    float* hin  = ws;                              // [N*D]
    float* zin  = hin + (size_t)NNODES * D;        // [N*D]  (z2 overlays zin)
    float* t    = zin + (size_t)NNODES * D;        // [N*D2]
    float* proj = t   + (size_t)NNODES * D2;       // [N*4]
    uint4* e32  = (uint4*)(proj + (size_t)NNODES * 4);      // [E * 32B], 16B-aligned
    __hip_bfloat16* hbf = (__hip_bfloat16*)(e32 + (size_t)NEDGES * 2);   // [N*D]
    // ---- contiguous zero-region: vn | vt0 | vt1 | stats(1536) | deg ----
    float* vn    = (float*)(hbf + (size_t)NNODES * D);
    float* vt0   = vn  + NG * D;
    float* vt1   = vt0 + NG * D;
    float* stats = vt1 + NG * D;                   // statsA: l*256 (0..767); statsB: 768+l*128
    int*   deg   = (int*)(stats + 1536);
    // ---- end zero-region ----
    int*   cursor = deg + NNODES;
    int*   bsum   = cursor + NNODES;
    int*   bbase  = bsum + NSB;
    float* ucm    = (float*)(bbase + NSB);         // [D2*NG]

    float* z2 = zin;   // overlay: zin dead after gemm1

    size_t zero_bytes = (size_t)(3 * NG * D + 1536) * 4 + (size_t)NNODES * 4;
    hipMemsetAsync(vn, 0, zero_bytes, stream);
    k_enc<<<NNODES / 4, 256, 0, stream>>>(x, Wenc, benc, eps, hin, hbf, zin);
    k_hist<<<(NEDGES + 255) / 256, 256, 0, stream>>>(ei, deg);
    k_scansum<<<NSB, 256, 0, stream>>>(deg, bsum);
    k_scanbase<<<1, 256, 0, stream>>>(bsum, bbase);
    k_scanwrite<<<NSB, 256, 0, stream>>>(deg, bbase, cursor);
    k_scatter<<<(NEDGES + 255) / 256, 256, 0, stream>>>(ei, ea, cursor, e32);

    for (int l = 0; l < 3; ++l) {
        float* statsA = stats + l * 256;
        float* statsB = stats + 768 + l * 128;
        if (l < 2) {
            float* vtb = (l == 0) ? vt0 : vt1;
            k_vt<<<(NNODES / 64 + 4) / 4, 256, 0, stream>>>(hin, batch, vtb);
            k_agg<<<(NEDGES + EPW * 4 - 1) / (EPW * 4), 256, 0, stream>>>(e32, We, be, l,
                                                                          hbf, zin);
            k_vn1<<<32, 256, 0, stream>>>(vtb, vn, Wv1, bv1, l, ucm);
            k_vn2<<<16, 256, 0, stream>>>(ucm, Wv2, bv2, l, vn);
        } else {
            k_agg<<<(NEDGES + EPW * 4 - 1) / (EPW * 4), 256, 0, stream>>>(e32, We, be, l,
                                                                          hbf, zin);
        }
        k_gemm1<<<(NNODES + 63) / 64, 256, 0, stream>>>(zin, W1, b1, l, t, statsA);
        k_gemm2<<<(NNODES + 31) / 32, 256, 0, stream>>>(t, statsA, W2, b2, l, z2, statsB);
        if (l < 2) {
            k_bnprep<<<NNODES * D / 256, 256, 0, stream>>>(z2, statsB, vn, batch, eps,
                                                           l + 1, hin, hbf, zin);
        } else {
            k_finish_att_proj<<<NNODES / 4, 256, 0, stream>>>(z2, statsB, Wna, bna, Wea,
                                                              proj, out);
        }
    }
    k_edge_final<<<(NEDGES + 255) / 256, 256, 0, stream>>>(ei, proj, bea, out);
}

// Round 9
// 729.158 us; speedup vs baseline: 1.9564x; 1.0244x over previous
//
#include <hip/hip_runtime.h>
#include <hip/hip_bf16.h>

#define NNODES 50000
#define NEDGES 800000
#define NG 64
#define D 64
#define D2 128
#define INDIM 39
#define EDIM 10
#define EPW 32             // edges per wave in k_agg
#define BN_EPS 1e-5f
#define BN_BIAS 1e-4f
#define NSB ((NNODES + 255) / 256)   // 196 scan blocks

__device__ __forceinline__ float blo(unsigned u) {
    union { unsigned i; float f; } c; c.i = u << 16; return c.f;
}
__device__ __forceinline__ float bhi(unsigned u) {
    union { unsigned i; float f; } c; c.i = u & 0xffff0000u; return c.f;
}

// ---------------- encoder: hin = x @ Wenc + benc (+ bf16 shadow, + zin init) ----------------
__global__ __launch_bounds__(256) void k_enc(const float* __restrict__ x,
                                             const float* __restrict__ Wenc,
                                             const float* __restrict__ benc,
                                             const float* __restrict__ eps,
                                             float* __restrict__ hin,
                                             __hip_bfloat16* __restrict__ hbf,
                                             float* __restrict__ zin) {
    __shared__ float sW[INDIM * D];
    for (int i = threadIdx.x; i < INDIM * D; i += 256) sW[i] = Wenc[i];
    __syncthreads();
    int wave = threadIdx.x >> 6, lane = threadIdx.x & 63;
    int row = blockIdx.x * 4 + wave;
    if (row >= NNODES) return;
    float xv = (lane < INDIM) ? x[row * INDIM + lane] : 0.f;
    float acc = benc[lane];
#pragma unroll
    for (int k = 0; k < INDIM; ++k) acc += __shfl(xv, k) * sW[k * D + lane];
    hin[row * D + lane] = acc;
    hbf[row * D + lane] = __float2bfloat16(acc);
    zin[row * D + lane] = (1.f + eps[0]) * acc;
}

// ---------------- CSR build ----------------
__global__ __launch_bounds__(256) void k_hist(const int* __restrict__ ei,
                                              int* __restrict__ deg) {
    int e = blockIdx.x * 256 + threadIdx.x;
    if (e < NEDGES) atomicAdd(&deg[ei[NEDGES + e]], 1);
}

__global__ __launch_bounds__(256) void k_scansum(const int* __restrict__ deg,
                                                 int* __restrict__ bsum) {
    int i = blockIdx.x * 256 + threadIdx.x;
    int v = (i < NNODES) ? deg[i] : 0;
#pragma unroll
    for (int o = 32; o; o >>= 1) v += __shfl_xor(v, o);
    __shared__ int ws[4];
    if ((threadIdx.x & 63) == 0) ws[threadIdx.x >> 6] = v;
    __syncthreads();
    if (threadIdx.x == 0) bsum[blockIdx.x] = ws[0] + ws[1] + ws[2] + ws[3];
}

__global__ __launch_bounds__(256) void k_scanbase(const int* __restrict__ bsum,
                                                  int* __restrict__ bbase) {
    __shared__ int s[256];
    int t = threadIdx.x;
    int v = (t < NSB) ? bsum[t] : 0;
    s[t] = v;
    __syncthreads();
    for (int o = 1; o < 256; o <<= 1) {
        int u = (t >= o) ? s[t - o] : 0;
        __syncthreads();
        s[t] += u;
        __syncthreads();
    }
    if (t < NSB) bbase[t] = s[t] - v;
}

__global__ __launch_bounds__(256) void k_scanwrite(const int* __restrict__ deg,
                                                   const int* __restrict__ bbase,
                                                   int* __restrict__ cursor) {
    __shared__ int s[256];
    int t = threadIdx.x;
    int i = blockIdx.x * 256 + t;
    int v = (i < NNODES) ? deg[i] : 0;
    s[t] = v;
    __syncthreads();
    for (int o = 1; o < 256; o <<= 1) {
        int u = (t >= o) ? s[t - o] : 0;
        __syncthreads();
        s[t] += u;
        __syncthreads();
    }
    int excl = bbase[blockIdx.x] + s[t] - v;
    if (i < NNODES) cursor[i] = excl;
}

// scatter fused 32B edge record {src, dst, 5 x bf16-pair} into CSR (dst-sorted) order
__global__ __launch_bounds__(256) void k_scatter(const int* __restrict__ ei,
                                                 const float* __restrict__ ea,
                                                 int* __restrict__ cursor,
                                                 uint4* __restrict__ e32) {
    int e = blockIdx.x * 256 + threadIdx.x;
    if (e >= NEDGES) return;
    int s = ei[e], d = ei[NEDGES + e];
    int p = atomicAdd(&cursor[d], 1);
    unsigned u[5];
#pragma unroll
    for (int i = 0; i < 5; ++i) {
        __hip_bfloat16 b0 = __float2bfloat16(ea[e * EDIM + 2 * i]);
        __hip_bfloat16 b1 = __float2bfloat16(ea[e * EDIM + 2 * i + 1]);
        u[i] = ((unsigned)*(unsigned short*)&b1 << 16) | (unsigned)*(unsigned short*)&b0;
    }
    uint4 lo, hi;
    lo.x = (unsigned)s; lo.y = (unsigned)d; lo.z = u[0]; lo.w = u[1];
    hi.x = u[2]; hi.y = u[3]; hi.z = u[4]; hi.w = 0;
    e32[(size_t)p * 2] = lo;
    e32[(size_t)p * 2 + 1] = hi;
}

// ---------------- aggregate, edge-balanced: zin[dst] += relu(hbf[src] + eemb) ----------------
__global__ __launch_bounds__(256) void k_agg(const uint4* __restrict__ e32,
                                             const float* __restrict__ We,
                                             const float* __restrict__ be, int l,
                                             const __hip_bfloat16* __restrict__ hbf,
                                             float* __restrict__ zin) {
    int wave = threadIdx.x >> 6, lane = threadIdx.x & 63;
    int j0 = (blockIdx.x * 4 + wave) * EPW;
    if (j0 >= NEDGES) return;
    int j1 = min(j0 + EPW, NEDGES);
    const float* Wl = We + l * EDIM * D;
    float w[EDIM];
#pragma unroll
    for (int k = 0; k < EDIM; ++k) w[k] = Wl[k * D + lane];
    float bias = be[l * D + lane];
    float acc = 0.f;
    int cur = (int)((const unsigned*)e32)[(size_t)j0 * 8 + 1];
#define EMB(lo, hi, m)                                                                   \
    {                                                                                    \
        m = bias;                                                                        \
        m += blo(lo.z) * w[0] + bhi(lo.z) * w[1] + blo(lo.w) * w[2] + bhi(lo.w) * w[3];  \
        m += blo(hi.x) * w[4] + bhi(hi.x) * w[5] + blo(hi.y) * w[6] + bhi(hi.y) * w[7];  \
        m += blo(hi.z) * w[8] + bhi(hi.z) * w[9];                                        \
    }
#define STEP(dd, mm, hh)                                                                 \
    {                                                                                    \
        if (dd != cur) {                                                                 \
            atomicAdd(&zin[(size_t)cur * D + lane], acc);                                \
            acc = 0.f; cur = dd;                                                         \
        }                                                                                \
        acc += fmaxf(mm + hh, 0.f);                                                      \
    }
    int j = j0;
    for (; j + 3 < j1; j += 4) {
        const uint4* r = e32 + (size_t)j * 2;
        uint4 lo0 = r[0], hi0 = r[1];
        uint4 lo1 = r[2], hi1 = r[3];
        uint4 lo2 = r[4], hi2 = r[5];
        uint4 lo3 = r[6], hi3 = r[7];
        float hv0 = __bfloat162float(hbf[(size_t)lo0.x * D + lane]);
        float hv1 = __bfloat162float(hbf[(size_t)lo1.x * D + lane]);
        float hv2 = __bfloat162float(hbf[(size_t)lo2.x * D + lane]);
        float hv3 = __bfloat162float(hbf[(size_t)lo3.x * D + lane]);
        float m0, m1, m2, m3;
        EMB(lo0, hi0, m0) EMB(lo1, hi1, m1) EMB(lo2, hi2, m2) EMB(lo3, hi3, m3)
        STEP((int)lo0.y, m0, hv0)
        STEP((int)lo1.y, m1, hv1)
        STEP((int)lo2.y, m2, hv2)
        STEP((int)lo3.y, m3, hv3)
    }
    for (; j < j1; ++j) {
        const uint4* r = e32 + (size_t)j * 2;
        uint4 lo = r[0], hi = r[1];
        float hv = __bfloat162float(hbf[(size_t)lo.x * D + lane]);
        float m;
        EMB(lo, hi, m)
        STEP((int)lo.y, m, hv)
    }
#undef EMB
#undef STEP
    atomicAdd(&zin[(size_t)cur * D + lane], acc);
}

// ---------------- GEMM1: t = zin @ W1 + b1 (+ BN stats of t) ----------------
// 64 rows/block; thread tile 4 rows x (4 + 4) cols; float4 LDS reads, conflict-free pads.
__global__ __launch_bounds__(256) void k_gemm1(const float* __restrict__ zin,
                                               const float* __restrict__ W1,
                                               const float* __restrict__ b1, int l,
                                               float* __restrict__ t,
                                               float* __restrict__ stats1) {
    __shared__ float sZ[64 * 68];    // 17.4 KB, row stride 68 (16B-aligned, bank-shifted)
    __shared__ float sW[D * D2];     // 32 KB
    __shared__ float sSum[D2], sSq[D2];
    const float* Wp = W1 + l * D * D2;
    int row0 = blockIdx.x * 64;
    int nvalid = min(64, NNODES - row0);
    for (int i = threadIdx.x; i < D * D2 / 4; i += 256)
        *(float4*)&sW[i * 4] = *(const float4*)&Wp[i * 4];
    for (int i = threadIdx.x; i < 64 * 16; i += 256) {
        int r = i >> 4, c4 = (i & 15) * 4;
        float4 v = (r < nvalid) ? *(const float4*)&zin[(size_t)(row0 + r) * D + c4]
                                : make_float4(0.f, 0.f, 0.f, 0.f);
        *(float4*)&sZ[r * 68 + c4] = v;
    }
    if (threadIdx.x < D2) { sSum[threadIdx.x] = 0.f; sSq[threadIdx.x] = 0.f; }
    __syncthreads();
    int rg = threadIdx.x >> 4;       // 16 row-groups x 4 rows
    int cg = threadIdx.x & 15;       // cols c0..c0+3 and 64+c0..64+c0+3
    int r0 = rg * 4, c0 = cg * 4;
    float4 bA = *(const float4*)&b1[l * D2 + c0];
    float4 bB = *(const float4*)&b1[l * D2 + 64 + c0];
    float accA[4][4], accB[4][4];
#pragma unroll
    for (int r = 0; r < 4; ++r) {
        accA[r][0] = bA.x; accA[r][1] = bA.y; accA[r][2] = bA.z; accA[r][3] = bA.w;
        accB[r][0] = bB.x; accB[r][1] = bB.y; accB[r][2] = bB.z; accB[r][3] = bB.w;
    }
    for (int kk = 0; kk < D; kk += 4) {
        float4 a[4];
#pragma unroll
        for (int r = 0; r < 4; ++r) a[r] = *(const float4*)&sZ[(r0 + r) * 68 + kk];
#pragma unroll
        for (int dk = 0; dk < 4; ++dk) {
            float4 wA = *(const float4*)&sW[(kk + dk) * D2 + c0];
            float4 wB = *(const float4*)&sW[(kk + dk) * D2 + 64 + c0];
#pragma unroll
            for (int r = 0; r < 4; ++r) {
                float av = (&a[r].x)[dk];
                accA[r][0] += av * wA.x; accA[r][1] += av * wA.y;
                accA[r][2] += av * wA.z; accA[r][3] += av * wA.w;
                accB[r][0] += av * wB.x; accB[r][1] += av * wB.y;
                accB[r][2] += av * wB.z; accB[r][3] += av * wB.w;
            }
        }
    }
    float sA[4] = {0, 0, 0, 0}, qA[4] = {0, 0, 0, 0};
    float sB[4] = {0, 0, 0, 0}, qB[4] = {0, 0, 0, 0};
#pragma unroll
    for (int r = 0; r < 4; ++r) {
        int row = r0 + r;
        if (row < nvalid) {
            *(float4*)&t[(size_t)(row0 + row) * D2 + c0] =
                make_float4(accA[r][0], accA[r][1], accA[r][2], accA[r][3]);
            *(float4*)&t[(size_t)(row0 + row) * D2 + 64 + c0] =
                make_float4(accB[r][0], accB[r][1], accB[r][2], accB[r][3]);
#pragma unroll
            for (int j = 0; j < 4; ++j) {
                sA[j] += accA[r][j]; qA[j] += accA[r][j] * accA[r][j];
                sB[j] += accB[r][j]; qB[j] += accB[r][j] * accB[r][j];
            }
        }
    }
#pragma unroll
    for (int j = 0; j < 4; ++j) {
        atomicAdd(&sSum[c0 + j], sA[j]);      atomicAdd(&sSq[c0 + j], qA[j]);
        atomicAdd(&sSum[64 + c0 + j], sB[j]); atomicAdd(&sSq[64 + c0 + j], qB[j]);
    }
    __syncthreads();
    if (threadIdx.x < D2) {
        atomicAdd(&stats1[threadIdx.x], sSum[threadIdx.x]);
        atomicAdd(&stats1[D2 + threadIdx.x], sSq[threadIdx.x]);
    }
}

// ---------------- GEMM2: z2 = relu(bn(t)) @ W2 + b2 (+ BN stats of z2) ----------------
// 32 rows/block; thread tile 2 rows x 4 cols; float4 LDS reads, conflict-free pads.
__global__ __launch_bounds__(256) void k_gemm2(const float* __restrict__ t,
                                               const float* __restrict__ stats1,
                                               const float* __restrict__ W2,
                                               const float* __restrict__ b2, int l,
                                               float* __restrict__ z2,
                                               float* __restrict__ stats2) {
    __shared__ float sT[32 * 132];   // 16.9 KB, row stride 132
    __shared__ float sW[D2 * D];     // 32 KB
    __shared__ float sSum[D], sSq[D];
    const float* Wp = W2 + l * D2 * D;
    int row0 = blockIdx.x * 32;
    int nvalid = min(32, NNODES - row0);
    for (int i = threadIdx.x; i < D2 * D / 4; i += 256)
        *(float4*)&sW[i * 4] = *(const float4*)&Wp[i * 4];
    const float invN = 1.f / NNODES;
    for (int i = threadIdx.x; i < 32 * 32; i += 256) {
        int r = i >> 5, c4 = (i & 31) * 4;
        float4 v = make_float4(0.f, 0.f, 0.f, 0.f);
        if (r < nvalid) {
            float4 tv = *(const float4*)&t[(size_t)(row0 + r) * D2 + c4];
            float4 su = *(const float4*)&stats1[c4];
            float4 sq = *(const float4*)&stats1[D2 + c4];
            float mu, var, rstd;
            mu = su.x * invN; var = sq.x * invN - mu * mu; rstd = rsqrtf(var + BN_EPS);
            v.x = fmaxf((tv.x - mu) * rstd + BN_BIAS, 0.f);
            mu = su.y * invN; var = sq.y * invN - mu * mu; rstd = rsqrtf(var + BN_EPS);
            v.y = fmaxf((tv.y - mu) * rstd + BN_BIAS, 0.f);
            mu = su.z * invN; var = sq.z * invN - mu * mu; rstd = rsqrtf(var + BN_EPS);
            v.z = fmaxf((tv.z - mu) * rstd + BN_BIAS, 0.f);
            mu = su.w * invN; var = sq.w * invN - mu * mu; rstd = rsqrtf(var + BN_EPS);
            v.w = fmaxf((tv.w - mu) * rstd + BN_BIAS, 0.f);
        }
        *(float4*)&sT[r * 132 + c4] = v;
    }
    if (threadIdx.x < D) { sSum[threadIdx.x] = 0.f; sSq[threadIdx.x] = 0.f; }
    __syncthreads();
    int rg = threadIdx.x >> 4;       // 16 row-groups x 2 rows
    int cg = threadIdx.x & 15;       // cols 4cg..4cg+3
    int r0 = rg * 2, c0 = cg * 4;
    float4 bv = *(const float4*)&b2[l * D + c0];
    float acc[2][4];
#pragma unroll
    for (int r = 0; r < 2; ++r) {
        acc[r][0] = bv.x; acc[r][1] = bv.y; acc[r][2] = bv.z; acc[r][3] = bv.w;
    }
    for (int kk = 0; kk < D2; kk += 4) {
        float4 a0 = *(const float4*)&sT[r0 * 132 + kk];
        float4 a1 = *(const float4*)&sT[(r0 + 1) * 132 + kk];
#pragma unroll
        for (int dk = 0; dk < 4; ++dk) {
            float4 w = *(const float4*)&sW[(kk + dk) * D + c0];
            float av0 = (&a0.x)[dk], av1 = (&a1.x)[dk];
            acc[0][0] += av0 * w.x; acc[0][1] += av0 * w.y;
            acc[0][2] += av0 * w.z; acc[0][3] += av0 * w.w;
            acc[1][0] += av1 * w.x; acc[1][1] += av1 * w.y;
            acc[1][2] += av1 * w.z; acc[1][3] += av1 * w.w;
        }
    }
    float s[4] = {0, 0, 0, 0}, q[4] = {0, 0, 0, 0};
#pragma unroll
    for (int r = 0; r < 2; ++r) {
        int row = r0 + r;
        if (row < nvalid) {
            *(float4*)&z2[(size_t)(row0 + row) * D + c0] =
                make_float4(acc[r][0], acc[r][1], acc[r][2], acc[r][3]);
#pragma unroll
            for (int j = 0; j < 4; ++j) { s[j] += acc[r][j]; q[j] += acc[r][j] * acc[r][j]; }
        }
    }
#pragma unroll
    for (int j = 0; j < 4; ++j) {
        atomicAdd(&sSum[c0 + j], s[j]); atomicAdd(&sSq[c0 + j], q[j]);
    }
    __syncthreads();
    if (threadIdx.x < D) {
        atomicAdd(&stats2[threadIdx.x], sSum[threadIdx.x]);
        atomicAdd(&stats2[D + threadIdx.x], sSq[threadIdx.x]);
    }
}

// ------- fused: hin = relu(bn(z2)) + vn[batch]; hbf shadow; zin init for NEXT layer -------
__global__ __launch_bounds__(256) void k_bnprep(const float* __restrict__ z2,
                                                const float* __restrict__ stats2,
                                                const float* __restrict__ vn,
                                                const int* __restrict__ batch,
                                                const float* __restrict__ eps, int lnext,
                                                float* __restrict__ hin,
                                                __hip_bfloat16* __restrict__ hbf,
                                                float* __restrict__ zin) {
    int idx = blockIdx.x * 256 + threadIdx.x;
    if (idx >= NNODES * D) return;
    int c = idx & 63, row = idx >> 6;
    const float invN = 1.f / NNODES;
    float mu = stats2[c] * invN;
    float var = stats2[D + c] * invN - mu * mu;
    float rstd = rsqrtf(var + BN_EPS);
    float v = (z2[idx] - mu) * rstd + BN_BIAS;
    v = fmaxf(v, 0.f);
    v += vn[batch[row] * D + c];
    hin[idx] = v;
    hbf[idx] = __float2bfloat16(v);
    zin[idx] = (1.f + eps[lnext]) * v;
}

// ---------------- fused final: bn(z2) -> node att + per-node edge projections ----------------
__global__ __launch_bounds__(256) void k_finish_att_proj(const float* __restrict__ z2,
                                                         const float* __restrict__ stats2,
                                                         const float* __restrict__ Wna,
                                                         const float* __restrict__ bna,
                                                         const float* __restrict__ Wea,
                                                         float* __restrict__ proj,
                                                         float* __restrict__ out) {
    int wave = threadIdx.x >> 6, lane = threadIdx.x & 63;
    int row = blockIdx.x * 4 + wave;
    if (row >= NNODES) return;
    const float invN = 1.f / NNODES;
    float mu = stats2[lane] * invN;
    float var = stats2[D + lane] * invN - mu * mu;
    float rstd = rsqrtf(var + BN_EPS);
    float v = (z2[row * D + lane] - mu) * rstd + BN_BIAS;
    float n0 = v * Wna[lane * 2 + 0];
    float n1 = v * Wna[lane * 2 + 1];
    float pa0 = v * Wea[lane * 2 + 0];
    float pa1 = v * Wea[lane * 2 + 1];
    float pb0 = v * Wea[(D + lane) * 2 + 0];
    float pb1 = v * Wea[(D + lane) * 2 + 1];
#pragma unroll
    for (int o = 32; o; o >>= 1) {
        n0 += __shfl_xor(n0, o); n1 += __shfl_xor(n1, o);
        pa0 += __shfl_xor(pa0, o); pa1 += __shfl_xor(pa1, o);
        pb0 += __shfl_xor(pb0, o); pb1 += __shfl_xor(pb1, o);
    }
    if (lane == 0) {
        out[row] = 1.f / (1.f + expf((n0 + bna[0]) - (n1 + bna[1])));
        proj[row * 4 + 0] = pa0;
        proj[row * 4 + 1] = pa1;
        proj[row * 4 + 2] = pb0;
        proj[row * 4 + 3] = pb1;
    }
}

// ---------------- edge attention from projection tables ----------------
__global__ __launch_bounds__(256) void k_edge_final(const int* __restrict__ ei,
                                                    const float* __restrict__ proj,
                                                    const float* __restrict__ bea,
                                                    float* __restrict__ out) {
    int e = blockIdx.x * 256 + threadIdx.x;
    if (e >= NEDGES) return;
    int src = ei[e], dst = ei[NEDGES + e];
    float4 ps = *(const float4*)&proj[src * 4];
    float4 pd = *(const float4*)&proj[dst * 4];
    float s0 = ps.x + pd.z + bea[0];
    float s1 = ps.y + pd.w + bea[1];
    out[NNODES + e] = 1.f / (1.f + expf(s0 - s1));
}

// ---------------- vt += segment_sum(hin) over contiguous row chunks ----------------
__global__ __launch_bounds__(256) void k_vt(const float* __restrict__ hin,
                                            const int* __restrict__ batch,
                                            float* __restrict__ vt) {
    int wave = threadIdx.x >> 6, lane = threadIdx.x & 63;
    int wid = blockIdx.x * 4 + wave;
    int r0 = wid * 64;
    if (r0 >= NNODES) return;
    int r1 = min(r0 + 64, NNODES);
    int g = batch[r0];
    float acc = 0.f;
    for (int r = r0; r < r1; ++r) {
        int gb = batch[r];
        if (gb != g) {
            atomicAdd(&vt[g * D + lane], acc);
            acc = 0.f; g = gb;
        }
        acc += hin[r * D + lane];
    }
    atomicAdd(&vt[g * D + lane], acc);
}

// ---------------- vn-MLP stage 1: ucm[col][row] = relu(bn((vt+vn) @ Wv1 + bv1)) ----------------
__global__ __launch_bounds__(256) void k_vn1(const float* __restrict__ vt,
                                             const float* __restrict__ vn,
                                             const float* __restrict__ Wv1,
                                             const float* __restrict__ bv1, int l,
                                             float* __restrict__ ucm) {
    __shared__ float sV[NG * 65];
    __shared__ float sW[NG * 4];
    int c0 = blockIdx.x * 4;
    for (int i = threadIdx.x; i < NG * D; i += 256) {
        int r = i >> 6, c = i & 63;
        sV[r * 65 + c] = vt[i] + vn[i];
    }
    {
        int k = threadIdx.x >> 2, c = threadIdx.x & 3;
        sW[threadIdx.x] = Wv1[l * D * D2 + k * D2 + c0 + c];
    }
    __syncthreads();
    int lane = threadIdx.x & 63, w = threadIdx.x >> 6;
    float acc = bv1[l * D2 + c0 + w];
#pragma unroll
    for (int k = 0; k < D; ++k) acc += sV[lane * 65 + k] * sW[k * 4 + w];
    float s = acc, sq = acc * acc;
#pragma unroll
    for (int o = 32; o; o >>= 1) { s += __shfl_xor(s, o); sq += __shfl_xor(sq, o); }
    float mu = s * (1.f / NG);
    float rstd = rsqrtf(sq * (1.f / NG) - mu * mu + BN_EPS);
    ucm[(c0 + w) * NG + lane] = fmaxf((acc - mu) * rstd + BN_BIAS, 0.f);
}

// ---------------- vn-MLP stage 2: vn = relu(bn(ucm^T @ Wv2 + bv2)) ----------------
__global__ __launch_bounds__(256) void k_vn2(const float* __restrict__ ucm,
                                             const float* __restrict__ Wv2,
                                             const float* __restrict__ bv2, int l,
                                             float* __restrict__ vn) {
    __shared__ float sU[D2 * NG];
    __shared__ float sW[D2 * 4];
    int c0 = blockIdx.x * 4;
    for (int i = threadIdx.x; i < D2 * NG; i += 256) sU[i] = ucm[i];
    for (int i = threadIdx.x; i < D2 * 4; i += 256) {
        int k = i >> 2, c = i & 3;
        sW[i] = Wv2[l * D2 * D + k * D + c0 + c];
    }
    __syncthreads();
    int lane = threadIdx.x & 63, w = threadIdx.x >> 6;
    float acc = bv2[l * D + c0 + w];
#pragma unroll
    for (int k = 0; k < D2; ++k) acc += sU[k * NG + lane] * sW[k * 4 + w];
    float s = acc, sq = acc * acc;
#pragma unroll
    for (int o = 32; o; o >>= 1) { s += __shfl_xor(s, o); sq += __shfl_xor(sq, o); }
    float mu = s * (1.f / NG);
    float rstd = rsqrtf(sq * (1.f / NG) - mu * mu + BN_EPS);
    vn[lane * D + c0 + w] = fmaxf((acc - mu) * rstd + BN_BIAS, 0.f);
}

extern "C" void kernel_launch(void* const* d_in, const int* in_sizes, int n_in,
                              void* d_out, int out_size, void* d_ws, size_t ws_size,
                              hipStream_t stream) {
    const float* x    = (const float*)d_in[0];
    const float* ea   = (const float*)d_in[1];
    const int*   ei   = (const int*)d_in[2];
    const int*   batch= (const int*)d_in[3];
    const float* Wenc = (const float*)d_in[4];
    const float* benc = (const float*)d_in[5];
    const float* We   = (const float*)d_in[6];
    const float* be   = (const float*)d_in[7];
    const float* eps  = (const float*)d_in[8];
    const float* W1   = (const float*)d_in[9];
    const float* b1   = (const float*)d_in[10];
    const float* W2   = (const float*)d_in[11];
    const float* b2   = (const float*)d_in[12];
    const float* Wv1  = (const float*)d_in[13];
    const float* bv1  = (const float*)d_in[14];
    const float* Wv2  = (const float*)d_in[15];
    const float* bv2  = (const float*)d_in[16];
    const float* Wea  = (const float*)d_in[17];
    const float* bea  = (const float*)d_in[18];
    const float* Wna  = (const float*)d_in[19];
    const float* bna  = (const float*)d_in[20];
    float* out = (float*)d_out;

    float* ws   = (float*)d_ws;
    float* hin  = ws;                              // [N*D]
    float* zin  = hin + (size_t)NNODES * D;        // [N*D]  (z2 overlays zin)
    float* t    = zin + (size_t)NNODES * D;        // [N*D2]
    float* proj = t   + (size_t)NNODES * D2;       // [N*4]
    uint4* e32  = (uint4*)(proj + (size_t)NNODES * 4);      // [E * 32B], 16B-aligned
    __hip_bfloat16* hbf = (__hip_bfloat16*)(e32 + (size_t)NEDGES * 2);   // [N*D]
    // ---- contiguous zero-region: vn | vt0 | vt1 | stats(1536) | deg ----
    float* vn    = (float*)(hbf + (size_t)NNODES * D);
    float* vt0   = vn  + NG * D;
    float* vt1   = vt0 + NG * D;
    float* stats = vt1 + NG * D;                   // statsA: l*256 (0..767); statsB: 768+l*128
    int*   deg   = (int*)(stats + 1536);
    // ---- end zero-region ----
    int*   cursor = deg + NNODES;
    int*   bsum   = cursor + NNODES;
    int*   bbase  = bsum + NSB;
    float* ucm    = (float*)(bbase + NSB);         // [D2*NG]

    float* z2 = zin;   // overlay: zin dead after gemm1

    size_t zero_bytes = (size_t)(3 * NG * D + 1536) * 4 + (size_t)NNODES * 4;
    hipMemsetAsync(vn, 0, zero_bytes, stream);
    k_enc<<<NNODES / 4, 256, 0, stream>>>(x, Wenc, benc, eps, hin, hbf, zin);
    k_hist<<<(NEDGES + 255) / 256, 256, 0, stream>>>(ei, deg);
    k_scansum<<<NSB, 256, 0, stream>>>(deg, bsum);
    k_scanbase<<<1, 256, 0, stream>>>(bsum, bbase);
    k_scanwrite<<<NSB, 256, 0, stream>>>(deg, bbase, cursor);
    k_scatter<<<(NEDGES + 255) / 256, 256, 0, stream>>>(ei, ea, cursor, e32);

    for (int l = 0; l < 3; ++l) {
        float* statsA = stats + l * 256;
        float* statsB = stats + 768 + l * 128;
        if (l < 2) {
            float* vtb = (l == 0) ? vt0 : vt1;
            k_vt<<<(NNODES / 64 + 4) / 4, 256, 0, stream>>>(hin, batch, vtb);
            k_agg<<<(NEDGES + EPW * 4 - 1) / (EPW * 4), 256, 0, stream>>>(e32, We, be, l,
                                                                          hbf, zin);
            k_vn1<<<32, 256, 0, stream>>>(vtb, vn, Wv1, bv1, l, ucm);
            k_vn2<<<16, 256, 0, stream>>>(ucm, Wv2, bv2, l, vn);
        } else {
            k_agg<<<(NEDGES + EPW * 4 - 1) / (EPW * 4), 256, 0, stream>>>(e32, We, be, l,
                                                                          hbf, zin);
        }
        k_gemm1<<<(NNODES + 63) / 64, 256, 0, stream>>>(zin, W1, b1, l, t, statsA);
        k_gemm2<<<(NNODES + 31) / 32, 256, 0, stream>>>(t, statsA, W2, b2, l, z2, statsB);
        if (l < 2) {
            k_bnprep<<<NNODES * D / 256, 256, 0, stream>>>(z2, statsB, vn, batch, eps,
                                                           l + 1, hin, hbf, zin);
        } else {
            k_finish_att_proj<<<NNODES / 4, 256, 0, stream>>>(z2, statsB, Wna, bna, Wea,
                                                              proj, out);
        }
    }
    k_edge_final<<<(NEDGES + 255) / 256, 256, 0, stream>>>(ei, proj, bea, out);
}

// Round 10
// 660.738 us; speedup vs baseline: 2.1590x; 1.1036x over previous
//
#include <hip/hip_runtime.h>
#include <hip/hip_bf16.h>

#define NNODES 50000
#define NEDGES 800000
#define NG 64
#define D 64
#define D2 128
#define INDIM 39
#define EDIM 10
#define EPW 32             // edges per wave in k_agg (exact: 6250*4*32 = 800000)
#define BN_EPS 1e-5f
#define BN_BIAS 1e-4f
#define NSB ((NNODES + 255) / 256)   // 196 scan blocks

__device__ __forceinline__ float blo(unsigned u) {
    union { unsigned i; float f; } c; c.i = u << 16; return c.f;
}
__device__ __forceinline__ float bhi(unsigned u) {
    union { unsigned i; float f; } c; c.i = u & 0xffff0000u; return c.f;
}
__device__ __forceinline__ unsigned pk2(float a, float b) {
    __hip_bfloat16 ba = __float2bfloat16(a), bb = __float2bfloat16(b);
    return ((unsigned)*(unsigned short*)&bb << 16) | (unsigned)*(unsigned short*)&ba;
}

// ---------------- encoder: hin = x @ Wenc + benc (+ bf16 shadow, + zin init) ----------------
__global__ __launch_bounds__(256) void k_enc(const float* __restrict__ x,
                                             const float* __restrict__ Wenc,
                                             const float* __restrict__ benc,
                                             const float* __restrict__ eps,
                                             float* __restrict__ hin,
                                             __hip_bfloat16* __restrict__ hbf,
                                             float* __restrict__ zin) {
    __shared__ float sW[INDIM * D];
    for (int i = threadIdx.x; i < INDIM * D; i += 256) sW[i] = Wenc[i];
    __syncthreads();
    int wave = threadIdx.x >> 6, lane = threadIdx.x & 63;
    int row = blockIdx.x * 4 + wave;
    if (row >= NNODES) return;
    float xv = (lane < INDIM) ? x[row * INDIM + lane] : 0.f;
    float acc = benc[lane];
#pragma unroll
    for (int k = 0; k < INDIM; ++k) acc += __shfl(xv, k) * sW[k * D + lane];
    hin[row * D + lane] = acc;
    hbf[row * D + lane] = __float2bfloat16(acc);
    zin[row * D + lane] = (1.f + eps[0]) * acc;
}

// ---------------- CSR build ----------------
__global__ __launch_bounds__(256) void k_hist(const int* __restrict__ ei,
                                              int* __restrict__ deg) {
    int e = blockIdx.x * 256 + threadIdx.x;
    if (e < NEDGES) atomicAdd(&deg[ei[NEDGES + e]], 1);
}

__global__ __launch_bounds__(256) void k_scansum(const int* __restrict__ deg,
                                                 int* __restrict__ bsum) {
    int i = blockIdx.x * 256 + threadIdx.x;
    int v = (i < NNODES) ? deg[i] : 0;
#pragma unroll
    for (int o = 32; o; o >>= 1) v += __shfl_xor(v, o);
    __shared__ int ws[4];
    if ((threadIdx.x & 63) == 0) ws[threadIdx.x >> 6] = v;
    __syncthreads();
    if (threadIdx.x == 0) bsum[blockIdx.x] = ws[0] + ws[1] + ws[2] + ws[3];
}

__global__ __launch_bounds__(256) void k_scanbase(const int* __restrict__ bsum,
                                                  int* __restrict__ bbase) {
    __shared__ int s[256];
    int t = threadIdx.x;
    int v = (t < NSB) ? bsum[t] : 0;
    s[t] = v;
    __syncthreads();
    for (int o = 1; o < 256; o <<= 1) {
        int u = (t >= o) ? s[t - o] : 0;
        __syncthreads();
        s[t] += u;
        __syncthreads();
    }
    if (t < NSB) bbase[t] = s[t] - v;
}

__global__ __launch_bounds__(256) void k_scanwrite(const int* __restrict__ deg,
                                                   const int* __restrict__ bbase,
                                                   int* __restrict__ cursor) {
    __shared__ int s[256];
    int t = threadIdx.x;
    int i = blockIdx.x * 256 + t;
    int v = (i < NNODES) ? deg[i] : 0;
    s[t] = v;
    __syncthreads();
    for (int o = 1; o < 256; o <<= 1) {
        int u = (t >= o) ? s[t - o] : 0;
        __syncthreads();
        s[t] += u;
        __syncthreads();
    }
    int excl = bbase[blockIdx.x] + s[t] - v;
    if (i < NNODES) cursor[i] = excl;
}

// scatter fused 32B edge record {src, dst, 5 x bf16-pair} into CSR (dst-sorted) order
__global__ __launch_bounds__(256) void k_scatter(const int* __restrict__ ei,
                                                 const float* __restrict__ ea,
                                                 int* __restrict__ cursor,
                                                 uint4* __restrict__ e32) {
    int e = blockIdx.x * 256 + threadIdx.x;
    if (e >= NEDGES) return;
    int s = ei[e], d = ei[NEDGES + e];
    int p = atomicAdd(&cursor[d], 1);
    unsigned u[5];
#pragma unroll
    for (int i = 0; i < 5; ++i)
        u[i] = pk2(ea[e * EDIM + 2 * i], ea[e * EDIM + 2 * i + 1]);
    uint4 lo, hi;
    lo.x = (unsigned)s; lo.y = (unsigned)d; lo.z = u[0]; lo.w = u[1];
    hi.x = u[2]; hi.y = u[3]; hi.z = u[4]; hi.w = 0;
    e32[(size_t)p * 2] = lo;
    e32[(size_t)p * 2 + 1] = hi;
}

// ---------------- aggregate, edge-balanced, scalar edge stream ----------------
// zin pre-initialized to (1+eps)*hin. Exactly EPW edges per wave; edge records are
// wave-uniform (readfirstlane wave id) -> scalar s_load path; only hbf gather is VMEM.
__global__ __launch_bounds__(256) void k_agg(const uint4* __restrict__ e32,
                                             const float* __restrict__ We,
                                             const float* __restrict__ be, int l,
                                             const __hip_bfloat16* __restrict__ hbf,
                                             float* __restrict__ zin) {
    int wid = __builtin_amdgcn_readfirstlane(threadIdx.x >> 6);
    int lane = threadIdx.x & 63;
    int j0 = (blockIdx.x * 4 + wid) * EPW;
    const float* Wl = We + l * EDIM * D;
    float w[EDIM];
#pragma unroll
    for (int k = 0; k < EDIM; ++k) w[k] = Wl[k * D + lane];
    float bias = be[l * D + lane];
    float acc = 0.f;
    const uint4* ep = e32 + (size_t)j0 * 2;
    int cur = (int)ep[0].y;
#define EMB(lo, hi, m)                                                                   \
    {                                                                                    \
        m = bias;                                                                        \
        m += blo(lo.z) * w[0] + bhi(lo.z) * w[1] + blo(lo.w) * w[2] + bhi(lo.w) * w[3];  \
        m += blo(hi.x) * w[4] + bhi(hi.x) * w[5] + blo(hi.y) * w[6] + bhi(hi.y) * w[7];  \
        m += blo(hi.z) * w[8] + bhi(hi.z) * w[9];                                        \
    }
#define STEP(dd, mm, hh)                                                                 \
    {                                                                                    \
        if (dd != cur) {                                                                 \
            atomicAdd(&zin[(size_t)cur * D + lane], acc);                                \
            acc = 0.f; cur = dd;                                                         \
        }                                                                                \
        acc += fmaxf(mm + hh, 0.f);                                                      \
    }
#pragma unroll 2
    for (int it = 0; it < EPW; it += 4) {
        const uint4* r = ep + it * 2;
        uint4 lo0 = r[0], hi0 = r[1];
        uint4 lo1 = r[2], hi1 = r[3];
        uint4 lo2 = r[4], hi2 = r[5];
        uint4 lo3 = r[6], hi3 = r[7];
        float hv0 = __bfloat162float(hbf[(size_t)lo0.x * D + lane]);
        float hv1 = __bfloat162float(hbf[(size_t)lo1.x * D + lane]);
        float hv2 = __bfloat162float(hbf[(size_t)lo2.x * D + lane]);
        float hv3 = __bfloat162float(hbf[(size_t)lo3.x * D + lane]);
        float m0, m1, m2, m3;
        EMB(lo0, hi0, m0) EMB(lo1, hi1, m1) EMB(lo2, hi2, m2) EMB(lo3, hi3, m3)
        STEP((int)lo0.y, m0, hv0)
        STEP((int)lo1.y, m1, hv1)
        STEP((int)lo2.y, m2, hv2)
        STEP((int)lo3.y, m3, hv3)
    }
#undef EMB
#undef STEP
    atomicAdd(&zin[(size_t)cur * D + lane], acc);
}

// ---------------- GEMM1: tbf = bf16(zin @ W1 + b1) (+ fp32 BN stats) ----------------
__global__ __launch_bounds__(256) void k_gemm1(const float* __restrict__ zin,
                                               const float* __restrict__ W1,
                                               const float* __restrict__ b1, int l,
                                               __hip_bfloat16* __restrict__ tbf,
                                               float* __restrict__ stats1) {
    __shared__ float sZ[64 * 68];
    __shared__ float sW[D * D2];
    __shared__ float sSum[D2], sSq[D2];
    const float* Wp = W1 + l * D * D2;
    int row0 = blockIdx.x * 64;
    int nvalid = min(64, NNODES - row0);
    for (int i = threadIdx.x; i < D * D2 / 4; i += 256)
        *(float4*)&sW[i * 4] = *(const float4*)&Wp[i * 4];
    for (int i = threadIdx.x; i < 64 * 16; i += 256) {
        int r = i >> 4, c4 = (i & 15) * 4;
        float4 v = (r < nvalid) ? *(const float4*)&zin[(size_t)(row0 + r) * D + c4]
                                : make_float4(0.f, 0.f, 0.f, 0.f);
        *(float4*)&sZ[r * 68 + c4] = v;
    }
    if (threadIdx.x < D2) { sSum[threadIdx.x] = 0.f; sSq[threadIdx.x] = 0.f; }
    __syncthreads();
    int rg = threadIdx.x >> 4;
    int cg = threadIdx.x & 15;
    int r0 = rg * 4, c0 = cg * 4;
    float4 bA = *(const float4*)&b1[l * D2 + c0];
    float4 bB = *(const float4*)&b1[l * D2 + 64 + c0];
    float accA[4][4], accB[4][4];
#pragma unroll
    for (int r = 0; r < 4; ++r) {
        accA[r][0] = bA.x; accA[r][1] = bA.y; accA[r][2] = bA.z; accA[r][3] = bA.w;
        accB[r][0] = bB.x; accB[r][1] = bB.y; accB[r][2] = bB.z; accB[r][3] = bB.w;
    }
    for (int kk = 0; kk < D; kk += 4) {
        float4 a[4];
#pragma unroll
        for (int r = 0; r < 4; ++r) a[r] = *(const float4*)&sZ[(r0 + r) * 68 + kk];
#pragma unroll
        for (int dk = 0; dk < 4; ++dk) {
            float4 wA = *(const float4*)&sW[(kk + dk) * D2 + c0];
            float4 wB = *(const float4*)&sW[(kk + dk) * D2 + 64 + c0];
#pragma unroll
            for (int r = 0; r < 4; ++r) {
                float av = (&a[r].x)[dk];
                accA[r][0] += av * wA.x; accA[r][1] += av * wA.y;
                accA[r][2] += av * wA.z; accA[r][3] += av * wA.w;
                accB[r][0] += av * wB.x; accB[r][1] += av * wB.y;
                accB[r][2] += av * wB.z; accB[r][3] += av * wB.w;
            }
        }
    }
    float sA[4] = {0, 0, 0, 0}, qA[4] = {0, 0, 0, 0};
    float sB[4] = {0, 0, 0, 0}, qB[4] = {0, 0, 0, 0};
#pragma unroll
    for (int r = 0; r < 4; ++r) {
        int row = r0 + r;
        if (row < nvalid) {
            size_t base = (size_t)(row0 + row) * D2;
            *(uint2*)(tbf + base + c0) =
                make_uint2(pk2(accA[r][0], accA[r][1]), pk2(accA[r][2], accA[r][3]));
            *(uint2*)(tbf + base + 64 + c0) =
                make_uint2(pk2(accB[r][0], accB[r][1]), pk2(accB[r][2], accB[r][3]));
#pragma unroll
            for (int j = 0; j < 4; ++j) {
                sA[j] += accA[r][j]; qA[j] += accA[r][j] * accA[r][j];
                sB[j] += accB[r][j]; qB[j] += accB[r][j] * accB[r][j];
            }
        }
    }
#pragma unroll
    for (int j = 0; j < 4; ++j) {
        atomicAdd(&sSum[c0 + j], sA[j]);      atomicAdd(&sSq[c0 + j], qA[j]);
        atomicAdd(&sSum[64 + c0 + j], sB[j]); atomicAdd(&sSq[64 + c0 + j], qB[j]);
    }
    __syncthreads();
    if (threadIdx.x < D2) {
        atomicAdd(&stats1[threadIdx.x], sSum[threadIdx.x]);
        atomicAdd(&stats1[D2 + threadIdx.x], sSq[threadIdx.x]);
    }
}

// ---------------- GEMM2: z2 = relu(bn(tbf)) @ W2 + b2 (+ BN stats of z2) ----------------
__global__ __launch_bounds__(256) void k_gemm2(const __hip_bfloat16* __restrict__ tbf,
                                               const float* __restrict__ stats1,
                                               const float* __restrict__ W2,
                                               const float* __restrict__ b2, int l,
                                               float* __restrict__ z2,
                                               float* __restrict__ stats2) {
    __shared__ float sT[32 * 132];
    __shared__ float sW[D2 * D];
    __shared__ float sSum[D], sSq[D];
    const float* Wp = W2 + l * D2 * D;
    int row0 = blockIdx.x * 32;
    int nvalid = min(32, NNODES - row0);
    for (int i = threadIdx.x; i < D2 * D / 4; i += 256)
        *(float4*)&sW[i * 4] = *(const float4*)&Wp[i * 4];
    const float invN = 1.f / NNODES;
    for (int i = threadIdx.x; i < 32 * 32; i += 256) {
        int r = i >> 5, c4 = (i & 31) * 4;
        float4 v = make_float4(0.f, 0.f, 0.f, 0.f);
        if (r < nvalid) {
            uint2 tv = *(const uint2*)(tbf + (size_t)(row0 + r) * D2 + c4);
            float4 su = *(const float4*)&stats1[c4];
            float4 sq = *(const float4*)&stats1[D2 + c4];
            float mu, var, rstd;
            mu = su.x * invN; var = sq.x * invN - mu * mu; rstd = rsqrtf(var + BN_EPS);
            v.x = fmaxf((blo(tv.x) - mu) * rstd + BN_BIAS, 0.f);
            mu = su.y * invN; var = sq.y * invN - mu * mu; rstd = rsqrtf(var + BN_EPS);
            v.y = fmaxf((bhi(tv.x) - mu) * rstd + BN_BIAS, 0.f);
            mu = su.z * invN; var = sq.z * invN - mu * mu; rstd = rsqrtf(var + BN_EPS);
            v.z = fmaxf((blo(tv.y) - mu) * rstd + BN_BIAS, 0.f);
            mu = su.w * invN; var = sq.w * invN - mu * mu; rstd = rsqrtf(var + BN_EPS);
            v.w = fmaxf((bhi(tv.y) - mu) * rstd + BN_BIAS, 0.f);
        }
        *(float4*)&sT[r * 132 + c4] = v;
    }
    if (threadIdx.x < D) { sSum[threadIdx.x] = 0.f; sSq[threadIdx.x] = 0.f; }
    __syncthreads();
    int rg = threadIdx.x >> 4;
    int cg = threadIdx.x & 15;
    int r0 = rg * 2, c0 = cg * 4;
    float4 bv = *(const float4*)&b2[l * D + c0];
    float acc[2][4];
#pragma unroll
    for (int r = 0; r < 2; ++r) {
        acc[r][0] = bv.x; acc[r][1] = bv.y; acc[r][2] = bv.z; acc[r][3] = bv.w;
    }
    for (int kk = 0; kk < D2; kk += 4) {
        float4 a0 = *(const float4*)&sT[r0 * 132 + kk];
        float4 a1 = *(const float4*)&sT[(r0 + 1) * 132 + kk];
#pragma unroll
        for (int dk = 0; dk < 4; ++dk) {
            float4 w = *(const float4*)&sW[(kk + dk) * D + c0];
            float av0 = (&a0.x)[dk], av1 = (&a1.x)[dk];
            acc[0][0] += av0 * w.x; acc[0][1] += av0 * w.y;
            acc[0][2] += av0 * w.z; acc[0][3] += av0 * w.w;
            acc[1][0] += av1 * w.x; acc[1][1] += av1 * w.y;
            acc[1][2] += av1 * w.z; acc[1][3] += av1 * w.w;
        }
    }
    float s[4] = {0, 0, 0, 0}, q[4] = {0, 0, 0, 0};
#pragma unroll
    for (int r = 0; r < 2; ++r) {
        int row = r0 + r;
        if (row < nvalid) {
            *(float4*)&z2[(size_t)(row0 + row) * D + c0] =
                make_float4(acc[r][0], acc[r][1], acc[r][2], acc[r][3]);
#pragma unroll
            for (int j = 0; j < 4; ++j) { s[j] += acc[r][j]; q[j] += acc[r][j] * acc[r][j]; }
        }
    }
#pragma unroll
    for (int j = 0; j < 4; ++j) {
        atomicAdd(&sSum[c0 + j], s[j]); atomicAdd(&sSq[c0 + j], q[j]);
    }
    __syncthreads();
    if (threadIdx.x < D) {
        atomicAdd(&stats2[threadIdx.x], sSum[threadIdx.x]);
        atomicAdd(&stats2[D + threadIdx.x], sSq[threadIdx.x]);
    }
}

// ------- fused: hin = relu(bn(z2)) + vn[batch]; hbf shadow; zin init for NEXT layer -------
__global__ __launch_bounds__(256) void k_bnprep(const float* __restrict__ z2,
                                                const float* __restrict__ stats2,
                                                const float* __restrict__ vn,
                                                const int* __restrict__ batch,
                                                const float* __restrict__ eps, int lnext,
                                                float* __restrict__ hin,
                                                __hip_bfloat16* __restrict__ hbf,
                                                float* __restrict__ zin) {
    int idx = blockIdx.x * 256 + threadIdx.x;
    if (idx >= NNODES * D) return;
    int c = idx & 63, row = idx >> 6;
    const float invN = 1.f / NNODES;
    float mu = stats2[c] * invN;
    float var = stats2[D + c] * invN - mu * mu;
    float rstd = rsqrtf(var + BN_EPS);
    float v = (z2[idx] - mu) * rstd + BN_BIAS;
    v = fmaxf(v, 0.f);
    v += vn[batch[row] * D + c];
    hin[idx] = v;
    hbf[idx] = __float2bfloat16(v);
    zin[idx] = (1.f + eps[lnext]) * v;
}

// ---------------- fused final: bn(z2) -> node att + per-node edge projections ----------------
__global__ __launch_bounds__(256) void k_finish_att_proj(const float* __restrict__ z2,
                                                         const float* __restrict__ stats2,
                                                         const float* __restrict__ Wna,
                                                         const float* __restrict__ bna,
                                                         const float* __restrict__ Wea,
                                                         float* __restrict__ proj,
                                                         float* __restrict__ out) {
    int wave = threadIdx.x >> 6, lane = threadIdx.x & 63;
    int row = blockIdx.x * 4 + wave;
    if (row >= NNODES) return;
    const float invN = 1.f / NNODES;
    float mu = stats2[lane] * invN;
    float var = stats2[D + lane] * invN - mu * mu;
    float rstd = rsqrtf(var + BN_EPS);
    float v = (z2[row * D + lane] - mu) * rstd + BN_BIAS;
    float n0 = v * Wna[lane * 2 + 0];
    float n1 = v * Wna[lane * 2 + 1];
    float pa0 = v * Wea[lane * 2 + 0];
    float pa1 = v * Wea[lane * 2 + 1];
    float pb0 = v * Wea[(D + lane) * 2 + 0];
    float pb1 = v * Wea[(D + lane) * 2 + 1];
#pragma unroll
    for (int o = 32; o; o >>= 1) {
        n0 += __shfl_xor(n0, o); n1 += __shfl_xor(n1, o);
        pa0 += __shfl_xor(pa0, o); pa1 += __shfl_xor(pa1, o);
        pb0 += __shfl_xor(pb0, o); pb1 += __shfl_xor(pb1, o);
    }
    if (lane == 0) {
        out[row] = 1.f / (1.f + expf((n0 + bna[0]) - (n1 + bna[1])));
        proj[row * 4 + 0] = pa0;
        proj[row * 4 + 1] = pa1;
        proj[row * 4 + 2] = pb0;
        proj[row * 4 + 3] = pb1;
    }
}

// ---------------- edge attention from projection tables ----------------
__global__ __launch_bounds__(256) void k_edge_final(const int* __restrict__ ei,
                                                    const float* __restrict__ proj,
                                                    const float* __restrict__ bea,
                                                    float* __restrict__ out) {
    int e = blockIdx.x * 256 + threadIdx.x;
    if (e >= NEDGES) return;
    int src = ei[e], dst = ei[NEDGES + e];
    float4 ps = *(const float4*)&proj[src * 4];
    float4 pd = *(const float4*)&proj[dst * 4];
    float s0 = ps.x + pd.z + bea[0];
    float s1 = ps.y + pd.w + bea[1];
    out[NNODES + e] = 1.f / (1.f + expf(s0 - s1));
}

// ---------------- vt += segment_sum(hin) over contiguous row chunks ----------------
__global__ __launch_bounds__(256) void k_vt(const float* __restrict__ hin,
                                            const int* __restrict__ batch,
                                            float* __restrict__ vt) {
    int wave = threadIdx.x >> 6, lane = threadIdx.x & 63;
    int wid = blockIdx.x * 4 + wave;
    int r0 = wid * 64;
    if (r0 >= NNODES) return;
    int r1 = min(r0 + 64, NNODES);
    int g = batch[r0];
    float acc = 0.f;
    for (int r = r0; r < r1; ++r) {
        int gb = batch[r];
        if (gb != g) {
            atomicAdd(&vt[g * D + lane], acc);
            acc = 0.f; g = gb;
        }
        acc += hin[r * D + lane];
    }
    atomicAdd(&vt[g * D + lane], acc);
}

// ---------------- vn-MLP stage 1: ucm[col][row] = relu(bn((vt+vn) @ Wv1 + bv1)) ----------------
__global__ __launch_bounds__(256) void k_vn1(const float* __restrict__ vt,
                                             const float* __restrict__ vn,
                                             const float* __restrict__ Wv1,
                                             const float* __restrict__ bv1, int l,
                                             float* __restrict__ ucm) {
    __shared__ float sV[NG * 65];
    __shared__ float sW[NG * 4];
    int c0 = blockIdx.x * 4;
    for (int i = threadIdx.x; i < NG * D; i += 256) {
        int r = i >> 6, c = i & 63;
        sV[r * 65 + c] = vt[i] + vn[i];
    }
    {
        int k = threadIdx.x >> 2, c = threadIdx.x & 3;
        sW[threadIdx.x] = Wv1[l * D * D2 + k * D2 + c0 + c];
    }
    __syncthreads();
    int lane = threadIdx.x & 63, w = threadIdx.x >> 6;
    float acc = bv1[l * D2 + c0 + w];
#pragma unroll
    for (int k = 0; k < D; ++k) acc += sV[lane * 65 + k] * sW[k * 4 + w];
    float s = acc, sq = acc * acc;
#pragma unroll
    for (int o = 32; o; o >>= 1) { s += __shfl_xor(s, o); sq += __shfl_xor(sq, o); }
    float mu = s * (1.f / NG);
    float rstd = rsqrtf(sq * (1.f / NG) - mu * mu + BN_EPS);
    ucm[(c0 + w) * NG + lane] = fmaxf((acc - mu) * rstd + BN_BIAS, 0.f);
}

// ---------------- vn-MLP stage 2: vn = relu(bn(ucm^T @ Wv2 + bv2)) ----------------
__global__ __launch_bounds__(256) void k_vn2(const float* __restrict__ ucm,
                                             const float* __restrict__ Wv2,
                                             const float* __restrict__ bv2, int l,
                                             float* __restrict__ vn) {
    __shared__ float sU[D2 * NG];
    __shared__ float sW[D2 * 4];
    int c0 = blockIdx.x * 4;
    for (int i = threadIdx.x; i < D2 * NG; i += 256) sU[i] = ucm[i];
    for (int i = threadIdx.x; i < D2 * 4; i += 256) {
        int k = i >> 2, c = i & 3;
        sW[i] = Wv2[l * D2 * D + k * D + c0 + c];
    }
    __syncthreads();
    int lane = threadIdx.x & 63, w = threadIdx.x >> 6;
    float acc = bv2[l * D + c0 + w];
#pragma unroll
    for (int k = 0; k < D2; ++k) acc += sU[k * NG + lane] * sW[k * 4 + w];
    float s = acc, sq = acc * acc;
#pragma unroll
    for (int o = 32; o; o >>= 1) { s += __shfl_xor(s, o); sq += __shfl_xor(sq, o); }
    float mu = s * (1.f / NG);
    float rstd = rsqrtf(sq * (1.f / NG) - mu * mu + BN_EPS);
    vn[lane * D + c0 + w] = fmaxf((acc - mu) * rstd + BN_BIAS, 0.f);
}

extern "C" void kernel_launch(void* const* d_in, const int* in_sizes, int n_in,
                              void* d_out, int out_size, void* d_ws, size_t ws_size,
                              hipStream_t stream) {
    const float* x    = (const float*)d_in[0];
    const float* ea   = (const float*)d_in[1];
    const int*   ei   = (const int*)d_in[2];
    const int*   batch= (const int*)d_in[3];
    const float* Wenc = (const float*)d_in[4];
    const float* benc = (const float*)d_in[5];
    const float* We   = (const float*)d_in[6];
    const float* be   = (const float*)d_in[7];
    const float* eps  = (const float*)d_in[8];
    const float* W1   = (const float*)d_in[9];
    const float* b1   = (const float*)d_in[10];
    const float* W2   = (const float*)d_in[11];
    const float* b2   = (const float*)d_in[12];
    const float* Wv1  = (const float*)d_in[13];
    const float* bv1  = (const float*)d_in[14];
    const float* Wv2  = (const float*)d_in[15];
    const float* bv2  = (const float*)d_in[16];
    const float* Wea  = (const float*)d_in[17];
    const float* bea  = (const float*)d_in[18];
    const float* Wna  = (const float*)d_in[19];
    const float* bna  = (const float*)d_in[20];
    float* out = (float*)d_out;

    float* ws   = (float*)d_ws;
    float* hin  = ws;                              // [N*D]
    float* zin  = hin + (size_t)NNODES * D;        // [N*D]  (z2 overlays zin)
    float* t    = zin + (size_t)NNODES * D;        // slot [N*D2] f32; used as bf16 [N*D2]
    float* proj = t   + (size_t)NNODES * D2;       // [N*4]
    uint4* e32  = (uint4*)(proj + (size_t)NNODES * 4);      // [E * 32B], 16B-aligned
    __hip_bfloat16* hbf = (__hip_bfloat16*)(e32 + (size_t)NEDGES * 2);   // [N*D]
    // ---- contiguous zero-region: vn | vt0 | vt1 | stats(1536) | deg ----
    float* vn    = (float*)(hbf + (size_t)NNODES * D);
    float* vt0   = vn  + NG * D;
    float* vt1   = vt0 + NG * D;
    float* stats = vt1 + NG * D;                   // statsA: l*256 (0..767); statsB: 768+l*128
    int*   deg   = (int*)(stats + 1536);
    // ---- end zero-region ----
    int*   cursor = deg + NNODES;
    int*   bsum   = cursor + NNODES;
    int*   bbase  = bsum + NSB;
    float* ucm    = (float*)(bbase + NSB);         // [D2*NG]

    __hip_bfloat16* tbf = (__hip_bfloat16*)t;
    float* z2 = zin;   // overlay: zin dead after gemm1

    size_t zero_bytes = (size_t)(3 * NG * D + 1536) * 4 + (size_t)NNODES * 4;
    hipMemsetAsync(vn, 0, zero_bytes, stream);
    k_enc<<<NNODES / 4, 256, 0, stream>>>(x, Wenc, benc, eps, hin, hbf, zin);
    k_hist<<<(NEDGES + 255) / 256, 256, 0, stream>>>(ei, deg);
    k_scansum<<<NSB, 256, 0, stream>>>(deg, bsum);
    k_scanbase<<<1, 256, 0, stream>>>(bsum, bbase);
    k_scanwrite<<<NSB, 256, 0, stream>>>(deg, bbase, cursor);
    k_scatter<<<(NEDGES + 255) / 256, 256, 0, stream>>>(ei, ea, cursor, e32);

    for (int l = 0; l < 3; ++l) {
        float* statsA = stats + l * 256;
        float* statsB = stats + 768 + l * 128;
        if (l < 2) {
            float* vtb = (l == 0) ? vt0 : vt1;
            k_vt<<<(NNODES / 64 + 4) / 4, 256, 0, stream>>>(hin, batch, vtb);
            k_agg<<<NEDGES / (EPW * 4), 256, 0, stream>>>(e32, We, be, l, hbf, zin);
            k_vn1<<<32, 256, 0, stream>>>(vtb, vn, Wv1, bv1, l, ucm);
            k_vn2<<<16, 256, 0, stream>>>(ucm, Wv2, bv2, l, vn);
        } else {
            k_agg<<<NEDGES / (EPW * 4), 256, 0, stream>>>(e32, We, be, l, hbf, zin);
        }
        k_gemm1<<<(NNODES + 63) / 64, 256, 0, stream>>>(zin, W1, b1, l, tbf, statsA);
        k_gemm2<<<(NNODES + 31) / 32, 256, 0, stream>>>(tbf, statsA, W2, b2, l, z2, statsB);
        if (l < 2) {
            k_bnprep<<<NNODES * D / 256, 256, 0, stream>>>(z2, statsB, vn, batch, eps,
                                                           l + 1, hin, hbf, zin);
        } else {
            k_finish_att_proj<<<NNODES / 4, 256, 0, stream>>>(z2, statsB, Wna, bna, Wea,
                                                              proj, out);
        }
    }
    k_edge_final<<<(NEDGES + 255) / 256, 256, 0, stream>>>(ei, proj, bea, out);
}